// Round 1
// baseline (4799.244 us; speedup 1.0000x reference)
//
#include <hip/hip_runtime.h>
#include <math.h>

// GVAE-Transformer forward (fp32 end-to-end, matches JAX reference numerics).
// Shapes: OBS=8 PRED=4 NAG=256 FIN=2 FOUT=2 H=128 NH=8 FF=2048 NL=6.
// Workspace use ~180 MB (QKV 50MB + Fs 64MB + X/O/tmp 16MB each + small).
//
// Input order: 0 traj_in 1 adj_in 2 eps 3 pro1_w 4 pro1_b 5 pro2_w 6 pro2_b
// 7 mu_w 8 mu_b 9 ls_w 10 ls_b 11 gdl_w 12 gdl_b 13 pro3_w 14 pro3_b
// 15 pro4_w 16 pro4_b 17 pro5_w 18 pro5_b 19 t_qkv_w 20 t_qkv_b 21 t_out_w
// 22 t_out_b 23 t_ff1_w 24 t_ff1_b 25 t_ff2_w 26 t_ff2_b 27 t_ln1_g
// 28 t_ln1_b 29 t_ln2_g 30 t_ln2_b 31 iftrain(int)

namespace {

constexpr int kOBS = 8, kNAG = 256, kH = 128, kFFCH = 512, kNCH = 4;
constexpr int kGN = kOBS * kNAG;   // 2048 graph nodes
constexpr int kROWS = kNAG * kH;   // 32768 transformer rows (S=256, B=128)

struct Scal {
  int    mn_bits;     // +0
  int    mx_bits;     // +4
  float  Amin;        // +8
  float  invr;        // +12
  float  c0;          // +16  (0 - Amin)*invr  (off-block ADJ value; ==0 in practice)
  int    pad;         // +20
  double kld_sum;     // +24
  double struct_sum;  // +32
  double traj_sum;    // +40
};

__device__ inline float waveReduceSum(float v) {
#pragma unroll
  for (int off = 32; off; off >>= 1) v += __shfl_xor(v, off, 64);
  return v;
}

__global__ void k_init(Scal* sc) {
  if (threadIdx.x == 0) {
    sc->mn_bits = 0x7f800000;   // +inf bits
    sc->mx_bits = 0xff800000;   // -inf bits
    sc->kld_sum = 0.0;
    sc->struct_sum = 0.0;
    sc->traj_sum = 0.0;
  }
}

// min/max over adj (all values >= 0, so int-ordered float atomics are valid)
__global__ void k_minmax(const float* __restrict__ adj, int n, Scal* sc) {
  float lmin = INFINITY, lmax = -INFINITY;
  for (int i = blockIdx.x * blockDim.x + threadIdx.x; i < n;
       i += gridDim.x * blockDim.x) {
    float v = adj[i];
    lmin = fminf(lmin, v);
    lmax = fmaxf(lmax, v);
  }
#pragma unroll
  for (int off = 32; off; off >>= 1) {
    lmin = fminf(lmin, __shfl_xor(lmin, off, 64));
    lmax = fmaxf(lmax, __shfl_xor(lmax, off, 64));
  }
  __shared__ float smn[4], smx[4];
  int w = threadIdx.x >> 6;
  if ((threadIdx.x & 63) == 0) { smn[w] = lmin; smx[w] = lmax; }
  __syncthreads();
  if (threadIdx.x == 0) {
    lmin = fminf(fminf(smn[0], smn[1]), fminf(smn[2], smn[3]));
    lmax = fmaxf(fmaxf(smx[0], smx[1]), fmaxf(smx[2], smx[3]));
    atomicMin(&sc->mn_bits, __float_as_int(lmin));
    atomicMax(&sc->mx_bits, __float_as_int(lmax));
  }
}

__global__ void k_scale(Scal* sc) {
  // A is 2048x2048 block-diag: off-block zeros always participate in min/max.
  float mn = fminf(0.0f, __int_as_float(sc->mn_bits));
  float mx = fmaxf(0.0f, __int_as_float(sc->mx_bits));
  sc->Amin = mn;
  sc->invr = 1.0f / (mx - mn);
  sc->c0 = (0.0f - mn) * sc->invr;
}

// deg = column sums of A_sl (ADJ + self-loop-where-diag==0); dis = deg>0 ? 1/sqrt : 0
__global__ void k_dis(const float* __restrict__ adj, const Scal* __restrict__ sc,
                      float* __restrict__ dis) {
  int j = blockIdx.x * 256 + threadIdx.x;  // 0..2047
  int t = j >> 8, jj = j & 255;
  const float* a = adj + (size_t)t * 65536;
  float Amin = sc->Amin, invr = sc->invr, c0 = sc->c0;
  float sum = 0.f;
  for (int i = 0; i < 256; ++i) sum += (a[i * 256 + jj] - Amin) * invr;
  float djj = (a[jj * 256 + jj] - Amin) * invr;
  float deg = sum + 1792.0f * c0 + (djj == 0.0f ? 1.0f : 0.0f);
  dis[j] = deg > 0.0f ? 1.0f / sqrtf(deg) : 0.0f;
}

// agg[t][i][j] = dis[t*256+j] * A_sl[t][j][i] * dis[t*256+i]   (agg = (D A_sl D)^T)
__global__ void k_agg(const float* __restrict__ adj, const Scal* __restrict__ sc,
                      const float* __restrict__ dis, float* __restrict__ agg) {
  int idx = blockIdx.x * 256 + threadIdx.x;  // 524288 total
  int t = idx >> 16, i = (idx >> 8) & 255, j = idx & 255;
  float v = (adj[(size_t)t * 65536 + j * 256 + i] - sc->Amin) * sc->invr;
  if (i == j && v == 0.0f) v += 1.0f;  // self-loop where diag==0
  agg[idx] = dis[t * 256 + j] * v * dis[t * 256 + i];
}

// enc1 = relu(batch_in @ pro1_w.T + pro1_b), batch_in (2048,2)
__global__ void k_enc1(const float* __restrict__ traj, const float* __restrict__ w,
                       const float* __restrict__ b, float* __restrict__ out) {
  int idx = blockIdx.x * 256 + threadIdx.x;  // 2048*128
  int r = idx >> 7, f = idx & 127;
  float v = traj[r * 2] * w[f * 2] + traj[r * 2 + 1] * w[f * 2 + 1] + b[f];
  out[idx] = fmaxf(v, 0.0f);
}

// ---------------- tiled fp32 GEMM ----------------
// C(M,N) = A(M,K) @ op(B) + bias.  TB=true: B is (N,K) row-major (C=A@B^T).
// TB=false: B is (K,N) row-major (C=A@B).  lda==K always. flags: 1=relu 2=acc.
// All M%64==0, N%64==0, K%32==0 in this model — no edge guards.
#define BM 64
#define BN 64
#define KC 32
#define LP 68  // LDS row pad: K-major tiles, b128 fragment reads ~conflict-free

template <bool TB>
__global__ __launch_bounds__(256) void gemm_kernel(
    const float* __restrict__ A, const float* __restrict__ B,
    const float* __restrict__ bias, float* __restrict__ C, int K, int ldb,
    int ldc, int flags, size_t aStride, size_t bStride, size_t cStride) {
  if (blockIdx.z) {
    A += (size_t)blockIdx.z * aStride;
    B += (size_t)blockIdx.z * bStride;
    C += (size_t)blockIdx.z * cStride;
  }
  __shared__ float As[KC][LP];
  __shared__ float Bs[KC][LP];
  const int tid = threadIdx.x;
  const int tx = tid & 15, ty = tid >> 4;
  const int m0 = blockIdx.y * BM, n0 = blockIdx.x * BN;
  float acc[4][4] = {};
  for (int k0 = 0; k0 < K; k0 += KC) {
    // stage A (transpose to K-major): 64 rows x 32 k = 512 float4
#pragma unroll
    for (int i = 0; i < 2; ++i) {
      int q = tid + i * 256;
      int row = q >> 3, kq = q & 7;
      float4 v = *reinterpret_cast<const float4*>(
          &A[(size_t)(m0 + row) * K + k0 + kq * 4]);
      As[kq * 4 + 0][row] = v.x;
      As[kq * 4 + 1][row] = v.y;
      As[kq * 4 + 2][row] = v.z;
      As[kq * 4 + 3][row] = v.w;
    }
    if (TB) {
#pragma unroll
      for (int i = 0; i < 2; ++i) {
        int q = tid + i * 256;
        int row = q >> 3, kq = q & 7;
        float4 v = *reinterpret_cast<const float4*>(
            &B[(size_t)(n0 + row) * ldb + k0 + kq * 4]);
        Bs[kq * 4 + 0][row] = v.x;
        Bs[kq * 4 + 1][row] = v.y;
        Bs[kq * 4 + 2][row] = v.z;
        Bs[kq * 4 + 3][row] = v.w;
      }
    } else {
#pragma unroll
      for (int i = 0; i < 2; ++i) {
        int q = tid + i * 256;
        int kr = q >> 4, nq = q & 15;
        float4 v = *reinterpret_cast<const float4*>(
            &B[(size_t)(k0 + kr) * ldb + n0 + nq * 4]);
        *reinterpret_cast<float4*>(&Bs[kr][nq * 4]) = v;
      }
    }
    __syncthreads();
#pragma unroll
    for (int kk = 0; kk < KC; ++kk) {
      float4 a4 = *reinterpret_cast<const float4*>(&As[kk][ty * 4]);
      float4 b4 = *reinterpret_cast<const float4*>(&Bs[kk][tx * 4]);
      float av[4] = {a4.x, a4.y, a4.z, a4.w};
      float bv[4] = {b4.x, b4.y, b4.z, b4.w};
#pragma unroll
      for (int i = 0; i < 4; ++i)
#pragma unroll
        for (int j = 0; j < 4; ++j) acc[i][j] += av[i] * bv[j];
    }
    __syncthreads();
  }
  float bv[4] = {0.f, 0.f, 0.f, 0.f};
  if (bias) {
    float4 b4 = *reinterpret_cast<const float4*>(&bias[n0 + tx * 4]);
    bv[0] = b4.x; bv[1] = b4.y; bv[2] = b4.z; bv[3] = b4.w;
  }
#pragma unroll
  for (int i = 0; i < 4; ++i) {
    float* cp = &C[(size_t)(m0 + ty * 4 + i) * ldc + n0 + tx * 4];
    float4 o;
    float ov[4];
#pragma unroll
    for (int j = 0; j < 4; ++j) ov[j] = acc[i][j] + bv[j];
    if (flags & 2) {
      float4 old = *reinterpret_cast<const float4*>(cp);
      ov[0] += old.x; ov[1] += old.y; ov[2] += old.z; ov[3] += old.w;
    }
    if (flags & 1) {
#pragma unroll
      for (int j = 0; j < 4; ++j) ov[j] = fmaxf(ov[j], 0.0f);
    }
    o.x = ov[0]; o.y = ov[1]; o.z = ov[2]; o.w = ov[3];
    *reinterpret_cast<float4*>(cp) = o;
  }
}

// Z = mu + eps*exp(min(ls,10)) (train) ; kld terms accumulated
__global__ void k_zkld(const float* __restrict__ mu, const float* __restrict__ lsr,
                       const float* __restrict__ eps, const int* __restrict__ iftrain,
                       float* __restrict__ Z, Scal* sc) {
  int i = blockIdx.x * 256 + threadIdx.x;
  float m = mu[i];
  float ls = fminf(lsr[i], 10.0f);
  float z = (*iftrain > 0) ? m + eps[i] * expf(ls) : m;
  Z[i] = z;
  float kt = 1.0f + 2.0f * ls - m * m - expf(2.0f * ls);
  kt = waveReduceSum(kt);
  __shared__ float sh[4];
  int w = threadIdx.x >> 6;
  if ((threadIdx.x & 63) == 0) sh[w] = kt;
  __syncthreads();
  if (threadIdx.x == 0)
    atomicAdd(&sc->kld_sum, (double)(sh[0] + sh[1] + sh[2] + sh[3]));
}

// struct loss: fused Z@Z^T tile + logistic-loss reduction (never materializes logits)
__global__ __launch_bounds__(256) void k_struct(const float* __restrict__ Z,
                                                const float* __restrict__ adj,
                                                Scal* sc) {
  __shared__ float As[KC][LP];
  __shared__ float Bs[KC][LP];
  const int tid = threadIdx.x;
  const int tx = tid & 15, ty = tid >> 4;
  const int m0 = blockIdx.y * BM, n0 = blockIdx.x * BN;
  float acc[4][4] = {};
  for (int k0 = 0; k0 < kH; k0 += KC) {
#pragma unroll
    for (int i = 0; i < 2; ++i) {
      int q = tid + i * 256;
      int row = q >> 3, kq = q & 7;
      float4 va = *reinterpret_cast<const float4*>(
          &Z[(size_t)(m0 + row) * kH + k0 + kq * 4]);
      As[kq * 4 + 0][row] = va.x;
      As[kq * 4 + 1][row] = va.y;
      As[kq * 4 + 2][row] = va.z;
      As[kq * 4 + 3][row] = va.w;
      float4 vb = *reinterpret_cast<const float4*>(
          &Z[(size_t)(n0 + row) * kH + k0 + kq * 4]);
      Bs[kq * 4 + 0][row] = vb.x;
      Bs[kq * 4 + 1][row] = vb.y;
      Bs[kq * 4 + 2][row] = vb.z;
      Bs[kq * 4 + 3][row] = vb.w;
    }
    __syncthreads();
#pragma unroll
    for (int kk = 0; kk < KC; ++kk) {
      float4 a4 = *reinterpret_cast<const float4*>(&As[kk][ty * 4]);
      float4 b4 = *reinterpret_cast<const float4*>(&Bs[kk][tx * 4]);
      float av[4] = {a4.x, a4.y, a4.z, a4.w};
      float bv[4] = {b4.x, b4.y, b4.z, b4.w};
#pragma unroll
      for (int i = 0; i < 4; ++i)
#pragma unroll
        for (int j = 0; j < 4; ++j) acc[i][j] += av[i] * bv[j];
    }
    __syncthreads();
  }
  float Amin = sc->Amin, invr = sc->invr, c0v = sc->c0;
  float lsum = 0.f;
#pragma unroll
  for (int i = 0; i < 4; ++i) {
#pragma unroll
    for (int j = 0; j < 4; ++j) {
      int gi = m0 + ty * 4 + i, gj = n0 + tx * 4 + j;
      float l = acc[i][j];
      float adjv = c0v;
      if ((gi >> 8) == (gj >> 8))
        adjv = (adj[((size_t)(gi >> 8) << 16) + (gi & 255) * 256 + (gj & 255)] -
                Amin) * invr;
      lsum += fmaxf(l, 0.0f) - l * adjv + log1pf(expf(-fabsf(l)));
    }
  }
  lsum = waveReduceSum(lsum);
  __shared__ float sh[4];
  int w = threadIdx.x >> 6;
  if ((threadIdx.x & 63) == 0) sh[w] = lsum;
  __syncthreads();
  if (threadIdx.x == 0)
    atomicAdd(&sc->struct_sum, (double)(sh[0] + sh[1] + sh[2] + sh[3]));
}

// X[(n*128+h)][f] = sum_o gdl[(o*256+n)*128+h] * pro3_w[f*8+o] + pro3_b[f]
__global__ void k_x0(const float* __restrict__ gdl, const float* __restrict__ w3,
                     const float* __restrict__ b3, float* __restrict__ X) {
  int f = threadIdx.x;
  size_t r = (size_t)blockIdx.x * 2 + threadIdx.y;
  int n = (int)(r >> 7), h = (int)(r & 127);
  float a = b3[f];
#pragma unroll
  for (int o = 0; o < 8; ++o)
    a += gdl[((size_t)o * 256 + n) * 128 + h] * w3[f * 8 + o];
  X[r * 128 + f] = a;
}

// attention for one (head, b): S=256, dh=16; exact 2-pass softmax
__global__ __launch_bounds__(256) void k_attn(const float* __restrict__ QKV,
                                              float* __restrict__ O) {
  const int head = blockIdx.x, b = blockIdx.y;
  const int s = threadIdx.x;
  __shared__ float ks[256][16];
  __shared__ float vs[256][16];
  const size_t base = ((size_t)s * 128 + b) * 384 + head * 16;
  {
    const float4* kp = reinterpret_cast<const float4*>(&QKV[base + 128]);
    const float4* vp = reinterpret_cast<const float4*>(&QKV[base + 256]);
#pragma unroll
    for (int i = 0; i < 4; ++i) {
      *reinterpret_cast<float4*>(&ks[s][i * 4]) = kp[i];
      *reinterpret_cast<float4*>(&vs[s][i * 4]) = vp[i];
    }
  }
  float q[16];
  {
    const float4* qp = reinterpret_cast<const float4*>(&QKV[base]);
#pragma unroll
    for (int i = 0; i < 4; ++i) {
      float4 v = qp[i];
      q[i * 4 + 0] = v.x; q[i * 4 + 1] = v.y; q[i * 4 + 2] = v.z; q[i * 4 + 3] = v.w;
    }
  }
  __syncthreads();
  float mx = -INFINITY;
  for (int t = 0; t < 256; ++t) {
    float d = 0.f;
#pragma unroll
    for (int i = 0; i < 4; ++i) {
      float4 kv = *reinterpret_cast<const float4*>(&ks[t][i * 4]);
      d += q[i * 4 + 0] * kv.x + q[i * 4 + 1] * kv.y + q[i * 4 + 2] * kv.z +
           q[i * 4 + 3] * kv.w;
    }
    mx = fmaxf(mx, d * 0.25f);
  }
  float sum = 0.f;
  float o[16] = {};
  for (int t = 0; t < 256; ++t) {
    float d = 0.f;
#pragma unroll
    for (int i = 0; i < 4; ++i) {
      float4 kv = *reinterpret_cast<const float4*>(&ks[t][i * 4]);
      d += q[i * 4 + 0] * kv.x + q[i * 4 + 1] * kv.y + q[i * 4 + 2] * kv.z +
           q[i * 4 + 3] * kv.w;
    }
    float p = expf(d * 0.25f - mx);
    sum += p;
#pragma unroll
    for (int i = 0; i < 4; ++i) {
      float4 vv = *reinterpret_cast<const float4*>(&vs[t][i * 4]);
      o[i * 4 + 0] += p * vv.x; o[i * 4 + 1] += p * vv.y;
      o[i * 4 + 2] += p * vv.z; o[i * 4 + 3] += p * vv.w;
    }
  }
  float inv = 1.0f / sum;
  float* op = &O[((size_t)s * 128 + b) * 128 + head * 16];
#pragma unroll
  for (int i = 0; i < 4; ++i) {
    float4 v;
    v.x = o[i * 4 + 0] * inv; v.y = o[i * 4 + 1] * inv;
    v.z = o[i * 4 + 2] * inv; v.w = o[i * 4 + 3] * inv;
    *reinterpret_cast<float4*>(&op[i * 4]) = v;
  }
}

// X = LN(X + T) row-wise over 128 features; 4 rows/block, 64 lanes/row
__global__ __launch_bounds__(256) void k_resid_ln(float* __restrict__ X,
                                                  const float* __restrict__ T,
                                                  const float* __restrict__ g,
                                                  const float* __restrict__ b) {
  int lane = threadIdx.x & 63, rl = threadIdx.x >> 6;
  size_t row = (size_t)blockIdx.x * 4 + rl;
  float* xp = X + row * 128;
  const float* tp = T + row * 128;
  float e0 = xp[lane] + tp[lane];
  float e1 = xp[lane + 64] + tp[lane + 64];
  float mean = waveReduceSum(e0 + e1) * 0.0078125f;
  float d0 = e0 - mean, d1 = e1 - mean;
  float var = waveReduceSum(d0 * d0 + d1 * d1) * 0.0078125f;
  float inv = 1.0f / sqrtf(var + 1e-5f);
  xp[lane] = d0 * inv * g[lane] + b[lane];
  xp[lane + 64] = d1 * inv * g[lane + 64] + b[lane + 64];
}

// y[r][o] = X[r] . pro4_w[o] + pro4_b[o]   (o=0..7)
__global__ void k_heady(const float* __restrict__ X, const float* __restrict__ w4,
                        const float* __restrict__ b4, float* __restrict__ y) {
  int tid = threadIdx.x;
  int o = tid & 7, rl = tid >> 3;
  size_t r = (size_t)blockIdx.x * 32 + rl;
  const float* xp = X + r * 128;
  const float* wp = w4 + o * 128;
  float a = b4[o];
  for (int f = 0; f < 128; f += 4)
    a += xp[f] * wp[f] + xp[f + 1] * wp[f + 1] + xp[f + 2] * wp[f + 2] +
         xp[f + 3] * wp[f + 3];
  y[r * 8 + o] = a;
}

// tra[o=4..7][n][c] + traj loss accumulation. One block per n, 64 lanes.
__global__ void k_traj(const float* __restrict__ y, const float* __restrict__ w5,
                       const float* __restrict__ b5,
                       const float* __restrict__ traj_in, float* __restrict__ dout,
                       Scal* sc) {
  int n = blockIdx.x, lane = threadIdx.x;
  float w0a = w5[lane], w0b = w5[lane + 64];
  float w1a = w5[128 + lane], w1b = w5[128 + lane + 64];
  float dsum = 0.f;
  for (int oi = 0; oi < 4; ++oi) {
    int o = 4 + oi;
    float ya = y[((size_t)n * 128 + lane) * 8 + o];
    float yb = y[((size_t)n * 128 + lane + 64) * 8 + o];
    float s0 = waveReduceSum(w0a * ya + w0b * yb);
    float s1 = waveReduceSum(w1a * ya + w1b * yb);
    if (lane == 0) {
      float t0 = s0 + b5[0], t1 = s1 + b5[1];
      dout[oi * 512 + n * 2 + 0] = t0;
      dout[oi * 512 + n * 2 + 1] = t1;
      float dx = t0 - traj_in[((8 + oi) * 256 + n) * 2 + 0];
      float dy = t1 - traj_in[((8 + oi) * 256 + n) * 2 + 1];
      dsum += sqrtf(dx * dx + dy * dy);
    }
  }
  if (lane == 0) atomicAdd(&sc->traj_sum, (double)dsum);
}

__global__ void k_loss(const Scal* sc, float* dout) {
  if (threadIdx.x == 0) {
    double traj_loss = sc->traj_sum / 256.0;
    double kld = -0.5 * sc->kld_sum / 2048.0;
    double st = sc->struct_sum / (2048.0 * 2048.0);
    dout[2048] = (float)(traj_loss + kld + st);
  }
}

}  // namespace

extern "C" void kernel_launch(void* const* d_in, const int* in_sizes, int n_in,
                              void* d_out, int out_size, void* d_ws,
                              size_t ws_size, hipStream_t stream) {
  (void)in_sizes; (void)n_in; (void)out_size; (void)ws_size;
  const float* traj_in = (const float*)d_in[0];
  const float* adj     = (const float*)d_in[1];
  const float* eps     = (const float*)d_in[2];
  const float* pro1_w  = (const float*)d_in[3];
  const float* pro1_b  = (const float*)d_in[4];
  const float* pro2_w  = (const float*)d_in[5];
  const float* pro2_b  = (const float*)d_in[6];
  const float* mu_w    = (const float*)d_in[7];
  const float* mu_b    = (const float*)d_in[8];
  const float* ls_w    = (const float*)d_in[9];
  const float* ls_b    = (const float*)d_in[10];
  const float* gdl_w   = (const float*)d_in[11];
  const float* gdl_b   = (const float*)d_in[12];
  const float* pro3_w  = (const float*)d_in[13];
  const float* pro3_b  = (const float*)d_in[14];
  const float* pro4_w  = (const float*)d_in[15];
  const float* pro4_b  = (const float*)d_in[16];
  const float* pro5_w  = (const float*)d_in[17];
  const float* pro5_b  = (const float*)d_in[18];
  const float* qkv_w   = (const float*)d_in[19];
  const float* qkv_b   = (const float*)d_in[20];
  const float* outp_w  = (const float*)d_in[21];
  const float* outp_b  = (const float*)d_in[22];
  const float* ff1_w   = (const float*)d_in[23];
  const float* ff1_b   = (const float*)d_in[24];
  const float* ff2_w   = (const float*)d_in[25];
  const float* ff2_b   = (const float*)d_in[26];
  const float* ln1_g   = (const float*)d_in[27];
  const float* ln1_b   = (const float*)d_in[28];
  const float* ln2_g   = (const float*)d_in[29];
  const float* ln2_b   = (const float*)d_in[30];
  const int*   iftrain = (const int*)d_in[31];
  float* dout = (float*)d_out;

  char* wsb = (char*)d_ws;
  size_t off = 0;
  auto alloc = [&](size_t floats) {
    float* p = (float*)(wsb + off);
    off += ((floats * 4 + 255) / 256) * 256;
    return p;
  };
  Scal* sc   = (Scal*)alloc(64);
  float* dis = alloc(kGN);
  float* agg = alloc((size_t)kOBS * 65536);
  float* enc1 = alloc((size_t)kGN * kH);
  float* enc  = alloc((size_t)kGN * kH);
  float* Mmu  = alloc((size_t)kGN * kH);
  float* Mls  = alloc((size_t)kGN * kH);
  float* mu   = alloc((size_t)kGN * kH);
  float* lsb  = alloc((size_t)kGN * kH);
  float* Z    = alloc((size_t)kGN * kH);
  float* gdl  = alloc((size_t)kGN * kH);
  float* X    = alloc((size_t)kROWS * kH);
  float* QKV  = alloc((size_t)kROWS * 3 * kH);
  float* O    = alloc((size_t)kROWS * kH);
  float* tmp  = alloc((size_t)kROWS * kH);
  float* Fs   = alloc((size_t)kROWS * kFFCH);
  float* y    = alloc((size_t)kROWS * 8);

  auto gemm_nt = [&](const float* A, const float* B, const float* bias, float* C,
                     int M, int N, int K, int ldb, int ldc, int flags) {
    dim3 g(N / 64, M / 64, 1);
    gemm_kernel<true><<<g, 256, 0, stream>>>(A, B, bias, C, K, ldb, ldc, flags,
                                             (size_t)0, (size_t)0, (size_t)0);
  };

  k_init<<<1, 64, 0, stream>>>(sc);
  k_minmax<<<512, 256, 0, stream>>>(adj, kOBS * kNAG * kNAG, sc);
  k_scale<<<1, 1, 0, stream>>>(sc);
  k_dis<<<8, 256, 0, stream>>>(adj, sc, dis);
  k_agg<<<2048, 256, 0, stream>>>(adj, sc, dis, agg);

  k_enc1<<<(kGN * kH) / 256, 256, 0, stream>>>(traj_in, pro1_w, pro1_b, enc1);
  gemm_nt(enc1, pro2_w, pro2_b, enc, kGN, kH, kH, kH, kH, 0);
  gemm_nt(enc, mu_w, mu_b, Mmu, kGN, kH, kH, kH, kH, 0);
  gemm_nt(enc, ls_w, ls_b, Mls, kGN, kH, kH, kH, kH, 0);
  {
    dim3 g(kH / 64, kNAG / 64, kOBS);
    gemm_kernel<false><<<g, 256, 0, stream>>>(agg, Mmu, nullptr, mu, kNAG, kH,
                                              kH, 0, (size_t)65536,
                                              (size_t)kNAG * kH, (size_t)kNAG * kH);
    gemm_kernel<false><<<g, 256, 0, stream>>>(agg, Mls, nullptr, lsb, kNAG, kH,
                                              kH, 0, (size_t)65536,
                                              (size_t)kNAG * kH, (size_t)kNAG * kH);
  }
  k_zkld<<<(kGN * kH) / 256, 256, 0, stream>>>(mu, lsb, eps, iftrain, Z, sc);
  gemm_nt(Z, gdl_w, gdl_b, gdl, kGN, kH, kH, kH, kH, 0);
  k_struct<<<dim3(kGN / 64, kGN / 64), 256, 0, stream>>>(Z, adj, sc);
  k_x0<<<kROWS / 2, dim3(128, 2), 0, stream>>>(gdl, pro3_w, pro3_b, X);

  for (int l = 0; l < 6; ++l) {
    gemm_nt(X, qkv_w + (size_t)l * 384 * kH, qkv_b + l * 384, QKV, kROWS, 384,
            kH, kH, 384, 0);
    k_attn<<<dim3(8, 128), 256, 0, stream>>>(QKV, O);
    gemm_nt(O, outp_w + (size_t)l * kH * kH, outp_b + l * kH, tmp, kROWS, kH,
            kH, kH, kH, 0);
    k_resid_ln<<<kROWS / 4, 256, 0, stream>>>(X, tmp, ln1_g + l * kH,
                                              ln1_b + l * kH);
    for (int c = 0; c < kNCH; ++c) {
      gemm_nt(X, ff1_w + (size_t)l * 2048 * kH + (size_t)c * kFFCH * kH,
              ff1_b + l * 2048 + c * kFFCH, Fs, kROWS, kFFCH, kH, kH, kFFCH,
              1 /*relu*/);
      gemm_nt(Fs, ff2_w + (size_t)l * kH * 2048 + c * kFFCH,
              (c == 0 ? ff2_b + l * kH : nullptr), tmp, kROWS, kH, kFFCH, 2048,
              kH, (c == 0 ? 0 : 2 /*acc*/));
    }
    k_resid_ln<<<kROWS / 4, 256, 0, stream>>>(X, tmp, ln2_g + l * kH,
                                              ln2_b + l * kH);
  }

  k_heady<<<kROWS / 32, 256, 0, stream>>>(X, pro4_w, pro4_b, y);
  k_traj<<<kNAG, 64, 0, stream>>>(y, pro5_w, pro5_b, traj_in, dout, sc);
  k_loss<<<1, 1, 0, stream>>>(sc, dout);
}

// Round 2
// 4679.730 us; speedup vs baseline: 1.0255x; 1.0255x over previous
//
#include <hip/hip_runtime.h>
#include <math.h>

// GVAE-Transformer forward (fp32 end-to-end, matches JAX reference numerics).
// Shapes: OBS=8 PRED=4 NAG=256 FIN=2 FOUT=2 H=128 NH=8 FF=2048 NL=6.
//
// R2 changes vs R1 baseline (4799 us):
//  - k_attn: single-pass online softmax w/ deferred rescale (THR=8), 2 q-rows
//    per thread, __expf, scale folded into q.  (was 200us/layer, 2-pass, expf)
//  - transformer GEMMs: 128-wide tiles, 8x8 / 8x4 micro-tiles, swizzled B
//    fragment layout (2-way bank conflicts only).
//  - __expf/__logf in loss kernels.

namespace {

constexpr int kOBS = 8, kNAG = 256, kH = 128, kFFCH = 512, kNCH = 4;
constexpr int kGN = kOBS * kNAG;   // 2048 graph nodes
constexpr int kROWS = kNAG * kH;   // 32768 transformer rows (S=256, B=128)

struct Scal {
  int    mn_bits;
  int    mx_bits;
  float  Amin;
  float  invr;
  float  c0;
  int    pad;
  double kld_sum;
  double struct_sum;
  double traj_sum;
};

__device__ inline float waveReduceSum(float v) {
#pragma unroll
  for (int off = 32; off; off >>= 1) v += __shfl_xor(v, off, 64);
  return v;
}

__global__ void k_init(Scal* sc) {
  if (threadIdx.x == 0) {
    sc->mn_bits = 0x7f800000;
    sc->mx_bits = 0xff800000;
    sc->kld_sum = 0.0;
    sc->struct_sum = 0.0;
    sc->traj_sum = 0.0;
  }
}

__global__ void k_minmax(const float* __restrict__ adj, int n, Scal* sc) {
  float lmin = INFINITY, lmax = -INFINITY;
  for (int i = blockIdx.x * blockDim.x + threadIdx.x; i < n;
       i += gridDim.x * blockDim.x) {
    float v = adj[i];
    lmin = fminf(lmin, v);
    lmax = fmaxf(lmax, v);
  }
#pragma unroll
  for (int off = 32; off; off >>= 1) {
    lmin = fminf(lmin, __shfl_xor(lmin, off, 64));
    lmax = fmaxf(lmax, __shfl_xor(lmax, off, 64));
  }
  __shared__ float smn[4], smx[4];
  int w = threadIdx.x >> 6;
  if ((threadIdx.x & 63) == 0) { smn[w] = lmin; smx[w] = lmax; }
  __syncthreads();
  if (threadIdx.x == 0) {
    lmin = fminf(fminf(smn[0], smn[1]), fminf(smn[2], smn[3]));
    lmax = fmaxf(fmaxf(smx[0], smx[1]), fmaxf(smx[2], smx[3]));
    atomicMin(&sc->mn_bits, __float_as_int(lmin));
    atomicMax(&sc->mx_bits, __float_as_int(lmax));
  }
}

__global__ void k_scale(Scal* sc) {
  float mn = fminf(0.0f, __int_as_float(sc->mn_bits));
  float mx = fmaxf(0.0f, __int_as_float(sc->mx_bits));
  sc->Amin = mn;
  sc->invr = 1.0f / (mx - mn);
  sc->c0 = (0.0f - mn) * sc->invr;
}

__global__ void k_dis(const float* __restrict__ adj, const Scal* __restrict__ sc,
                      float* __restrict__ dis) {
  int j = blockIdx.x * 256 + threadIdx.x;
  int t = j >> 8, jj = j & 255;
  const float* a = adj + (size_t)t * 65536;
  float Amin = sc->Amin, invr = sc->invr, c0 = sc->c0;
  float sum = 0.f;
  for (int i = 0; i < 256; ++i) sum += (a[i * 256 + jj] - Amin) * invr;
  float djj = (a[jj * 256 + jj] - Amin) * invr;
  float deg = sum + 1792.0f * c0 + (djj == 0.0f ? 1.0f : 0.0f);
  dis[j] = deg > 0.0f ? 1.0f / sqrtf(deg) : 0.0f;
}

__global__ void k_agg(const float* __restrict__ adj, const Scal* __restrict__ sc,
                      const float* __restrict__ dis, float* __restrict__ agg) {
  int idx = blockIdx.x * 256 + threadIdx.x;
  int t = idx >> 16, i = (idx >> 8) & 255, j = idx & 255;
  float v = (adj[(size_t)t * 65536 + j * 256 + i] - sc->Amin) * sc->invr;
  if (i == j && v == 0.0f) v += 1.0f;
  agg[idx] = dis[t * 256 + j] * v * dis[t * 256 + i];
}

__global__ void k_enc1(const float* __restrict__ traj, const float* __restrict__ w,
                       const float* __restrict__ b, float* __restrict__ out) {
  int idx = blockIdx.x * 256 + threadIdx.x;
  int r = idx >> 7, f = idx & 127;
  float v = traj[r * 2] * w[f * 2] + traj[r * 2 + 1] * w[f * 2 + 1] + b[f];
  out[idx] = fmaxf(v, 0.0f);
}

// ---------------- small fp32 GEMM (front-end, M=2048) ----------------
#define BM 64
#define BN 64
#define KC 32
#define LP 68

template <bool TB>
__global__ __launch_bounds__(256) void gemm_kernel(
    const float* __restrict__ A, const float* __restrict__ B,
    const float* __restrict__ bias, float* __restrict__ C, int K, int ldb,
    int ldc, int flags, size_t aStride, size_t bStride, size_t cStride) {
  if (blockIdx.z) {
    A += (size_t)blockIdx.z * aStride;
    B += (size_t)blockIdx.z * bStride;
    C += (size_t)blockIdx.z * cStride;
  }
  __shared__ float As[KC][LP];
  __shared__ float Bs[KC][LP];
  const int tid = threadIdx.x;
  const int tx = tid & 15, ty = tid >> 4;
  const int m0 = blockIdx.y * BM, n0 = blockIdx.x * BN;
  float acc[4][4] = {};
  for (int k0 = 0; k0 < K; k0 += KC) {
#pragma unroll
    for (int i = 0; i < 2; ++i) {
      int q = tid + i * 256;
      int row = q >> 3, kq = q & 7;
      float4 v = *reinterpret_cast<const float4*>(
          &A[(size_t)(m0 + row) * K + k0 + kq * 4]);
      As[kq * 4 + 0][row] = v.x;
      As[kq * 4 + 1][row] = v.y;
      As[kq * 4 + 2][row] = v.z;
      As[kq * 4 + 3][row] = v.w;
    }
    if (TB) {
#pragma unroll
      for (int i = 0; i < 2; ++i) {
        int q = tid + i * 256;
        int row = q >> 3, kq = q & 7;
        float4 v = *reinterpret_cast<const float4*>(
            &B[(size_t)(n0 + row) * ldb + k0 + kq * 4]);
        Bs[kq * 4 + 0][row] = v.x;
        Bs[kq * 4 + 1][row] = v.y;
        Bs[kq * 4 + 2][row] = v.z;
        Bs[kq * 4 + 3][row] = v.w;
      }
    } else {
#pragma unroll
      for (int i = 0; i < 2; ++i) {
        int q = tid + i * 256;
        int kr = q >> 4, nq = q & 15;
        float4 v = *reinterpret_cast<const float4*>(
            &B[(size_t)(k0 + kr) * ldb + n0 + nq * 4]);
        *reinterpret_cast<float4*>(&Bs[kr][nq * 4]) = v;
      }
    }
    __syncthreads();
#pragma unroll
    for (int kk = 0; kk < KC; ++kk) {
      float4 a4 = *reinterpret_cast<const float4*>(&As[kk][ty * 4]);
      float4 b4 = *reinterpret_cast<const float4*>(&Bs[kk][tx * 4]);
      float av[4] = {a4.x, a4.y, a4.z, a4.w};
      float bv[4] = {b4.x, b4.y, b4.z, b4.w};
#pragma unroll
      for (int i = 0; i < 4; ++i)
#pragma unroll
        for (int j = 0; j < 4; ++j) acc[i][j] += av[i] * bv[j];
    }
    __syncthreads();
  }
  float bv[4] = {0.f, 0.f, 0.f, 0.f};
  if (bias) {
    float4 b4 = *reinterpret_cast<const float4*>(&bias[n0 + tx * 4]);
    bv[0] = b4.x; bv[1] = b4.y; bv[2] = b4.z; bv[3] = b4.w;
  }
#pragma unroll
  for (int i = 0; i < 4; ++i) {
    float* cp = &C[(size_t)(m0 + ty * 4 + i) * ldc + n0 + tx * 4];
    float4 o;
    float ov[4];
#pragma unroll
    for (int j = 0; j < 4; ++j) ov[j] = acc[i][j] + bv[j];
    if (flags & 2) {
      float4 old = *reinterpret_cast<const float4*>(cp);
      ov[0] += old.x; ov[1] += old.y; ov[2] += old.z; ov[3] += old.w;
    }
    if (flags & 1) {
#pragma unroll
      for (int j = 0; j < 4; ++j) ov[j] = fmaxf(ov[j], 0.0f);
    }
    o.x = ov[0]; o.y = ov[1]; o.z = ov[2]; o.w = ov[3];
    *reinterpret_cast<float4*>(cp) = o;
  }
}

// ---------------- big fp32 GEMM (transformer, M=32768) ----------------
// 256 threads as tx(0..15) x ty(0..15); per-thread micro-tile WMxWN.
// BM=16*WM rows, BN=16*WN cols, K-chunk 16.  B fragments stored with a
// 32-group offset swizzle (col + (col>>5)*4) -> 2-way LDS conflicts (free).
constexpr int KC2 = 16;

template <bool TB, int BMb, int BNb, int WM, int WN>
__global__ __launch_bounds__(256) void gemm_big(
    const float* __restrict__ A, const float* __restrict__ B,
    const float* __restrict__ bias, float* __restrict__ C, int K, int ldb,
    int ldc, int flags) {
  constexpr int LPA = BMb + 4;
  constexpr int LPB = BNb + (BNb / 32) * 4;
  __shared__ float As[KC2][LPA];
  __shared__ float Bs[KC2][LPB];
  const int tid = threadIdx.x;
  const int tx = tid & 15, ty = tid >> 4;
  const int m0 = blockIdx.y * BMb, n0 = blockIdx.x * BNb;
  float acc[WM][WN] = {};
  for (int k0 = 0; k0 < K; k0 += KC2) {
    // stage A (transpose to K-major): BMb*16 floats = BMb*4 float4
#pragma unroll
    for (int i = 0; i < BMb / 64; ++i) {
      int q = tid + i * 256;
      int row = q >> 2, k4 = q & 3;
      float4 v = *reinterpret_cast<const float4*>(
          &A[(size_t)(m0 + row) * K + k0 + k4 * 4]);
      As[k4 * 4 + 0][row] = v.x;
      As[k4 * 4 + 1][row] = v.y;
      As[k4 * 4 + 2][row] = v.z;
      As[k4 * 4 + 3][row] = v.w;
    }
    if (TB) {
#pragma unroll
      for (int i = 0; i < BNb / 64; ++i) {
        int q = tid + i * 256;
        int row = q >> 2, k4 = q & 3;  // row = n index within tile
        float4 v = *reinterpret_cast<const float4*>(
            &B[(size_t)(n0 + row) * ldb + k0 + k4 * 4]);
        int pc = row + (row >> 5) * 4;
        Bs[k4 * 4 + 0][pc] = v.x;
        Bs[k4 * 4 + 1][pc] = v.y;
        Bs[k4 * 4 + 2][pc] = v.z;
        Bs[k4 * 4 + 3][pc] = v.w;
      }
    } else {
#pragma unroll
      for (int i = 0; i < BNb / 64; ++i) {
        int q = tid + i * 256;
        int kr = q / (BNb / 4), nq = q % (BNb / 4);
        float4 v = *reinterpret_cast<const float4*>(
            &B[(size_t)(k0 + kr) * ldb + n0 + nq * 4]);
        int c = nq * 4;
        *reinterpret_cast<float4*>(&Bs[kr][c + (c >> 5) * 4]) = v;
      }
    }
    __syncthreads();
#pragma unroll
    for (int kk = 0; kk < KC2; ++kk) {
      float a[WM], b[WN];
#pragma unroll
      for (int i = 0; i < WM / 4; ++i) {
        float4 v = *reinterpret_cast<const float4*>(&As[kk][ty * WM + i * 4]);
        a[i * 4 + 0] = v.x; a[i * 4 + 1] = v.y;
        a[i * 4 + 2] = v.z; a[i * 4 + 3] = v.w;
      }
      const int bbase = tx * WN + ((tx * WN) >> 5) * 4;
#pragma unroll
      for (int j = 0; j < WN / 4; ++j) {
        float4 v = *reinterpret_cast<const float4*>(&Bs[kk][bbase + j * 4]);
        b[j * 4 + 0] = v.x; b[j * 4 + 1] = v.y;
        b[j * 4 + 2] = v.z; b[j * 4 + 3] = v.w;
      }
#pragma unroll
      for (int i = 0; i < WM; ++i)
#pragma unroll
        for (int j = 0; j < WN; ++j) acc[i][j] += a[i] * b[j];
    }
    __syncthreads();
  }
  float bvv[WN];
#pragma unroll
  for (int j = 0; j < WN; ++j) bvv[j] = 0.f;
  if (bias) {
#pragma unroll
    for (int j4 = 0; j4 < WN / 4; ++j4) {
      float4 b4 = *reinterpret_cast<const float4*>(&bias[n0 + tx * WN + j4 * 4]);
      bvv[j4 * 4 + 0] = b4.x; bvv[j4 * 4 + 1] = b4.y;
      bvv[j4 * 4 + 2] = b4.z; bvv[j4 * 4 + 3] = b4.w;
    }
  }
#pragma unroll
  for (int i = 0; i < WM; ++i) {
    float* cp = &C[(size_t)(m0 + ty * WM + i) * ldc + n0 + tx * WN];
#pragma unroll
    for (int j4 = 0; j4 < WN / 4; ++j4) {
      float ov[4];
#pragma unroll
      for (int j = 0; j < 4; ++j) ov[j] = acc[i][j4 * 4 + j] + bvv[j4 * 4 + j];
      if (flags & 2) {
        float4 old = *reinterpret_cast<const float4*>(cp + j4 * 4);
        ov[0] += old.x; ov[1] += old.y; ov[2] += old.z; ov[3] += old.w;
      }
      if (flags & 1) {
#pragma unroll
        for (int j = 0; j < 4; ++j) ov[j] = fmaxf(ov[j], 0.0f);
      }
      float4 o;
      o.x = ov[0]; o.y = ov[1]; o.z = ov[2]; o.w = ov[3];
      *reinterpret_cast<float4*>(cp + j4 * 4) = o;
    }
  }
}

__global__ void k_zkld(const float* __restrict__ mu, const float* __restrict__ lsr,
                       const float* __restrict__ eps, const int* __restrict__ iftrain,
                       float* __restrict__ Z, Scal* sc) {
  int i = blockIdx.x * 256 + threadIdx.x;
  float m = mu[i];
  float ls = fminf(lsr[i], 10.0f);
  float z = (*iftrain > 0) ? m + eps[i] * __expf(ls) : m;
  Z[i] = z;
  float kt = 1.0f + 2.0f * ls - m * m - __expf(2.0f * ls);
  kt = waveReduceSum(kt);
  __shared__ float sh[4];
  int w = threadIdx.x >> 6;
  if ((threadIdx.x & 63) == 0) sh[w] = kt;
  __syncthreads();
  if (threadIdx.x == 0)
    atomicAdd(&sc->kld_sum, (double)(sh[0] + sh[1] + sh[2] + sh[3]));
}

__global__ __launch_bounds__(256) void k_struct(const float* __restrict__ Z,
                                                const float* __restrict__ adj,
                                                Scal* sc) {
  __shared__ float As[KC][LP];
  __shared__ float Bs[KC][LP];
  const int tid = threadIdx.x;
  const int tx = tid & 15, ty = tid >> 4;
  const int m0 = blockIdx.y * BM, n0 = blockIdx.x * BN;
  float acc[4][4] = {};
  for (int k0 = 0; k0 < kH; k0 += KC) {
#pragma unroll
    for (int i = 0; i < 2; ++i) {
      int q = tid + i * 256;
      int row = q >> 3, kq = q & 7;
      float4 va = *reinterpret_cast<const float4*>(
          &Z[(size_t)(m0 + row) * kH + k0 + kq * 4]);
      As[kq * 4 + 0][row] = va.x;
      As[kq * 4 + 1][row] = va.y;
      As[kq * 4 + 2][row] = va.z;
      As[kq * 4 + 3][row] = va.w;
      float4 vb = *reinterpret_cast<const float4*>(
          &Z[(size_t)(n0 + row) * kH + k0 + kq * 4]);
      Bs[kq * 4 + 0][row] = vb.x;
      Bs[kq * 4 + 1][row] = vb.y;
      Bs[kq * 4 + 2][row] = vb.z;
      Bs[kq * 4 + 3][row] = vb.w;
    }
    __syncthreads();
#pragma unroll
    for (int kk = 0; kk < KC; ++kk) {
      float4 a4 = *reinterpret_cast<const float4*>(&As[kk][ty * 4]);
      float4 b4 = *reinterpret_cast<const float4*>(&Bs[kk][tx * 4]);
      float av[4] = {a4.x, a4.y, a4.z, a4.w};
      float bv[4] = {b4.x, b4.y, b4.z, b4.w};
#pragma unroll
      for (int i = 0; i < 4; ++i)
#pragma unroll
        for (int j = 0; j < 4; ++j) acc[i][j] += av[i] * bv[j];
    }
    __syncthreads();
  }
  float Amin = sc->Amin, invr = sc->invr, c0v = sc->c0;
  float lsum = 0.f;
#pragma unroll
  for (int i = 0; i < 4; ++i) {
#pragma unroll
    for (int j = 0; j < 4; ++j) {
      int gi = m0 + ty * 4 + i, gj = n0 + tx * 4 + j;
      float l = acc[i][j];
      float adjv = c0v;
      if ((gi >> 8) == (gj >> 8))
        adjv = (adj[((size_t)(gi >> 8) << 16) + (gi & 255) * 256 + (gj & 255)] -
                Amin) * invr;
      lsum += fmaxf(l, 0.0f) - l * adjv + __logf(1.0f + __expf(-fabsf(l)));
    }
  }
  lsum = waveReduceSum(lsum);
  __shared__ float sh[4];
  int w = threadIdx.x >> 6;
  if ((threadIdx.x & 63) == 0) sh[w] = lsum;
  __syncthreads();
  if (threadIdx.x == 0)
    atomicAdd(&sc->struct_sum, (double)(sh[0] + sh[1] + sh[2] + sh[3]));
}

__global__ void k_x0(const float* __restrict__ gdl, const float* __restrict__ w3,
                     const float* __restrict__ b3, float* __restrict__ X) {
  int f = threadIdx.x;
  size_t r = (size_t)blockIdx.x * 2 + threadIdx.y;
  int n = (int)(r >> 7), h = (int)(r & 127);
  float a = b3[f];
#pragma unroll
  for (int o = 0; o < 8; ++o)
    a += gdl[((size_t)o * 256 + n) * 128 + h] * w3[f * 8 + o];
  X[r * 128 + f] = a;
}

// attention: one block per (head,b); 128 threads, 2 q-rows each (s, s+128).
// Single-pass online softmax with deferred rescale (threshold 8): rescale
// only when the new score beats the running max by >8, so the divergent
// rescale body almost never executes after warm-up.  Scale 1/4 folded into q.
__global__ __launch_bounds__(128) void k_attn(const float* __restrict__ QKV,
                                              float* __restrict__ O) {
  const int head = blockIdx.x, b = blockIdx.y;
  const int s = threadIdx.x;  // 0..127
  __shared__ float ks[256][16];
  __shared__ float vs[256][16];
#pragma unroll
  for (int rr = 0; rr < 2; ++rr) {
    int r = s + rr * 128;
    const size_t base = ((size_t)r * 128 + b) * 384 + head * 16;
#pragma unroll
    for (int i = 0; i < 4; ++i) {
      *reinterpret_cast<float4*>(&ks[r][i * 4]) =
          *reinterpret_cast<const float4*>(&QKV[base + 128 + i * 4]);
      *reinterpret_cast<float4*>(&vs[r][i * 4]) =
          *reinterpret_cast<const float4*>(&QKV[base + 256 + i * 4]);
    }
  }
  float q0[16], q1[16];
  {
    const size_t b0 = ((size_t)s * 128 + b) * 384 + head * 16;
    const size_t b1 = ((size_t)(s + 128) * 128 + b) * 384 + head * 16;
#pragma unroll
    for (int i = 0; i < 4; ++i) {
      float4 v0 = *reinterpret_cast<const float4*>(&QKV[b0 + i * 4]);
      float4 v1 = *reinterpret_cast<const float4*>(&QKV[b1 + i * 4]);
      q0[i * 4 + 0] = v0.x * 0.25f; q0[i * 4 + 1] = v0.y * 0.25f;
      q0[i * 4 + 2] = v0.z * 0.25f; q0[i * 4 + 3] = v0.w * 0.25f;
      q1[i * 4 + 0] = v1.x * 0.25f; q1[i * 4 + 1] = v1.y * 0.25f;
      q1[i * 4 + 2] = v1.z * 0.25f; q1[i * 4 + 3] = v1.w * 0.25f;
    }
  }
  __syncthreads();
  float m0 = -1e30f, m1 = -1e30f, l0 = 0.f, l1 = 0.f;
  float o0[16] = {}, o1[16] = {};
#pragma unroll 2
  for (int t = 0; t < 256; ++t) {
    float kv[16], vv[16];
#pragma unroll
    for (int i = 0; i < 4; ++i) {
      float4 k4 = *reinterpret_cast<const float4*>(&ks[t][i * 4]);
      float4 v4 = *reinterpret_cast<const float4*>(&vs[t][i * 4]);
      kv[i * 4 + 0] = k4.x; kv[i * 4 + 1] = k4.y;
      kv[i * 4 + 2] = k4.z; kv[i * 4 + 3] = k4.w;
      vv[i * 4 + 0] = v4.x; vv[i * 4 + 1] = v4.y;
      vv[i * 4 + 2] = v4.z; vv[i * 4 + 3] = v4.w;
    }
    float d0 = 0.f, d1 = 0.f;
#pragma unroll
    for (int i = 0; i < 16; ++i) {
      d0 += q0[i] * kv[i];
      d1 += q1[i] * kv[i];
    }
    if (d0 > m0 + 8.f) {
      float c = __expf(m0 - d0);
      l0 *= c;
#pragma unroll
      for (int i = 0; i < 16; ++i) o0[i] *= c;
      m0 = d0;
    }
    if (d1 > m1 + 8.f) {
      float c = __expf(m1 - d1);
      l1 *= c;
#pragma unroll
      for (int i = 0; i < 16; ++i) o1[i] *= c;
      m1 = d1;
    }
    float p0 = __expf(d0 - m0);
    float p1 = __expf(d1 - m1);
    l0 += p0;
    l1 += p1;
#pragma unroll
    for (int i = 0; i < 16; ++i) {
      o0[i] += p0 * vv[i];
      o1[i] += p1 * vv[i];
    }
  }
  float inv0 = 1.0f / l0, inv1 = 1.0f / l1;
  float* op0 = &O[((size_t)s * 128 + b) * 128 + head * 16];
  float* op1 = &O[((size_t)(s + 128) * 128 + b) * 128 + head * 16];
#pragma unroll
  for (int i = 0; i < 4; ++i) {
    float4 w0, w1;
    w0.x = o0[i * 4 + 0] * inv0; w0.y = o0[i * 4 + 1] * inv0;
    w0.z = o0[i * 4 + 2] * inv0; w0.w = o0[i * 4 + 3] * inv0;
    w1.x = o1[i * 4 + 0] * inv1; w1.y = o1[i * 4 + 1] * inv1;
    w1.z = o1[i * 4 + 2] * inv1; w1.w = o1[i * 4 + 3] * inv1;
    *reinterpret_cast<float4*>(&op0[i * 4]) = w0;
    *reinterpret_cast<float4*>(&op1[i * 4]) = w1;
  }
}

__global__ __launch_bounds__(256) void k_resid_ln(float* __restrict__ X,
                                                  const float* __restrict__ T,
                                                  const float* __restrict__ g,
                                                  const float* __restrict__ b) {
  int lane = threadIdx.x & 63, rl = threadIdx.x >> 6;
  size_t row = (size_t)blockIdx.x * 4 + rl;
  float* xp = X + row * 128;
  const float* tp = T + row * 128;
  float e0 = xp[lane] + tp[lane];
  float e1 = xp[lane + 64] + tp[lane + 64];
  float mean = waveReduceSum(e0 + e1) * 0.0078125f;
  float d0 = e0 - mean, d1 = e1 - mean;
  float var = waveReduceSum(d0 * d0 + d1 * d1) * 0.0078125f;
  float inv = 1.0f / sqrtf(var + 1e-5f);
  xp[lane] = d0 * inv * g[lane] + b[lane];
  xp[lane + 64] = d1 * inv * g[lane + 64] + b[lane + 64];
}

__global__ void k_heady(const float* __restrict__ X, const float* __restrict__ w4,
                        const float* __restrict__ b4, float* __restrict__ y) {
  int tid = threadIdx.x;
  int o = tid & 7, rl = tid >> 3;
  size_t r = (size_t)blockIdx.x * 32 + rl;
  const float* xp = X + r * 128;
  const float* wp = w4 + o * 128;
  float a = b4[o];
  for (int f = 0; f < 128; f += 4)
    a += xp[f] * wp[f] + xp[f + 1] * wp[f + 1] + xp[f + 2] * wp[f + 2] +
         xp[f + 3] * wp[f + 3];
  y[r * 8 + o] = a;
}

__global__ void k_traj(const float* __restrict__ y, const float* __restrict__ w5,
                       const float* __restrict__ b5,
                       const float* __restrict__ traj_in, float* __restrict__ dout,
                       Scal* sc) {
  int n = blockIdx.x, lane = threadIdx.x;
  float w0a = w5[lane], w0b = w5[lane + 64];
  float w1a = w5[128 + lane], w1b = w5[128 + lane + 64];
  float dsum = 0.f;
  for (int oi = 0; oi < 4; ++oi) {
    int o = 4 + oi;
    float ya = y[((size_t)n * 128 + lane) * 8 + o];
    float yb = y[((size_t)n * 128 + lane + 64) * 8 + o];
    float s0 = waveReduceSum(w0a * ya + w0b * yb);
    float s1 = waveReduceSum(w1a * ya + w1b * yb);
    if (lane == 0) {
      float t0 = s0 + b5[0], t1 = s1 + b5[1];
      dout[oi * 512 + n * 2 + 0] = t0;
      dout[oi * 512 + n * 2 + 1] = t1;
      float dx = t0 - traj_in[((8 + oi) * 256 + n) * 2 + 0];
      float dy = t1 - traj_in[((8 + oi) * 256 + n) * 2 + 1];
      dsum += sqrtf(dx * dx + dy * dy);
    }
  }
  if (lane == 0) atomicAdd(&sc->traj_sum, (double)dsum);
}

__global__ void k_loss(const Scal* sc, float* dout) {
  if (threadIdx.x == 0) {
    double traj_loss = sc->traj_sum / 256.0;
    double kld = -0.5 * sc->kld_sum / 2048.0;
    double st = sc->struct_sum / (2048.0 * 2048.0);
    dout[2048] = (float)(traj_loss + kld + st);
  }
}

}  // namespace

extern "C" void kernel_launch(void* const* d_in, const int* in_sizes, int n_in,
                              void* d_out, int out_size, void* d_ws,
                              size_t ws_size, hipStream_t stream) {
  (void)in_sizes; (void)n_in; (void)out_size; (void)ws_size;
  const float* traj_in = (const float*)d_in[0];
  const float* adj     = (const float*)d_in[1];
  const float* eps     = (const float*)d_in[2];
  const float* pro1_w  = (const float*)d_in[3];
  const float* pro1_b  = (const float*)d_in[4];
  const float* pro2_w  = (const float*)d_in[5];
  const float* pro2_b  = (const float*)d_in[6];
  const float* mu_w    = (const float*)d_in[7];
  const float* mu_b    = (const float*)d_in[8];
  const float* ls_w    = (const float*)d_in[9];
  const float* ls_b    = (const float*)d_in[10];
  const float* gdl_w   = (const float*)d_in[11];
  const float* gdl_b   = (const float*)d_in[12];
  const float* pro3_w  = (const float*)d_in[13];
  const float* pro3_b  = (const float*)d_in[14];
  const float* pro4_w  = (const float*)d_in[15];
  const float* pro4_b  = (const float*)d_in[16];
  const float* pro5_w  = (const float*)d_in[17];
  const float* pro5_b  = (const float*)d_in[18];
  const float* qkv_w   = (const float*)d_in[19];
  const float* qkv_b   = (const float*)d_in[20];
  const float* outp_w  = (const float*)d_in[21];
  const float* outp_b  = (const float*)d_in[22];
  const float* ff1_w   = (const float*)d_in[23];
  const float* ff1_b   = (const float*)d_in[24];
  const float* ff2_w   = (const float*)d_in[25];
  const float* ff2_b   = (const float*)d_in[26];
  const float* ln1_g   = (const float*)d_in[27];
  const float* ln1_b   = (const float*)d_in[28];
  const float* ln2_g   = (const float*)d_in[29];
  const float* ln2_b   = (const float*)d_in[30];
  const int*   iftrain = (const int*)d_in[31];
  float* dout = (float*)d_out;

  char* wsb = (char*)d_ws;
  size_t off = 0;
  auto alloc = [&](size_t floats) {
    float* p = (float*)(wsb + off);
    off += ((floats * 4 + 255) / 256) * 256;
    return p;
  };
  Scal* sc   = (Scal*)alloc(64);
  float* dis = alloc(kGN);
  float* agg = alloc((size_t)kOBS * 65536);
  float* enc1 = alloc((size_t)kGN * kH);
  float* enc  = alloc((size_t)kGN * kH);
  float* Mmu  = alloc((size_t)kGN * kH);
  float* Mls  = alloc((size_t)kGN * kH);
  float* mu   = alloc((size_t)kGN * kH);
  float* lsb  = alloc((size_t)kGN * kH);
  float* Z    = alloc((size_t)kGN * kH);
  float* gdl  = alloc((size_t)kGN * kH);
  float* X    = alloc((size_t)kROWS * kH);
  float* QKV  = alloc((size_t)kROWS * 3 * kH);
  float* O    = alloc((size_t)kROWS * kH);
  float* tmp  = alloc((size_t)kROWS * kH);
  float* Fs   = alloc((size_t)kROWS * kFFCH);
  float* y    = alloc((size_t)kROWS * 8);

  auto gemm_nt_small = [&](const float* A, const float* B, const float* bias,
                           float* C, int M, int N, int K, int ldb, int ldc,
                           int flags) {
    dim3 g(N / 64, M / 64, 1);
    gemm_kernel<true><<<g, 256, 0, stream>>>(A, B, bias, C, K, ldb, ldc, flags,
                                             (size_t)0, (size_t)0, (size_t)0);
  };

  k_init<<<1, 64, 0, stream>>>(sc);
  k_minmax<<<512, 256, 0, stream>>>(adj, kOBS * kNAG * kNAG, sc);
  k_scale<<<1, 1, 0, stream>>>(sc);
  k_dis<<<8, 256, 0, stream>>>(adj, sc, dis);
  k_agg<<<2048, 256, 0, stream>>>(adj, sc, dis, agg);

  k_enc1<<<(kGN * kH) / 256, 256, 0, stream>>>(traj_in, pro1_w, pro1_b, enc1);
  gemm_nt_small(enc1, pro2_w, pro2_b, enc, kGN, kH, kH, kH, kH, 0);
  gemm_nt_small(enc, mu_w, mu_b, Mmu, kGN, kH, kH, kH, kH, 0);
  gemm_nt_small(enc, ls_w, ls_b, Mls, kGN, kH, kH, kH, kH, 0);
  {
    dim3 g(kH / 64, kNAG / 64, kOBS);
    gemm_kernel<false><<<g, 256, 0, stream>>>(agg, Mmu, nullptr, mu, kNAG, kH,
                                              kH, 0, (size_t)65536,
                                              (size_t)kNAG * kH, (size_t)kNAG * kH);
    gemm_kernel<false><<<g, 256, 0, stream>>>(agg, Mls, nullptr, lsb, kNAG, kH,
                                              kH, 0, (size_t)65536,
                                              (size_t)kNAG * kH, (size_t)kNAG * kH);
  }
  k_zkld<<<(kGN * kH) / 256, 256, 0, stream>>>(mu, lsb, eps, iftrain, Z, sc);
  gemm_nt_small(Z, gdl_w, gdl_b, gdl, kGN, kH, kH, kH, kH, 0);
  k_struct<<<dim3(kGN / 64, kGN / 64), 256, 0, stream>>>(Z, adj, sc);
  k_x0<<<kROWS / 2, dim3(128, 2), 0, stream>>>(gdl, pro3_w, pro3_b, X);

  for (int l = 0; l < 6; ++l) {
    // qkv: (32768,384) = X @ Wqkv^T
    gemm_big<true, 128, 128, 8, 8><<<dim3(3, 256), 256, 0, stream>>>(
        X, qkv_w + (size_t)l * 384 * kH, qkv_b + l * 384, QKV, kH, kH, 384, 0);
    k_attn<<<dim3(8, 128), 128, 0, stream>>>(QKV, O);
    // out-proj: (32768,128)
    gemm_big<true, 128, 64, 8, 4><<<dim3(2, 256), 256, 0, stream>>>(
        O, outp_w + (size_t)l * kH * kH, outp_b + l * kH, tmp, kH, kH, kH, 0);
    k_resid_ln<<<kROWS / 4, 256, 0, stream>>>(X, tmp, ln1_g + l * kH,
                                              ln1_b + l * kH);
    for (int c = 0; c < kNCH; ++c) {
      // ff1 chunk: (32768,512) relu
      gemm_big<true, 128, 128, 8, 8><<<dim3(4, 256), 256, 0, stream>>>(
          X, ff1_w + (size_t)l * 2048 * kH + (size_t)c * kFFCH * kH,
          ff1_b + l * 2048 + c * kFFCH, Fs, kH, kH, kFFCH, 1 /*relu*/);
      // ff2 chunk: (32768,128), K=512, accumulate
      gemm_big<true, 128, 64, 8, 4><<<dim3(2, 256), 256, 0, stream>>>(
          Fs, ff2_w + (size_t)l * kH * 2048 + c * kFFCH,
          (c == 0 ? ff2_b + l * kH : nullptr), tmp, kFFCH, 2048, kH,
          (c == 0 ? 0 : 2 /*acc*/));
    }
    k_resid_ln<<<kROWS / 4, 256, 0, stream>>>(X, tmp, ln2_g + l * kH,
                                              ln2_b + l * kH);
  }

  k_heady<<<kROWS / 32, 256, 0, stream>>>(X, pro4_w, pro4_b, y);
  k_traj<<<kNAG, 64, 0, stream>>>(y, pro5_w, pro5_b, traj_in, dout, sc);
  k_loss<<<1, 1, 0, stream>>>(sc, dout);
}

// Round 3
// 3069.786 us; speedup vs baseline: 1.5634x; 1.5244x over previous
//
#include <hip/hip_runtime.h>
#include <math.h>

// GVAE-Transformer forward. fp32 interfaces; transformer GEMMs run on MFMA
// via split-bf16 (3-term Ootomo: ah*bh + ah*bl + al*bh, fp32 accumulate).
// Shapes: OBS=8 PRED=4 NAG=256 FIN=2 FOUT=2 H=128 NH=8 FF=2048 NL=6.
//
// R3 changes vs R2 (4679 us):
//  - gemm_mfma: 128x128 tile, BK=32, 4 waves (2x2), 64x64/wave via 4x4
//    mfma_f32_16x16x32_bf16 frags, on-the-fly fp32->bf16 hi/lo staging.
//    Replaces the fp32 gemm_big for qkv / attn-out / ff1 / ff2.
//  - k_attn: back to 256 threads (1 q-row/thread) + online softmax with
//    deferred rescale (R2's 128-thr version halved occupancy: 47% VALUBusy).

namespace {

constexpr int kOBS = 8, kNAG = 256, kH = 128, kFFCH = 512, kNCH = 4;
constexpr int kGN = kOBS * kNAG;   // 2048 graph nodes
constexpr int kROWS = kNAG * kH;   // 32768 transformer rows (S=256, B=128)

typedef __attribute__((ext_vector_type(8))) short bf16x8;
typedef __attribute__((ext_vector_type(4))) float f32x4;
typedef __attribute__((ext_vector_type(4))) unsigned short us4;

struct Scal {
  int    mn_bits;
  int    mx_bits;
  float  Amin;
  float  invr;
  float  c0;
  int    pad;
  double kld_sum;
  double struct_sum;
  double traj_sum;
};

__device__ inline float waveReduceSum(float v) {
#pragma unroll
  for (int off = 32; off; off >>= 1) v += __shfl_xor(v, off, 64);
  return v;
}

__device__ inline unsigned short f2bf(float f) {  // RNE fp32 -> bf16
  unsigned u = __float_as_uint(f);
  return (unsigned short)((u + 0x7fffu + ((u >> 16) & 1u)) >> 16);
}
__device__ inline float bf2f(unsigned short h) {
  return __uint_as_float((unsigned)h << 16);
}

__global__ void k_init(Scal* sc) {
  if (threadIdx.x == 0) {
    sc->mn_bits = 0x7f800000;
    sc->mx_bits = 0xff800000;
    sc->kld_sum = 0.0;
    sc->struct_sum = 0.0;
    sc->traj_sum = 0.0;
  }
}

__global__ void k_minmax(const float* __restrict__ adj, int n, Scal* sc) {
  float lmin = INFINITY, lmax = -INFINITY;
  for (int i = blockIdx.x * blockDim.x + threadIdx.x; i < n;
       i += gridDim.x * blockDim.x) {
    float v = adj[i];
    lmin = fminf(lmin, v);
    lmax = fmaxf(lmax, v);
  }
#pragma unroll
  for (int off = 32; off; off >>= 1) {
    lmin = fminf(lmin, __shfl_xor(lmin, off, 64));
    lmax = fmaxf(lmax, __shfl_xor(lmax, off, 64));
  }
  __shared__ float smn[4], smx[4];
  int w = threadIdx.x >> 6;
  if ((threadIdx.x & 63) == 0) { smn[w] = lmin; smx[w] = lmax; }
  __syncthreads();
  if (threadIdx.x == 0) {
    lmin = fminf(fminf(smn[0], smn[1]), fminf(smn[2], smn[3]));
    lmax = fmaxf(fmaxf(smx[0], smx[1]), fmaxf(smx[2], smx[3]));
    atomicMin(&sc->mn_bits, __float_as_int(lmin));
    atomicMax(&sc->mx_bits, __float_as_int(lmax));
  }
}

__global__ void k_scale(Scal* sc) {
  float mn = fminf(0.0f, __int_as_float(sc->mn_bits));
  float mx = fmaxf(0.0f, __int_as_float(sc->mx_bits));
  sc->Amin = mn;
  sc->invr = 1.0f / (mx - mn);
  sc->c0 = (0.0f - mn) * sc->invr;
}

__global__ void k_dis(const float* __restrict__ adj, const Scal* __restrict__ sc,
                      float* __restrict__ dis) {
  int j = blockIdx.x * 256 + threadIdx.x;
  int t = j >> 8, jj = j & 255;
  const float* a = adj + (size_t)t * 65536;
  float Amin = sc->Amin, invr = sc->invr, c0 = sc->c0;
  float sum = 0.f;
  for (int i = 0; i < 256; ++i) sum += (a[i * 256 + jj] - Amin) * invr;
  float djj = (a[jj * 256 + jj] - Amin) * invr;
  float deg = sum + 1792.0f * c0 + (djj == 0.0f ? 1.0f : 0.0f);
  dis[j] = deg > 0.0f ? 1.0f / sqrtf(deg) : 0.0f;
}

__global__ void k_agg(const float* __restrict__ adj, const Scal* __restrict__ sc,
                      const float* __restrict__ dis, float* __restrict__ agg) {
  int idx = blockIdx.x * 256 + threadIdx.x;
  int t = idx >> 16, i = (idx >> 8) & 255, j = idx & 255;
  float v = (adj[(size_t)t * 65536 + j * 256 + i] - sc->Amin) * sc->invr;
  if (i == j && v == 0.0f) v += 1.0f;
  agg[idx] = dis[t * 256 + j] * v * dis[t * 256 + i];
}

__global__ void k_enc1(const float* __restrict__ traj, const float* __restrict__ w,
                       const float* __restrict__ b, float* __restrict__ out) {
  int idx = blockIdx.x * 256 + threadIdx.x;
  int r = idx >> 7, f = idx & 127;
  float v = traj[r * 2] * w[f * 2] + traj[r * 2 + 1] * w[f * 2 + 1] + b[f];
  out[idx] = fmaxf(v, 0.0f);
}

// ---------------- small fp32 GEMM (front-end, M=2048) ----------------
#define BM 64
#define BN 64
#define KC 32
#define LP 68

template <bool TB>
__global__ __launch_bounds__(256) void gemm_kernel(
    const float* __restrict__ A, const float* __restrict__ B,
    const float* __restrict__ bias, float* __restrict__ C, int K, int ldb,
    int ldc, int flags, size_t aStride, size_t bStride, size_t cStride) {
  if (blockIdx.z) {
    A += (size_t)blockIdx.z * aStride;
    B += (size_t)blockIdx.z * bStride;
    C += (size_t)blockIdx.z * cStride;
  }
  __shared__ float As[KC][LP];
  __shared__ float Bs[KC][LP];
  const int tid = threadIdx.x;
  const int tx = tid & 15, ty = tid >> 4;
  const int m0 = blockIdx.y * BM, n0 = blockIdx.x * BN;
  float acc[4][4] = {};
  for (int k0 = 0; k0 < K; k0 += KC) {
#pragma unroll
    for (int i = 0; i < 2; ++i) {
      int q = tid + i * 256;
      int row = q >> 3, kq = q & 7;
      float4 v = *reinterpret_cast<const float4*>(
          &A[(size_t)(m0 + row) * K + k0 + kq * 4]);
      As[kq * 4 + 0][row] = v.x;
      As[kq * 4 + 1][row] = v.y;
      As[kq * 4 + 2][row] = v.z;
      As[kq * 4 + 3][row] = v.w;
    }
    if (TB) {
#pragma unroll
      for (int i = 0; i < 2; ++i) {
        int q = tid + i * 256;
        int row = q >> 3, kq = q & 7;
        float4 v = *reinterpret_cast<const float4*>(
            &B[(size_t)(n0 + row) * ldb + k0 + kq * 4]);
        Bs[kq * 4 + 0][row] = v.x;
        Bs[kq * 4 + 1][row] = v.y;
        Bs[kq * 4 + 2][row] = v.z;
        Bs[kq * 4 + 3][row] = v.w;
      }
    } else {
#pragma unroll
      for (int i = 0; i < 2; ++i) {
        int q = tid + i * 256;
        int kr = q >> 4, nq = q & 15;
        float4 v = *reinterpret_cast<const float4*>(
            &B[(size_t)(k0 + kr) * ldb + n0 + nq * 4]);
        *reinterpret_cast<float4*>(&Bs[kr][nq * 4]) = v;
      }
    }
    __syncthreads();
#pragma unroll
    for (int kk = 0; kk < KC; ++kk) {
      float4 a4 = *reinterpret_cast<const float4*>(&As[kk][ty * 4]);
      float4 b4 = *reinterpret_cast<const float4*>(&Bs[kk][tx * 4]);
      float av[4] = {a4.x, a4.y, a4.z, a4.w};
      float bv[4] = {b4.x, b4.y, b4.z, b4.w};
#pragma unroll
      for (int i = 0; i < 4; ++i)
#pragma unroll
        for (int j = 0; j < 4; ++j) acc[i][j] += av[i] * bv[j];
    }
    __syncthreads();
  }
  float bv[4] = {0.f, 0.f, 0.f, 0.f};
  if (bias) {
    float4 b4 = *reinterpret_cast<const float4*>(&bias[n0 + tx * 4]);
    bv[0] = b4.x; bv[1] = b4.y; bv[2] = b4.z; bv[3] = b4.w;
  }
#pragma unroll
  for (int i = 0; i < 4; ++i) {
    float* cp = &C[(size_t)(m0 + ty * 4 + i) * ldc + n0 + tx * 4];
    float4 o;
    float ov[4];
#pragma unroll
    for (int j = 0; j < 4; ++j) ov[j] = acc[i][j] + bv[j];
    if (flags & 2) {
      float4 old = *reinterpret_cast<const float4*>(cp);
      ov[0] += old.x; ov[1] += old.y; ov[2] += old.z; ov[3] += old.w;
    }
    if (flags & 1) {
#pragma unroll
      for (int j = 0; j < 4; ++j) ov[j] = fmaxf(ov[j], 0.0f);
    }
    o.x = ov[0]; o.y = ov[1]; o.z = ov[2]; o.w = ov[3];
    *reinterpret_cast<float4*>(cp) = o;
  }
}

// ---------------- MFMA split-bf16 GEMM (transformer, M=32768) ----------------
// C(M,N) = A(M,K) @ B(N,K)^T + bias.  A,B,C fp32 in global; A/B converted to
// bf16 hi/lo during LDS staging (RNE).  Tile 128x128, BK=32, 256 thr = 4 waves
// (2x2), wave tile 64x64 = 4x4 frags of mfma_f32_16x16x32_bf16, 3 MFMA/frag
// (ah*bh + ah*bl + al*bh).  LDS rows padded to 40 bf16 (80B) -> <=2-way extra
// aliasing on ds_read_b128 fragment reads.  flags: 1=relu 2=acc(+=C).
__global__ __launch_bounds__(256) void gemm_mfma(
    const float* __restrict__ A, const float* __restrict__ B,
    const float* __restrict__ bias, float* __restrict__ C, int K, int ldb,
    int ldc, int flags) {
  __shared__ unsigned short Ah[128 * 40], Al[128 * 40];
  __shared__ unsigned short Bh[128 * 40], Bl[128 * 40];
  const int tid = threadIdx.x;
  const int lane = tid & 63, w = tid >> 6;
  const int wr = w >> 1, wc = w & 1;
  const int m0 = blockIdx.y * 128, n0 = blockIdx.x * 128;
  f32x4 acc[4][4];
#pragma unroll
  for (int i = 0; i < 4; ++i)
#pragma unroll
    for (int j = 0; j < 4; ++j) acc[i][j] = (f32x4){0.f, 0.f, 0.f, 0.f};

  for (int k0 = 0; k0 < K; k0 += 32) {
    // stage A and B tiles (128x32 each) as bf16 hi/lo
#pragma unroll
    for (int i = 0; i < 4; ++i) {
      int idx = tid + i * 256;          // 0..1023
      int row = idx >> 3, k4 = idx & 7; // row 0..127, k4 0..7 (4 floats each)
      float4 va = *reinterpret_cast<const float4*>(
          &A[(size_t)(m0 + row) * K + k0 + k4 * 4]);
      us4 h, l;
      h.x = f2bf(va.x); l.x = f2bf(va.x - bf2f(h.x));
      h.y = f2bf(va.y); l.y = f2bf(va.y - bf2f(h.y));
      h.z = f2bf(va.z); l.z = f2bf(va.z - bf2f(h.z));
      h.w = f2bf(va.w); l.w = f2bf(va.w - bf2f(h.w));
      *reinterpret_cast<us4*>(&Ah[row * 40 + k4 * 4]) = h;
      *reinterpret_cast<us4*>(&Al[row * 40 + k4 * 4]) = l;
      float4 vb = *reinterpret_cast<const float4*>(
          &B[(size_t)(n0 + row) * ldb + k0 + k4 * 4]);
      h.x = f2bf(vb.x); l.x = f2bf(vb.x - bf2f(h.x));
      h.y = f2bf(vb.y); l.y = f2bf(vb.y - bf2f(h.y));
      h.z = f2bf(vb.z); l.z = f2bf(vb.z - bf2f(h.z));
      h.w = f2bf(vb.w); l.w = f2bf(vb.w - bf2f(h.w));
      *reinterpret_cast<us4*>(&Bh[row * 40 + k4 * 4]) = h;
      *reinterpret_cast<us4*>(&Bl[row * 40 + k4 * 4]) = l;
    }
    __syncthreads();
    // fragment reads + MFMAs.  A-frag: row=lane&15 (+16*mi), k=(lane>>4)*8+i.
    bf16x8 bh[4], bl[4];
#pragma unroll
    for (int ni = 0; ni < 4; ++ni) {
      int off = (wc * 64 + ni * 16 + (lane & 15)) * 40 + (lane >> 4) * 8;
      bh[ni] = *reinterpret_cast<const bf16x8*>(&Bh[off]);
      bl[ni] = *reinterpret_cast<const bf16x8*>(&Bl[off]);
    }
#pragma unroll
    for (int mi = 0; mi < 4; ++mi) {
      int off = (wr * 64 + mi * 16 + (lane & 15)) * 40 + (lane >> 4) * 8;
      bf16x8 ah = *reinterpret_cast<const bf16x8*>(&Ah[off]);
      bf16x8 al = *reinterpret_cast<const bf16x8*>(&Al[off]);
#pragma unroll
      for (int ni = 0; ni < 4; ++ni) {
        acc[mi][ni] = __builtin_amdgcn_mfma_f32_16x16x32_bf16(
            ah, bh[ni], acc[mi][ni], 0, 0, 0);
        acc[mi][ni] = __builtin_amdgcn_mfma_f32_16x16x32_bf16(
            ah, bl[ni], acc[mi][ni], 0, 0, 0);
        acc[mi][ni] = __builtin_amdgcn_mfma_f32_16x16x32_bf16(
            al, bh[ni], acc[mi][ni], 0, 0, 0);
      }
    }
    __syncthreads();
  }
  // epilogue: C row = m0+wr*64+mi*16+(lane>>4)*4+r, col = n0+wc*64+ni*16+(lane&15)
  const int crow0 = m0 + wr * 64 + (lane >> 4) * 4;
  const int ccol0 = n0 + wc * 64 + (lane & 15);
#pragma unroll
  for (int ni = 0; ni < 4; ++ni) {
    int col = ccol0 + ni * 16;
    float bv = bias ? bias[col] : 0.f;
#pragma unroll
    for (int mi = 0; mi < 4; ++mi) {
#pragma unroll
      for (int r = 0; r < 4; ++r) {
        int row = crow0 + mi * 16 + r;
        float* cp = &C[(size_t)row * ldc + col];
        float v = acc[mi][ni][r] + bv;
        if (flags & 2) v += *cp;
        if (flags & 1) v = fmaxf(v, 0.0f);
        *cp = v;
      }
    }
  }
}

__global__ void k_zkld(const float* __restrict__ mu, const float* __restrict__ lsr,
                       const float* __restrict__ eps, const int* __restrict__ iftrain,
                       float* __restrict__ Z, Scal* sc) {
  int i = blockIdx.x * 256 + threadIdx.x;
  float m = mu[i];
  float ls = fminf(lsr[i], 10.0f);
  float z = (*iftrain > 0) ? m + eps[i] * __expf(ls) : m;
  Z[i] = z;
  float kt = 1.0f + 2.0f * ls - m * m - __expf(2.0f * ls);
  kt = waveReduceSum(kt);
  __shared__ float sh[4];
  int w = threadIdx.x >> 6;
  if ((threadIdx.x & 63) == 0) sh[w] = kt;
  __syncthreads();
  if (threadIdx.x == 0)
    atomicAdd(&sc->kld_sum, (double)(sh[0] + sh[1] + sh[2] + sh[3]));
}

__global__ __launch_bounds__(256) void k_struct(const float* __restrict__ Z,
                                                const float* __restrict__ adj,
                                                Scal* sc) {
  __shared__ float As[KC][LP];
  __shared__ float Bs[KC][LP];
  const int tid = threadIdx.x;
  const int tx = tid & 15, ty = tid >> 4;
  const int m0 = blockIdx.y * BM, n0 = blockIdx.x * BN;
  float acc[4][4] = {};
  for (int k0 = 0; k0 < kH; k0 += KC) {
#pragma unroll
    for (int i = 0; i < 2; ++i) {
      int q = tid + i * 256;
      int row = q >> 3, kq = q & 7;
      float4 va = *reinterpret_cast<const float4*>(
          &Z[(size_t)(m0 + row) * kH + k0 + kq * 4]);
      As[kq * 4 + 0][row] = va.x;
      As[kq * 4 + 1][row] = va.y;
      As[kq * 4 + 2][row] = va.z;
      As[kq * 4 + 3][row] = va.w;
      float4 vb = *reinterpret_cast<const float4*>(
          &Z[(size_t)(n0 + row) * kH + k0 + kq * 4]);
      Bs[kq * 4 + 0][row] = vb.x;
      Bs[kq * 4 + 1][row] = vb.y;
      Bs[kq * 4 + 2][row] = vb.z;
      Bs[kq * 4 + 3][row] = vb.w;
    }
    __syncthreads();
#pragma unroll
    for (int kk = 0; kk < KC; ++kk) {
      float4 a4 = *reinterpret_cast<const float4*>(&As[kk][ty * 4]);
      float4 b4 = *reinterpret_cast<const float4*>(&Bs[kk][tx * 4]);
      float av[4] = {a4.x, a4.y, a4.z, a4.w};
      float bv[4] = {b4.x, b4.y, b4.z, b4.w};
#pragma unroll
      for (int i = 0; i < 4; ++i)
#pragma unroll
        for (int j = 0; j < 4; ++j) acc[i][j] += av[i] * bv[j];
    }
    __syncthreads();
  }
  float Amin = sc->Amin, invr = sc->invr, c0v = sc->c0;
  float lsum = 0.f;
#pragma unroll
  for (int i = 0; i < 4; ++i) {
#pragma unroll
    for (int j = 0; j < 4; ++j) {
      int gi = m0 + ty * 4 + i, gj = n0 + tx * 4 + j;
      float l = acc[i][j];
      float adjv = c0v;
      if ((gi >> 8) == (gj >> 8))
        adjv = (adj[((size_t)(gi >> 8) << 16) + (gi & 255) * 256 + (gj & 255)] -
                Amin) * invr;
      lsum += fmaxf(l, 0.0f) - l * adjv + __logf(1.0f + __expf(-fabsf(l)));
    }
  }
  lsum = waveReduceSum(lsum);
  __shared__ float sh[4];
  int w = threadIdx.x >> 6;
  if ((threadIdx.x & 63) == 0) sh[w] = lsum;
  __syncthreads();
  if (threadIdx.x == 0)
    atomicAdd(&sc->struct_sum, (double)(sh[0] + sh[1] + sh[2] + sh[3]));
}

__global__ void k_x0(const float* __restrict__ gdl, const float* __restrict__ w3,
                     const float* __restrict__ b3, float* __restrict__ X) {
  int f = threadIdx.x;
  size_t r = (size_t)blockIdx.x * 2 + threadIdx.y;
  int n = (int)(r >> 7), h = (int)(r & 127);
  float a = b3[f];
#pragma unroll
  for (int o = 0; o < 8; ++o)
    a += gdl[((size_t)o * 256 + n) * 128 + h] * w3[f * 8 + o];
  X[r * 128 + f] = a;
}

// attention: one block per (head,b); 256 threads, 1 q-row each.  Single-pass
// online softmax w/ deferred rescale (THR=8).  Scale 1/4 folded into q.
__global__ __launch_bounds__(256) void k_attn(const float* __restrict__ QKV,
                                              float* __restrict__ O) {
  const int head = blockIdx.x, b = blockIdx.y;
  const int s = threadIdx.x;  // 0..255
  __shared__ float ks[256][16];
  __shared__ float vs[256][16];
  const size_t base = ((size_t)s * 128 + b) * 384 + head * 16;
#pragma unroll
  for (int i = 0; i < 4; ++i) {
    *reinterpret_cast<float4*>(&ks[s][i * 4]) =
        *reinterpret_cast<const float4*>(&QKV[base + 128 + i * 4]);
    *reinterpret_cast<float4*>(&vs[s][i * 4]) =
        *reinterpret_cast<const float4*>(&QKV[base + 256 + i * 4]);
  }
  float q[16];
#pragma unroll
  for (int i = 0; i < 4; ++i) {
    float4 v = *reinterpret_cast<const float4*>(&QKV[base + i * 4]);
    q[i * 4 + 0] = v.x * 0.25f; q[i * 4 + 1] = v.y * 0.25f;
    q[i * 4 + 2] = v.z * 0.25f; q[i * 4 + 3] = v.w * 0.25f;
  }
  __syncthreads();
  float m = -1e30f, lsum = 0.f;
  float o[16] = {};
#pragma unroll 2
  for (int t = 0; t < 256; ++t) {
    float kv[16], vv[16];
#pragma unroll
    for (int i = 0; i < 4; ++i) {
      float4 k4 = *reinterpret_cast<const float4*>(&ks[t][i * 4]);
      float4 v4 = *reinterpret_cast<const float4*>(&vs[t][i * 4]);
      kv[i * 4 + 0] = k4.x; kv[i * 4 + 1] = k4.y;
      kv[i * 4 + 2] = k4.z; kv[i * 4 + 3] = k4.w;
      vv[i * 4 + 0] = v4.x; vv[i * 4 + 1] = v4.y;
      vv[i * 4 + 2] = v4.z; vv[i * 4 + 3] = v4.w;
    }
    float d = 0.f;
#pragma unroll
    for (int i = 0; i < 16; ++i) d += q[i] * kv[i];
    if (d > m + 8.f) {            // deferred rescale (T13)
      float c = __expf(m - d);
      lsum *= c;
#pragma unroll
      for (int i = 0; i < 16; ++i) o[i] *= c;
      m = d;
    }
    float p = __expf(d - m);
    lsum += p;
#pragma unroll
    for (int i = 0; i < 16; ++i) o[i] += p * vv[i];
  }
  float inv = 1.0f / lsum;
  float* op = &O[((size_t)s * 128 + b) * 128 + head * 16];
#pragma unroll
  for (int i = 0; i < 4; ++i) {
    float4 v;
    v.x = o[i * 4 + 0] * inv; v.y = o[i * 4 + 1] * inv;
    v.z = o[i * 4 + 2] * inv; v.w = o[i * 4 + 3] * inv;
    *reinterpret_cast<float4*>(&op[i * 4]) = v;
  }
}

__global__ __launch_bounds__(256) void k_resid_ln(float* __restrict__ X,
                                                  const float* __restrict__ T,
                                                  const float* __restrict__ g,
                                                  const float* __restrict__ b) {
  int lane = threadIdx.x & 63, rl = threadIdx.x >> 6;
  size_t row = (size_t)blockIdx.x * 4 + rl;
  float* xp = X + row * 128;
  const float* tp = T + row * 128;
  float e0 = xp[lane] + tp[lane];
  float e1 = xp[lane + 64] + tp[lane + 64];
  float mean = waveReduceSum(e0 + e1) * 0.0078125f;
  float d0 = e0 - mean, d1 = e1 - mean;
  float var = waveReduceSum(d0 * d0 + d1 * d1) * 0.0078125f;
  float inv = 1.0f / sqrtf(var + 1e-5f);
  xp[lane] = d0 * inv * g[lane] + b[lane];
  xp[lane + 64] = d1 * inv * g[lane + 64] + b[lane + 64];
}

__global__ void k_heady(const float* __restrict__ X, const float* __restrict__ w4,
                        const float* __restrict__ b4, float* __restrict__ y) {
  int tid = threadIdx.x;
  int o = tid & 7, rl = tid >> 3;
  size_t r = (size_t)blockIdx.x * 32 + rl;
  const float* xp = X + r * 128;
  const float* wp = w4 + o * 128;
  float a = b4[o];
  for (int f = 0; f < 128; f += 4)
    a += xp[f] * wp[f] + xp[f + 1] * wp[f + 1] + xp[f + 2] * wp[f + 2] +
         xp[f + 3] * wp[f + 3];
  y[r * 8 + o] = a;
}

__global__ void k_traj(const float* __restrict__ y, const float* __restrict__ w5,
                       const float* __restrict__ b5,
                       const float* __restrict__ traj_in, float* __restrict__ dout,
                       Scal* sc) {
  int n = blockIdx.x, lane = threadIdx.x;
  float w0a = w5[lane], w0b = w5[lane + 64];
  float w1a = w5[128 + lane], w1b = w5[128 + lane + 64];
  float dsum = 0.f;
  for (int oi = 0; oi < 4; ++oi) {
    int o = 4 + oi;
    float ya = y[((size_t)n * 128 + lane) * 8 + o];
    float yb = y[((size_t)n * 128 + lane + 64) * 8 + o];
    float s0 = waveReduceSum(w0a * ya + w0b * yb);
    float s1 = waveReduceSum(w1a * ya + w1b * yb);
    if (lane == 0) {
      float t0 = s0 + b5[0], t1 = s1 + b5[1];
      dout[oi * 512 + n * 2 + 0] = t0;
      dout[oi * 512 + n * 2 + 1] = t1;
      float dx = t0 - traj_in[((8 + oi) * 256 + n) * 2 + 0];
      float dy = t1 - traj_in[((8 + oi) * 256 + n) * 2 + 1];
      dsum += sqrtf(dx * dx + dy * dy);
    }
  }
  if (lane == 0) atomicAdd(&sc->traj_sum, (double)dsum);
}

__global__ void k_loss(const Scal* sc, float* dout) {
  if (threadIdx.x == 0) {
    double traj_loss = sc->traj_sum / 256.0;
    double kld = -0.5 * sc->kld_sum / 2048.0;
    double st = sc->struct_sum / (2048.0 * 2048.0);
    dout[2048] = (float)(traj_loss + kld + st);
  }
}

}  // namespace

extern "C" void kernel_launch(void* const* d_in, const int* in_sizes, int n_in,
                              void* d_out, int out_size, void* d_ws,
                              size_t ws_size, hipStream_t stream) {
  (void)in_sizes; (void)n_in; (void)out_size; (void)ws_size;
  const float* traj_in = (const float*)d_in[0];
  const float* adj     = (const float*)d_in[1];
  const float* eps     = (const float*)d_in[2];
  const float* pro1_w  = (const float*)d_in[3];
  const float* pro1_b  = (const float*)d_in[4];
  const float* pro2_w  = (const float*)d_in[5];
  const float* pro2_b  = (const float*)d_in[6];
  const float* mu_w    = (const float*)d_in[7];
  const float* mu_b    = (const float*)d_in[8];
  const float* ls_w    = (const float*)d_in[9];
  const float* ls_b    = (const float*)d_in[10];
  const float* gdl_w   = (const float*)d_in[11];
  const float* gdl_b   = (const float*)d_in[12];
  const float* pro3_w  = (const float*)d_in[13];
  const float* pro3_b  = (const float*)d_in[14];
  const float* pro4_w  = (const float*)d_in[15];
  const float* pro4_b  = (const float*)d_in[16];
  const float* pro5_w  = (const float*)d_in[17];
  const float* pro5_b  = (const float*)d_in[18];
  const float* qkv_w   = (const float*)d_in[19];
  const float* qkv_b   = (const float*)d_in[20];
  const float* outp_w  = (const float*)d_in[21];
  const float* outp_b  = (const float*)d_in[22];
  const float* ff1_w   = (const float*)d_in[23];
  const float* ff1_b   = (const float*)d_in[24];
  const float* ff2_w   = (const float*)d_in[25];
  const float* ff2_b   = (const float*)d_in[26];
  const float* ln1_g   = (const float*)d_in[27];
  const float* ln1_b   = (const float*)d_in[28];
  const float* ln2_g   = (const float*)d_in[29];
  const float* ln2_b   = (const float*)d_in[30];
  const int*   iftrain = (const int*)d_in[31];
  float* dout = (float*)d_out;

  char* wsb = (char*)d_ws;
  size_t off = 0;
  auto alloc = [&](size_t floats) {
    float* p = (float*)(wsb + off);
    off += ((floats * 4 + 255) / 256) * 256;
    return p;
  };
  Scal* sc   = (Scal*)alloc(64);
  float* dis = alloc(kGN);
  float* agg = alloc((size_t)kOBS * 65536);
  float* enc1 = alloc((size_t)kGN * kH);
  float* enc  = alloc((size_t)kGN * kH);
  float* Mmu  = alloc((size_t)kGN * kH);
  float* Mls  = alloc((size_t)kGN * kH);
  float* mu   = alloc((size_t)kGN * kH);
  float* lsb  = alloc((size_t)kGN * kH);
  float* Z    = alloc((size_t)kGN * kH);
  float* gdl  = alloc((size_t)kGN * kH);
  float* X    = alloc((size_t)kROWS * kH);
  float* QKV  = alloc((size_t)kROWS * 3 * kH);
  float* O    = alloc((size_t)kROWS * kH);
  float* tmp  = alloc((size_t)kROWS * kH);
  float* Fs   = alloc((size_t)kROWS * kFFCH);
  float* y    = alloc((size_t)kROWS * 8);

  auto gemm_nt_small = [&](const float* A, const float* B, const float* bias,
                           float* C, int M, int N, int K, int ldb, int ldc,
                           int flags) {
    dim3 g(N / 64, M / 64, 1);
    gemm_kernel<true><<<g, 256, 0, stream>>>(A, B, bias, C, K, ldb, ldc, flags,
                                             (size_t)0, (size_t)0, (size_t)0);
  };
  // transformer GEMM: C(32768,N) = A(32768,K) @ B(N,K)^T
  auto gemm_t = [&](const float* A, const float* B, const float* bias, float* C,
                    int N, int K, int ldb, int ldc, int flags) {
    gemm_mfma<<<dim3(N / 128, kROWS / 128), 256, 0, stream>>>(A, B, bias, C, K,
                                                              ldb, ldc, flags);
  };

  k_init<<<1, 64, 0, stream>>>(sc);
  k_minmax<<<512, 256, 0, stream>>>(adj, kOBS * kNAG * kNAG, sc);
  k_scale<<<1, 1, 0, stream>>>(sc);
  k_dis<<<8, 256, 0, stream>>>(adj, sc, dis);
  k_agg<<<2048, 256, 0, stream>>>(adj, sc, dis, agg);

  k_enc1<<<(kGN * kH) / 256, 256, 0, stream>>>(traj_in, pro1_w, pro1_b, enc1);
  gemm_nt_small(enc1, pro2_w, pro2_b, enc, kGN, kH, kH, kH, kH, 0);
  gemm_nt_small(enc, mu_w, mu_b, Mmu, kGN, kH, kH, kH, kH, 0);
  gemm_nt_small(enc, ls_w, ls_b, Mls, kGN, kH, kH, kH, kH, 0);
  {
    dim3 g(kH / 64, kNAG / 64, kOBS);
    gemm_kernel<false><<<g, 256, 0, stream>>>(agg, Mmu, nullptr, mu, kNAG, kH,
                                              kH, 0, (size_t)65536,
                                              (size_t)kNAG * kH, (size_t)kNAG * kH);
    gemm_kernel<false><<<g, 256, 0, stream>>>(agg, Mls, nullptr, lsb, kNAG, kH,
                                              kH, 0, (size_t)65536,
                                              (size_t)kNAG * kH, (size_t)kNAG * kH);
  }
  k_zkld<<<(kGN * kH) / 256, 256, 0, stream>>>(mu, lsb, eps, iftrain, Z, sc);
  gemm_nt_small(Z, gdl_w, gdl_b, gdl, kGN, kH, kH, kH, kH, 0);
  k_struct<<<dim3(kGN / 64, kGN / 64), 256, 0, stream>>>(Z, adj, sc);
  k_x0<<<kROWS / 2, dim3(128, 2), 0, stream>>>(gdl, pro3_w, pro3_b, X);

  for (int l = 0; l < 6; ++l) {
    // qkv: (32768,384) = X @ Wqkv^T
    gemm_t(X, qkv_w + (size_t)l * 384 * kH, qkv_b + l * 384, QKV, 384, kH, kH,
           384, 0);
    k_attn<<<dim3(8, 128), 256, 0, stream>>>(QKV, O);
    // out-proj: (32768,128)
    gemm_t(O, outp_w + (size_t)l * kH * kH, outp_b + l * kH, tmp, kH, kH, kH,
           kH, 0);
    k_resid_ln<<<kROWS / 4, 256, 0, stream>>>(X, tmp, ln1_g + l * kH,
                                              ln1_b + l * kH);
    for (int c = 0; c < kNCH; ++c) {
      // ff1 chunk: (32768,512) relu
      gemm_t(X, ff1_w + (size_t)l * 2048 * kH + (size_t)c * kFFCH * kH,
             ff1_b + l * 2048 + c * kFFCH, Fs, kFFCH, kH, kH, kFFCH, 1);
      // ff2 chunk: (32768,128), K=512, accumulate
      gemm_t(Fs, ff2_w + (size_t)l * kH * 2048 + c * kFFCH,
             (c == 0 ? ff2_b + l * kH : nullptr), tmp, kH, kFFCH, 2048, kH,
             (c == 0 ? 0 : 2));
    }
    k_resid_ln<<<kROWS / 4, 256, 0, stream>>>(X, tmp, ln2_g + l * kH,
                                              ln2_b + l * kH);
  }

  k_heady<<<kROWS / 32, 256, 0, stream>>>(X, pro4_w, pro4_b, y);
  k_traj<<<kNAG, 64, 0, stream>>>(y, pro5_w, pro5_b, traj_in, dout, sc);
  k_loss<<<1, 1, 0, stream>>>(sc, dout);
}

// Round 4
// 2907.627 us; speedup vs baseline: 1.6506x; 1.0558x over previous
//
#include <hip/hip_runtime.h>
#include <math.h>

// GVAE-Transformer forward. fp32 interfaces; transformer GEMMs on MFMA via
// split-bf16 (3-term: ah*bh + ah*bl + al*bh, fp32 accum), with all inputs
// PRE-converted to bf16 hi/lo (weights once per launch; activations written
// hi/lo by their producers) and global_load_lds(16B) staging — no VALU work
// in the GEMM hot loop.
// Shapes: OBS=8 PRED=4 NAG=256 FIN=2 FOUT=2 H=128 NH=8 FF=2048 NL=6.
//
// R4 changes vs R3 (3069 us, gemm ~2.0ms / attn 625us):
//  - gemm_bf: bf16-in GEMM, 128x128 & 64x128 tiles, BK=32, global_load_lds.
//  - k_cvt: one-time weight conversion; k_x0/k_resid_ln/k_attn/ff1-epilogue
//    emit bf16 hi/lo pairs directly.
//  - ws: QKV unioned with Fsh/Fsl (~156 MB total).

namespace {

constexpr int kOBS = 8, kNAG = 256, kH = 128, kFFCH = 512, kNCH = 4;
constexpr int kGN = kOBS * kNAG;   // 2048 graph nodes
constexpr int kROWS = kNAG * kH;   // 32768 transformer rows (S=256, B=128)

typedef __attribute__((ext_vector_type(8))) short bf16x8;
typedef __attribute__((ext_vector_type(4))) float f32x4;
typedef __attribute__((ext_vector_type(4))) unsigned short us4;

struct Scal {
  int    mn_bits;
  int    mx_bits;
  float  Amin;
  float  invr;
  float  c0;
  int    pad;
  double kld_sum;
  double struct_sum;
  double traj_sum;
};

__device__ inline float waveReduceSum(float v) {
#pragma unroll
  for (int off = 32; off; off >>= 1) v += __shfl_xor(v, off, 64);
  return v;
}

__device__ inline unsigned short f2bf(float f) {  // RNE fp32 -> bf16
  unsigned u = __float_as_uint(f);
  return (unsigned short)((u + 0x7fffu + ((u >> 16) & 1u)) >> 16);
}
__device__ inline float bf2f(unsigned short h) {
  return __uint_as_float((unsigned)h << 16);
}
__device__ inline void split4(float4 v, us4& h, us4& l) {
  h.x = f2bf(v.x); l.x = f2bf(v.x - bf2f(h.x));
  h.y = f2bf(v.y); l.y = f2bf(v.y - bf2f(h.y));
  h.z = f2bf(v.z); l.z = f2bf(v.z - bf2f(h.z));
  h.w = f2bf(v.w); l.w = f2bf(v.w - bf2f(h.w));
}

// async global->LDS, 16B per lane (dest = uniform base + lane*16)
#define GLL(g, s)                                             \
  __builtin_amdgcn_global_load_lds(                           \
      (const __attribute__((address_space(1))) void*)(g),     \
      (__attribute__((address_space(3))) void*)(s), 16, 0, 0)

__global__ void k_init(Scal* sc) {
  if (threadIdx.x == 0) {
    sc->mn_bits = 0x7f800000;
    sc->mx_bits = 0xff800000;
    sc->kld_sum = 0.0;
    sc->struct_sum = 0.0;
    sc->traj_sum = 0.0;
  }
}

__global__ void k_minmax(const float* __restrict__ adj, int n, Scal* sc) {
  float lmin = INFINITY, lmax = -INFINITY;
  for (int i = blockIdx.x * blockDim.x + threadIdx.x; i < n;
       i += gridDim.x * blockDim.x) {
    float v = adj[i];
    lmin = fminf(lmin, v);
    lmax = fmaxf(lmax, v);
  }
#pragma unroll
  for (int off = 32; off; off >>= 1) {
    lmin = fminf(lmin, __shfl_xor(lmin, off, 64));
    lmax = fmaxf(lmax, __shfl_xor(lmax, off, 64));
  }
  __shared__ float smn[4], smx[4];
  int w = threadIdx.x >> 6;
  if ((threadIdx.x & 63) == 0) { smn[w] = lmin; smx[w] = lmax; }
  __syncthreads();
  if (threadIdx.x == 0) {
    lmin = fminf(fminf(smn[0], smn[1]), fminf(smn[2], smn[3]));
    lmax = fmaxf(fmaxf(smx[0], smx[1]), fmaxf(smx[2], smx[3]));
    atomicMin(&sc->mn_bits, __float_as_int(lmin));
    atomicMax(&sc->mx_bits, __float_as_int(lmax));
  }
}

__global__ void k_scale(Scal* sc) {
  float mn = fminf(0.0f, __int_as_float(sc->mn_bits));
  float mx = fmaxf(0.0f, __int_as_float(sc->mx_bits));
  sc->Amin = mn;
  sc->invr = 1.0f / (mx - mn);
  sc->c0 = (0.0f - mn) * sc->invr;
}

__global__ void k_dis(const float* __restrict__ adj, const Scal* __restrict__ sc,
                      float* __restrict__ dis) {
  int j = blockIdx.x * 256 + threadIdx.x;
  int t = j >> 8, jj = j & 255;
  const float* a = adj + (size_t)t * 65536;
  float Amin = sc->Amin, invr = sc->invr, c0 = sc->c0;
  float sum = 0.f;
  for (int i = 0; i < 256; ++i) sum += (a[i * 256 + jj] - Amin) * invr;
  float djj = (a[jj * 256 + jj] - Amin) * invr;
  float deg = sum + 1792.0f * c0 + (djj == 0.0f ? 1.0f : 0.0f);
  dis[j] = deg > 0.0f ? 1.0f / sqrtf(deg) : 0.0f;
}

__global__ void k_agg(const float* __restrict__ adj, const Scal* __restrict__ sc,
                      const float* __restrict__ dis, float* __restrict__ agg) {
  int idx = blockIdx.x * 256 + threadIdx.x;
  int t = idx >> 16, i = (idx >> 8) & 255, j = idx & 255;
  float v = (adj[(size_t)t * 65536 + j * 256 + i] - sc->Amin) * sc->invr;
  if (i == j && v == 0.0f) v += 1.0f;
  agg[idx] = dis[t * 256 + j] * v * dis[t * 256 + i];
}

__global__ void k_enc1(const float* __restrict__ traj, const float* __restrict__ w,
                       const float* __restrict__ b, float* __restrict__ out) {
  int idx = blockIdx.x * 256 + threadIdx.x;
  int r = idx >> 7, f = idx & 127;
  float v = traj[r * 2] * w[f * 2] + traj[r * 2 + 1] * w[f * 2 + 1] + b[f];
  out[idx] = fmaxf(v, 0.0f);
}

// fp32 -> bf16 hi/lo, 4 elems/thread
__global__ void k_cvt(const float* __restrict__ src, unsigned short* __restrict__ h,
                      unsigned short* __restrict__ l, int n4) {
  int i = blockIdx.x * 256 + threadIdx.x;
  if (i >= n4) return;
  float4 v = reinterpret_cast<const float4*>(src)[i];
  us4 hh, ll;
  split4(v, hh, ll);
  reinterpret_cast<us4*>(h)[i] = hh;
  reinterpret_cast<us4*>(l)[i] = ll;
}

// ---------------- small fp32 GEMM (front-end, M=2048) ----------------
#define BM 64
#define BN 64
#define KC 32
#define LP 68

template <bool TB>
__global__ __launch_bounds__(256) void gemm_kernel(
    const float* __restrict__ A, const float* __restrict__ B,
    const float* __restrict__ bias, float* __restrict__ C, int K, int ldb,
    int ldc, int flags, size_t aStride, size_t bStride, size_t cStride) {
  if (blockIdx.z) {
    A += (size_t)blockIdx.z * aStride;
    B += (size_t)blockIdx.z * bStride;
    C += (size_t)blockIdx.z * cStride;
  }
  __shared__ float As[KC][LP];
  __shared__ float Bs[KC][LP];
  const int tid = threadIdx.x;
  const int tx = tid & 15, ty = tid >> 4;
  const int m0 = blockIdx.y * BM, n0 = blockIdx.x * BN;
  float acc[4][4] = {};
  for (int k0 = 0; k0 < K; k0 += KC) {
#pragma unroll
    for (int i = 0; i < 2; ++i) {
      int q = tid + i * 256;
      int row = q >> 3, kq = q & 7;
      float4 v = *reinterpret_cast<const float4*>(
          &A[(size_t)(m0 + row) * K + k0 + kq * 4]);
      As[kq * 4 + 0][row] = v.x;
      As[kq * 4 + 1][row] = v.y;
      As[kq * 4 + 2][row] = v.z;
      As[kq * 4 + 3][row] = v.w;
    }
    if (TB) {
#pragma unroll
      for (int i = 0; i < 2; ++i) {
        int q = tid + i * 256;
        int row = q >> 3, kq = q & 7;
        float4 v = *reinterpret_cast<const float4*>(
            &B[(size_t)(n0 + row) * ldb + k0 + kq * 4]);
        Bs[kq * 4 + 0][row] = v.x;
        Bs[kq * 4 + 1][row] = v.y;
        Bs[kq * 4 + 2][row] = v.z;
        Bs[kq * 4 + 3][row] = v.w;
      }
    } else {
#pragma unroll
      for (int i = 0; i < 2; ++i) {
        int q = tid + i * 256;
        int kr = q >> 4, nq = q & 15;
        float4 v = *reinterpret_cast<const float4*>(
            &B[(size_t)(k0 + kr) * ldb + n0 + nq * 4]);
        *reinterpret_cast<float4*>(&Bs[kr][nq * 4]) = v;
      }
    }
    __syncthreads();
#pragma unroll
    for (int kk = 0; kk < KC; ++kk) {
      float4 a4 = *reinterpret_cast<const float4*>(&As[kk][ty * 4]);
      float4 b4 = *reinterpret_cast<const float4*>(&Bs[kk][tx * 4]);
      float av[4] = {a4.x, a4.y, a4.z, a4.w};
      float bv[4] = {b4.x, b4.y, b4.z, b4.w};
#pragma unroll
      for (int i = 0; i < 4; ++i)
#pragma unroll
        for (int j = 0; j < 4; ++j) acc[i][j] += av[i] * bv[j];
    }
    __syncthreads();
  }
  float bv[4] = {0.f, 0.f, 0.f, 0.f};
  if (bias) {
    float4 b4 = *reinterpret_cast<const float4*>(&bias[n0 + tx * 4]);
    bv[0] = b4.x; bv[1] = b4.y; bv[2] = b4.z; bv[3] = b4.w;
  }
#pragma unroll
  for (int i = 0; i < 4; ++i) {
    float* cp = &C[(size_t)(m0 + ty * 4 + i) * ldc + n0 + tx * 4];
    float4 o;
    float ov[4];
#pragma unroll
    for (int j = 0; j < 4; ++j) ov[j] = acc[i][j] + bv[j];
    if (flags & 2) {
      float4 old = *reinterpret_cast<const float4*>(cp);
      ov[0] += old.x; ov[1] += old.y; ov[2] += old.z; ov[3] += old.w;
    }
    if (flags & 1) {
#pragma unroll
      for (int j = 0; j < 4; ++j) ov[j] = fmaxf(ov[j], 0.0f);
    }
    o.x = ov[0]; o.y = ov[1]; o.z = ov[2]; o.w = ov[3];
    *reinterpret_cast<float4*>(cp) = o;
  }
}

// ---------------- MFMA split-bf16 GEMM, pre-converted bf16 inputs ----------
// C(M,N) = (Ah+Al)(M,K) @ (Bh+Bl)(N,K)^T + bias  (3-term product).
// Tile BMb x BNb, BK=32, 4 waves (2x2), wave tile BMb/2 x BNb/2 of 16x16x32
// frags.  Staging via global_load_lds(16B), linear LDS [rows][32] bf16.
// flags: 1=relu  2=acc into fp32 C  4=write bf16 hi/lo to Ch/Cl.
template <int BMb, int BNb>
__global__ __launch_bounds__(256) void gemm_bf(
    const unsigned short* __restrict__ Ah, const unsigned short* __restrict__ Al,
    const unsigned short* __restrict__ Bh, const unsigned short* __restrict__ Bl,
    const float* __restrict__ bias, float* __restrict__ C,
    unsigned short* __restrict__ Ch, unsigned short* __restrict__ Cl,
    int K, int lda, int ldb, int ldc, int flags) {
  constexpr int MI = BMb / 32, NI = BNb / 32;
  constexpr int WTM = BMb / 2, WTN = BNb / 2;
  __shared__ unsigned short sAh[BMb * 32], sAl[BMb * 32];
  __shared__ unsigned short sBh[BNb * 32], sBl[BNb * 32];
  const int tid = threadIdx.x, lane = tid & 63, w = tid >> 6;
  const int wr = w >> 1, wc = w & 1;
  const int m0 = blockIdx.y * BMb, n0 = blockIdx.x * BNb;
  f32x4 acc[MI][NI];
#pragma unroll
  for (int i = 0; i < MI; ++i)
#pragma unroll
    for (int j = 0; j < NI; ++j) acc[i][j] = (f32x4){0.f, 0.f, 0.f, 0.f};

  for (int k0 = 0; k0 < K; k0 += 32) {
#pragma unroll
    for (int i = 0; i < BMb / 64; ++i) {
      int c = tid + i * 256;        // 16B chunk id; row = c>>2
      int row = c >> 2, c4 = c & 3;
      size_t g = (size_t)(m0 + row) * lda + k0 + c4 * 8;
      GLL(&Ah[g], &sAh[c * 8]);
      GLL(&Al[g], &sAl[c * 8]);
    }
#pragma unroll
    for (int i = 0; i < BNb / 64; ++i) {
      int c = tid + i * 256;
      int row = c >> 2, c4 = c & 3;
      size_t g = (size_t)(n0 + row) * ldb + k0 + c4 * 8;
      GLL(&Bh[g], &sBh[c * 8]);
      GLL(&Bl[g], &sBl[c * 8]);
    }
    __syncthreads();
    bf16x8 bh[NI], bl[NI];
#pragma unroll
    for (int ni = 0; ni < NI; ++ni) {
      int off = (wc * WTN + ni * 16 + (lane & 15)) * 32 + (lane >> 4) * 8;
      bh[ni] = *reinterpret_cast<const bf16x8*>(&sBh[off]);
      bl[ni] = *reinterpret_cast<const bf16x8*>(&sBl[off]);
    }
#pragma unroll
    for (int mi = 0; mi < MI; ++mi) {
      int off = (wr * WTM + mi * 16 + (lane & 15)) * 32 + (lane >> 4) * 8;
      bf16x8 ah = *reinterpret_cast<const bf16x8*>(&sAh[off]);
      bf16x8 al = *reinterpret_cast<const bf16x8*>(&sAl[off]);
#pragma unroll
      for (int ni = 0; ni < NI; ++ni) {
        acc[mi][ni] = __builtin_amdgcn_mfma_f32_16x16x32_bf16(
            ah, bh[ni], acc[mi][ni], 0, 0, 0);
        acc[mi][ni] = __builtin_amdgcn_mfma_f32_16x16x32_bf16(
            ah, bl[ni], acc[mi][ni], 0, 0, 0);
        acc[mi][ni] = __builtin_amdgcn_mfma_f32_16x16x32_bf16(
            al, bh[ni], acc[mi][ni], 0, 0, 0);
      }
    }
    __syncthreads();
  }
  const int crow0 = m0 + wr * WTM + (lane >> 4) * 4;
  const int ccol0 = n0 + wc * WTN + (lane & 15);
#pragma unroll
  for (int ni = 0; ni < NI; ++ni) {
    int col = ccol0 + ni * 16;
    float bv = bias ? bias[col] : 0.f;
#pragma unroll
    for (int mi = 0; mi < MI; ++mi) {
#pragma unroll
      for (int r = 0; r < 4; ++r) {
        int row = crow0 + mi * 16 + r;
        float v = acc[mi][ni][r] + bv;
        if (flags & 2) v += C[(size_t)row * ldc + col];
        if (flags & 1) v = fmaxf(v, 0.0f);
        if (flags & 4) {
          unsigned short h = f2bf(v);
          Ch[(size_t)row * ldc + col] = h;
          Cl[(size_t)row * ldc + col] = f2bf(v - bf2f(h));
        } else {
          C[(size_t)row * ldc + col] = v;
        }
      }
    }
  }
}

__global__ void k_zkld(const float* __restrict__ mu, const float* __restrict__ lsr,
                       const float* __restrict__ eps, const int* __restrict__ iftrain,
                       float* __restrict__ Z, Scal* sc) {
  int i = blockIdx.x * 256 + threadIdx.x;
  float m = mu[i];
  float ls = fminf(lsr[i], 10.0f);
  float z = (*iftrain > 0) ? m + eps[i] * __expf(ls) : m;
  Z[i] = z;
  float kt = 1.0f + 2.0f * ls - m * m - __expf(2.0f * ls);
  kt = waveReduceSum(kt);
  __shared__ float sh[4];
  int w = threadIdx.x >> 6;
  if ((threadIdx.x & 63) == 0) sh[w] = kt;
  __syncthreads();
  if (threadIdx.x == 0)
    atomicAdd(&sc->kld_sum, (double)(sh[0] + sh[1] + sh[2] + sh[3]));
}

__global__ __launch_bounds__(256) void k_struct(const float* __restrict__ Z,
                                                const float* __restrict__ adj,
                                                Scal* sc) {
  __shared__ float As[KC][LP];
  __shared__ float Bs[KC][LP];
  const int tid = threadIdx.x;
  const int tx = tid & 15, ty = tid >> 4;
  const int m0 = blockIdx.y * BM, n0 = blockIdx.x * BN;
  float acc[4][4] = {};
  for (int k0 = 0; k0 < kH; k0 += KC) {
#pragma unroll
    for (int i = 0; i < 2; ++i) {
      int q = tid + i * 256;
      int row = q >> 3, kq = q & 7;
      float4 va = *reinterpret_cast<const float4*>(
          &Z[(size_t)(m0 + row) * kH + k0 + kq * 4]);
      As[kq * 4 + 0][row] = va.x;
      As[kq * 4 + 1][row] = va.y;
      As[kq * 4 + 2][row] = va.z;
      As[kq * 4 + 3][row] = va.w;
      float4 vb = *reinterpret_cast<const float4*>(
          &Z[(size_t)(n0 + row) * kH + k0 + kq * 4]);
      Bs[kq * 4 + 0][row] = vb.x;
      Bs[kq * 4 + 1][row] = vb.y;
      Bs[kq * 4 + 2][row] = vb.z;
      Bs[kq * 4 + 3][row] = vb.w;
    }
    __syncthreads();
#pragma unroll
    for (int kk = 0; kk < KC; ++kk) {
      float4 a4 = *reinterpret_cast<const float4*>(&As[kk][ty * 4]);
      float4 b4 = *reinterpret_cast<const float4*>(&Bs[kk][tx * 4]);
      float av[4] = {a4.x, a4.y, a4.z, a4.w};
      float bv[4] = {b4.x, b4.y, b4.z, b4.w};
#pragma unroll
      for (int i = 0; i < 4; ++i)
#pragma unroll
        for (int j = 0; j < 4; ++j) acc[i][j] += av[i] * bv[j];
    }
    __syncthreads();
  }
  float Amin = sc->Amin, invr = sc->invr, c0v = sc->c0;
  float lsum = 0.f;
#pragma unroll
  for (int i = 0; i < 4; ++i) {
#pragma unroll
    for (int j = 0; j < 4; ++j) {
      int gi = m0 + ty * 4 + i, gj = n0 + tx * 4 + j;
      float l = acc[i][j];
      float adjv = c0v;
      if ((gi >> 8) == (gj >> 8))
        adjv = (adj[((size_t)(gi >> 8) << 16) + (gi & 255) * 256 + (gj & 255)] -
                Amin) * invr;
      lsum += fmaxf(l, 0.0f) - l * adjv + __logf(1.0f + __expf(-fabsf(l)));
    }
  }
  lsum = waveReduceSum(lsum);
  __shared__ float sh[4];
  int w = threadIdx.x >> 6;
  if ((threadIdx.x & 63) == 0) sh[w] = lsum;
  __syncthreads();
  if (threadIdx.x == 0)
    atomicAdd(&sc->struct_sum, (double)(sh[0] + sh[1] + sh[2] + sh[3]));
}

__global__ void k_x0(const float* __restrict__ gdl, const float* __restrict__ w3,
                     const float* __restrict__ b3, float* __restrict__ X,
                     unsigned short* __restrict__ Xh,
                     unsigned short* __restrict__ Xl) {
  int f = threadIdx.x;
  size_t r = (size_t)blockIdx.x * 2 + threadIdx.y;
  int n = (int)(r >> 7), h = (int)(r & 127);
  float a = b3[f];
#pragma unroll
  for (int o = 0; o < 8; ++o)
    a += gdl[((size_t)o * 256 + n) * 128 + h] * w3[f * 8 + o];
  X[r * 128 + f] = a;
  unsigned short hh = f2bf(a);
  Xh[r * 128 + f] = hh;
  Xl[r * 128 + f] = f2bf(a - bf2f(hh));
}

// attention: one block per (head,b); 256 threads, 1 q-row each.  Single-pass
// online softmax w/ deferred rescale (THR=8).  Writes O as bf16 hi/lo.
__global__ __launch_bounds__(256) void k_attn(const float* __restrict__ QKV,
                                              unsigned short* __restrict__ Oh,
                                              unsigned short* __restrict__ Ol) {
  const int head = blockIdx.x, b = blockIdx.y;
  const int s = threadIdx.x;  // 0..255
  __shared__ float ks[256][16];
  __shared__ float vs[256][16];
  const size_t base = ((size_t)s * 128 + b) * 384 + head * 16;
#pragma unroll
  for (int i = 0; i < 4; ++i) {
    *reinterpret_cast<float4*>(&ks[s][i * 4]) =
        *reinterpret_cast<const float4*>(&QKV[base + 128 + i * 4]);
    *reinterpret_cast<float4*>(&vs[s][i * 4]) =
        *reinterpret_cast<const float4*>(&QKV[base + 256 + i * 4]);
  }
  float q[16];
#pragma unroll
  for (int i = 0; i < 4; ++i) {
    float4 v = *reinterpret_cast<const float4*>(&QKV[base + i * 4]);
    q[i * 4 + 0] = v.x * 0.25f; q[i * 4 + 1] = v.y * 0.25f;
    q[i * 4 + 2] = v.z * 0.25f; q[i * 4 + 3] = v.w * 0.25f;
  }
  __syncthreads();
  float m = -1e30f, lsum = 0.f;
  float o[16] = {};
#pragma unroll 2
  for (int t = 0; t < 256; ++t) {
    float kv[16], vv[16];
#pragma unroll
    for (int i = 0; i < 4; ++i) {
      float4 k4 = *reinterpret_cast<const float4*>(&ks[t][i * 4]);
      float4 v4 = *reinterpret_cast<const float4*>(&vs[t][i * 4]);
      kv[i * 4 + 0] = k4.x; kv[i * 4 + 1] = k4.y;
      kv[i * 4 + 2] = k4.z; kv[i * 4 + 3] = k4.w;
      vv[i * 4 + 0] = v4.x; vv[i * 4 + 1] = v4.y;
      vv[i * 4 + 2] = v4.z; vv[i * 4 + 3] = v4.w;
    }
    float d = 0.f;
#pragma unroll
    for (int i = 0; i < 16; ++i) d += q[i] * kv[i];
    if (d > m + 8.f) {            // deferred rescale (T13)
      float c = __expf(m - d);
      lsum *= c;
#pragma unroll
      for (int i = 0; i < 16; ++i) o[i] *= c;
      m = d;
    }
    float p = __expf(d - m);
    lsum += p;
#pragma unroll
    for (int i = 0; i < 16; ++i) o[i] += p * vv[i];
  }
  float inv = 1.0f / lsum;
  size_t ob = ((size_t)s * 128 + b) * 128 + head * 16;
#pragma unroll
  for (int i = 0; i < 4; ++i) {
    float4 v;
    v.x = o[i * 4 + 0] * inv; v.y = o[i * 4 + 1] * inv;
    v.z = o[i * 4 + 2] * inv; v.w = o[i * 4 + 3] * inv;
    us4 hh, ll;
    split4(v, hh, ll);
    *reinterpret_cast<us4*>(&Oh[ob + i * 4]) = hh;
    *reinterpret_cast<us4*>(&Ol[ob + i * 4]) = ll;
  }
}

// X = LN(X + T); also emits Xh/Xl bf16 hi/lo
__global__ __launch_bounds__(256) void k_resid_ln(
    float* __restrict__ X, const float* __restrict__ T,
    const float* __restrict__ g, const float* __restrict__ b,
    unsigned short* __restrict__ Xh, unsigned short* __restrict__ Xl) {
  int lane = threadIdx.x & 63, rl = threadIdx.x >> 6;
  size_t row = (size_t)blockIdx.x * 4 + rl;
  float* xp = X + row * 128;
  const float* tp = T + row * 128;
  float e0 = xp[lane] + tp[lane];
  float e1 = xp[lane + 64] + tp[lane + 64];
  float mean = waveReduceSum(e0 + e1) * 0.0078125f;
  float d0 = e0 - mean, d1 = e1 - mean;
  float var = waveReduceSum(d0 * d0 + d1 * d1) * 0.0078125f;
  float inv = 1.0f / sqrtf(var + 1e-5f);
  float v0 = d0 * inv * g[lane] + b[lane];
  float v1 = d1 * inv * g[lane + 64] + b[lane + 64];
  xp[lane] = v0;
  xp[lane + 64] = v1;
  unsigned short h0 = f2bf(v0), h1 = f2bf(v1);
  Xh[row * 128 + lane] = h0;
  Xl[row * 128 + lane] = f2bf(v0 - bf2f(h0));
  Xh[row * 128 + lane + 64] = h1;
  Xl[row * 128 + lane + 64] = f2bf(v1 - bf2f(h1));
}

__global__ void k_heady(const float* __restrict__ X, const float* __restrict__ w4,
                        const float* __restrict__ b4, float* __restrict__ y) {
  int tid = threadIdx.x;
  int o = tid & 7, rl = tid >> 3;
  size_t r = (size_t)blockIdx.x * 32 + rl;
  const float* xp = X + r * 128;
  const float* wp = w4 + o * 128;
  float a = b4[o];
  for (int f = 0; f < 128; f += 4)
    a += xp[f] * wp[f] + xp[f + 1] * wp[f + 1] + xp[f + 2] * wp[f + 2] +
         xp[f + 3] * wp[f + 3];
  y[r * 8 + o] = a;
}

__global__ void k_traj(const float* __restrict__ y, const float* __restrict__ w5,
                       const float* __restrict__ b5,
                       const float* __restrict__ traj_in, float* __restrict__ dout,
                       Scal* sc) {
  int n = blockIdx.x, lane = threadIdx.x;
  float w0a = w5[lane], w0b = w5[lane + 64];
  float w1a = w5[128 + lane], w1b = w5[128 + lane + 64];
  float dsum = 0.f;
  for (int oi = 0; oi < 4; ++oi) {
    int o = 4 + oi;
    float ya = y[((size_t)n * 128 + lane) * 8 + o];
    float yb = y[((size_t)n * 128 + lane + 64) * 8 + o];
    float s0 = waveReduceSum(w0a * ya + w0b * yb);
    float s1 = waveReduceSum(w1a * ya + w1b * yb);
    if (lane == 0) {
      float t0 = s0 + b5[0], t1 = s1 + b5[1];
      dout[oi * 512 + n * 2 + 0] = t0;
      dout[oi * 512 + n * 2 + 1] = t1;
      float dx = t0 - traj_in[((8 + oi) * 256 + n) * 2 + 0];
      float dy = t1 - traj_in[((8 + oi) * 256 + n) * 2 + 1];
      dsum += sqrtf(dx * dx + dy * dy);
    }
  }
  if (lane == 0) atomicAdd(&sc->traj_sum, (double)dsum);
}

__global__ void k_loss(const Scal* sc, float* dout) {
  if (threadIdx.x == 0) {
    double traj_loss = sc->traj_sum / 256.0;
    double kld = -0.5 * sc->kld_sum / 2048.0;
    double st = sc->struct_sum / (2048.0 * 2048.0);
    dout[2048] = (float)(traj_loss + kld + st);
  }
}

}  // namespace

extern "C" void kernel_launch(void* const* d_in, const int* in_sizes, int n_in,
                              void* d_out, int out_size, void* d_ws,
                              size_t ws_size, hipStream_t stream) {
  (void)in_sizes; (void)n_in; (void)out_size; (void)ws_size;
  const float* traj_in = (const float*)d_in[0];
  const float* adj     = (const float*)d_in[1];
  const float* eps     = (const float*)d_in[2];
  const float* pro1_w  = (const float*)d_in[3];
  const float* pro1_b  = (const float*)d_in[4];
  const float* pro2_w  = (const float*)d_in[5];
  const float* pro2_b  = (const float*)d_in[6];
  const float* mu_w    = (const float*)d_in[7];
  const float* mu_b    = (const float*)d_in[8];
  const float* ls_w    = (const float*)d_in[9];
  const float* ls_b    = (const float*)d_in[10];
  const float* gdl_w   = (const float*)d_in[11];
  const float* gdl_b   = (const float*)d_in[12];
  const float* pro3_w  = (const float*)d_in[13];
  const float* pro3_b  = (const float*)d_in[14];
  const float* pro4_w  = (const float*)d_in[15];
  const float* pro4_b  = (const float*)d_in[16];
  const float* pro5_w  = (const float*)d_in[17];
  const float* pro5_b  = (const float*)d_in[18];
  const float* qkv_w   = (const float*)d_in[19];
  const float* qkv_b   = (const float*)d_in[20];
  const float* outp_w  = (const float*)d_in[21];
  const float* outp_b  = (const float*)d_in[22];
  const float* ff1_w   = (const float*)d_in[23];
  const float* ff1_b   = (const float*)d_in[24];
  const float* ff2_w   = (const float*)d_in[25];
  const float* ff2_b   = (const float*)d_in[26];
  const float* ln1_g   = (const float*)d_in[27];
  const float* ln1_b   = (const float*)d_in[28];
  const float* ln2_g   = (const float*)d_in[29];
  const float* ln2_b   = (const float*)d_in[30];
  const int*   iftrain = (const int*)d_in[31];
  float* dout = (float*)d_out;

  char* wsb = (char*)d_ws;
  size_t off = 0;
  auto alloc = [&](size_t bytes) {
    char* p = wsb + off;
    off += (bytes + 255) & ~(size_t)255;
    return p;
  };
  Scal* sc    = (Scal*)alloc(256);
  float* dis  = (float*)alloc(kGN * 4);
  float* agg  = (float*)alloc((size_t)kOBS * 65536 * 4);
  float* enc1 = (float*)alloc((size_t)kGN * kH * 4);
  float* enc  = (float*)alloc((size_t)kGN * kH * 4);
  float* Mmu  = (float*)alloc((size_t)kGN * kH * 4);
  float* Mls  = (float*)alloc((size_t)kGN * kH * 4);
  float* mu   = (float*)alloc((size_t)kGN * kH * 4);
  float* lsb  = (float*)alloc((size_t)kGN * kH * 4);
  float* Z    = (float*)alloc((size_t)kGN * kH * 4);
  float* gdl  = (float*)alloc((size_t)kGN * kH * 4);
  float* X    = (float*)alloc((size_t)kROWS * kH * 4);
  unsigned short* Xh = (unsigned short*)alloc((size_t)kROWS * kH * 2);
  unsigned short* Xl = (unsigned short*)alloc((size_t)kROWS * kH * 2);
  // union: QKV fp32 (50.3 MB)  |  Fsh+Fsl bf16 (33.6 + 33.6 MB)
  char* U = alloc((size_t)kROWS * kFFCH * 2 * 2);
  float* QKV = (float*)U;
  unsigned short* Fsh = (unsigned short*)U;
  unsigned short* Fsl = Fsh + (size_t)kROWS * kFFCH;
  unsigned short* Oh = (unsigned short*)alloc((size_t)kROWS * kH * 2);
  unsigned short* Ol = (unsigned short*)alloc((size_t)kROWS * kH * 2);
  float* tmp  = (float*)alloc((size_t)kROWS * kH * 4);
  float* y    = (float*)alloc((size_t)kROWS * 8 * 4);
  unsigned short* qkvWh = (unsigned short*)alloc(6 * 384 * 128 * 2);
  unsigned short* qkvWl = (unsigned short*)alloc(6 * 384 * 128 * 2);
  unsigned short* outWh = (unsigned short*)alloc(6 * 128 * 128 * 2);
  unsigned short* outWl = (unsigned short*)alloc(6 * 128 * 128 * 2);
  unsigned short* ff1Wh = (unsigned short*)alloc(6 * 2048 * 128 * 2);
  unsigned short* ff1Wl = (unsigned short*)alloc(6 * 2048 * 128 * 2);
  unsigned short* ff2Wh = (unsigned short*)alloc(6 * 128 * 2048 * 2);
  unsigned short* ff2Wl = (unsigned short*)alloc(6 * 128 * 2048 * 2);

  auto gemm_nt_small = [&](const float* A, const float* B, const float* bias,
                           float* C, int M, int N, int K, int ldb, int ldc,
                           int flags) {
    dim3 g(N / 64, M / 64, 1);
    gemm_kernel<true><<<g, 256, 0, stream>>>(A, B, bias, C, K, ldb, ldc, flags,
                                             (size_t)0, (size_t)0, (size_t)0);
  };

  // one-time weight conversions
  k_cvt<<<(6 * 384 * 128 / 4 + 255) / 256, 256, 0, stream>>>(
      qkv_w, qkvWh, qkvWl, 6 * 384 * 128 / 4);
  k_cvt<<<(6 * 128 * 128 / 4 + 255) / 256, 256, 0, stream>>>(
      outp_w, outWh, outWl, 6 * 128 * 128 / 4);
  k_cvt<<<(6 * 2048 * 128 / 4 + 255) / 256, 256, 0, stream>>>(
      ff1_w, ff1Wh, ff1Wl, 6 * 2048 * 128 / 4);
  k_cvt<<<(6 * 128 * 2048 / 4 + 255) / 256, 256, 0, stream>>>(
      ff2_w, ff2Wh, ff2Wl, 6 * 128 * 2048 / 4);

  k_init<<<1, 64, 0, stream>>>(sc);
  k_minmax<<<512, 256, 0, stream>>>(adj, kOBS * kNAG * kNAG, sc);
  k_scale<<<1, 1, 0, stream>>>(sc);
  k_dis<<<8, 256, 0, stream>>>(adj, sc, dis);
  k_agg<<<2048, 256, 0, stream>>>(adj, sc, dis, agg);

  k_enc1<<<(kGN * kH) / 256, 256, 0, stream>>>(traj_in, pro1_w, pro1_b, enc1);
  gemm_nt_small(enc1, pro2_w, pro2_b, enc, kGN, kH, kH, kH, kH, 0);
  gemm_nt_small(enc, mu_w, mu_b, Mmu, kGN, kH, kH, kH, kH, 0);
  gemm_nt_small(enc, ls_w, ls_b, Mls, kGN, kH, kH, kH, kH, 0);
  {
    dim3 g(kH / 64, kNAG / 64, kOBS);
    gemm_kernel<false><<<g, 256, 0, stream>>>(agg, Mmu, nullptr, mu, kNAG, kH,
                                              kH, 0, (size_t)65536,
                                              (size_t)kNAG * kH, (size_t)kNAG * kH);
    gemm_kernel<false><<<g, 256, 0, stream>>>(agg, Mls, nullptr, lsb, kNAG, kH,
                                              kH, 0, (size_t)65536,
                                              (size_t)kNAG * kH, (size_t)kNAG * kH);
  }
  k_zkld<<<(kGN * kH) / 256, 256, 0, stream>>>(mu, lsb, eps, iftrain, Z, sc);
  gemm_nt_small(Z, gdl_w, gdl_b, gdl, kGN, kH, kH, kH, kH, 0);
  k_struct<<<dim3(kGN / 64, kGN / 64), 256, 0, stream>>>(Z, adj, sc);
  k_x0<<<kROWS / 2, dim3(128, 2), 0, stream>>>(gdl, pro3_w, pro3_b, X, Xh, Xl);

  for (int l = 0; l < 6; ++l) {
    // qkv: (32768,384) = X @ Wqkv^T  -> fp32 QKV
    gemm_bf<128, 128><<<dim3(3, kROWS / 128), 256, 0, stream>>>(
        Xh, Xl, qkvWh + (size_t)l * 384 * 128, qkvWl + (size_t)l * 384 * 128,
        qkv_b + l * 384, QKV, nullptr, nullptr, 128, 128, 128, 384, 0);
    k_attn<<<dim3(8, 128), 256, 0, stream>>>(QKV, Oh, Ol);
    // out-proj: (32768,128) -> fp32 tmp
    gemm_bf<64, 128><<<dim3(1, kROWS / 64), 256, 0, stream>>>(
        Oh, Ol, outWh + (size_t)l * 128 * 128, outWl + (size_t)l * 128 * 128,
        outp_b + l * 128, tmp, nullptr, nullptr, 128, 128, 128, 128, 0);
    k_resid_ln<<<kROWS / 4, 256, 0, stream>>>(X, tmp, ln1_g + l * kH,
                                              ln1_b + l * kH, Xh, Xl);
    for (int c = 0; c < kNCH; ++c) {
      // ff1 chunk: (32768,512) relu -> bf16 hi/lo Fs
      gemm_bf<128, 128><<<dim3(kFFCH / 128, kROWS / 128), 256, 0, stream>>>(
          Xh, Xl, ff1Wh + (size_t)l * 2048 * 128 + (size_t)c * kFFCH * 128,
          ff1Wl + (size_t)l * 2048 * 128 + (size_t)c * kFFCH * 128,
          ff1_b + l * 2048 + c * kFFCH, nullptr, Fsh, Fsl, 128, 128, 128,
          kFFCH, 1 | 4);
      // ff2 chunk: (32768,128), K=512, accumulate into fp32 tmp
      gemm_bf<64, 128><<<dim3(1, kROWS / 64), 256, 0, stream>>>(
          Fsh, Fsl, ff2Wh + (size_t)l * 128 * 2048 + c * kFFCH,
          ff2Wl + (size_t)l * 128 * 2048 + c * kFFCH,
          (c == 0 ? ff2_b + l * 128 : nullptr), tmp, nullptr, nullptr, kFFCH,
          kFFCH, 2048, 128, (c == 0 ? 0 : 2));
    }
    k_resid_ln<<<kROWS / 4, 256, 0, stream>>>(X, tmp, ln2_g + l * kH,
                                              ln2_b + l * kH, Xh, Xl);
  }

  k_heady<<<kROWS / 32, 256, 0, stream>>>(X, pro4_w, pro4_b, y);
  k_traj<<<kNAG, 64, 0, stream>>>(y, pro5_w, pro5_b, traj_in, dout, sc);
  k_loss<<<1, 1, 0, stream>>>(sc, dout);
}

// Round 6
// 1974.141 us; speedup vs baseline: 2.4311x; 1.4729x over previous
//
#include <hip/hip_runtime.h>
#include <math.h>

// GVAE-Transformer forward. fp32 interfaces; transformer matmuls on MFMA via
// split-bf16 (3-term: ah*bh + ah*bl + al*bh, fp32 accum), pre-converted
// inputs, global_load_lds staging with involution-swizzled LDS (T2 both-sides
// rule: linear LDS dest + swizzled global source + swizzled read).
// Shapes: OBS=8 PRED=4 NAG=256 FIN=2 FOUT=2 H=128 NH=8 FF=2048 NL=6.
//
// R5 (resubmit; prior round hit GPU-acquisition timeout, never measured):
//  - k_ffn: fused ff1+relu+ff2 per 64-row block; Fs never materialized
//    (-512 MB/layer), tmp acc chain gone; X frags hoisted to registers.
//  - LDS swizzle (c^((c>>3)&7) / c^((c>>4)&7)) in gemm_bf & k_ffn: 8-way
//    bank conflict -> <=2-way.

namespace {

constexpr int kOBS = 8, kNAG = 256, kH = 128;
constexpr int kGN = kOBS * kNAG;   // 2048 graph nodes
constexpr int kROWS = kNAG * kH;   // 32768 transformer rows (S=256, B=128)

typedef __attribute__((ext_vector_type(8))) short bf16x8;
typedef __attribute__((ext_vector_type(4))) float f32x4;
typedef __attribute__((ext_vector_type(4))) unsigned short us4;

struct Scal {
  int    mn_bits;
  int    mx_bits;
  float  Amin;
  float  invr;
  float  c0;
  int    pad;
  double kld_sum;
  double struct_sum;
  double traj_sum;
};

__device__ inline float waveReduceSum(float v) {
#pragma unroll
  for (int off = 32; off; off >>= 1) v += __shfl_xor(v, off, 64);
  return v;
}

__device__ inline unsigned short f2bf(float f) {  // RNE fp32 -> bf16
  unsigned u = __float_as_uint(f);
  return (unsigned short)((u + 0x7fffu + ((u >> 16) & 1u)) >> 16);
}
__device__ inline float bf2f(unsigned short h) {
  return __uint_as_float((unsigned)h << 16);
}
__device__ inline void split4(float4 v, us4& h, us4& l) {
  h.x = f2bf(v.x); l.x = f2bf(v.x - bf2f(h.x));
  h.y = f2bf(v.y); l.y = f2bf(v.y - bf2f(h.y));
  h.z = f2bf(v.z); l.z = f2bf(v.z - bf2f(h.z));
  h.w = f2bf(v.w); l.w = f2bf(v.w - bf2f(h.w));
}

// involution chunk swizzles (16B chunk index c).  swz4: rows of 4 chunks
// (32 shorts); swz16: rows of 16 chunks (128 shorts).  Applied to BOTH the
// global source chunk (staging) and the read chunk -> bank spread 8 groups.
__device__ inline int swz4(int c)  { return c ^ ((c >> 3) & 7); }
__device__ inline int swz16(int c) { return c ^ ((c >> 4) & 7); }

// async global->LDS, 16B per lane (dest = uniform base + lane*16)
#define GLL(g, s)                                             \
  __builtin_amdgcn_global_load_lds(                           \
      (const __attribute__((address_space(1))) void*)(g),     \
      (__attribute__((address_space(3))) void*)(s), 16, 0, 0)

__global__ void k_init(Scal* sc) {
  if (threadIdx.x == 0) {
    sc->mn_bits = 0x7f800000;
    sc->mx_bits = 0xff800000;
    sc->kld_sum = 0.0;
    sc->struct_sum = 0.0;
    sc->traj_sum = 0.0;
  }
}

__global__ void k_minmax(const float* __restrict__ adj, int n, Scal* sc) {
  float lmin = INFINITY, lmax = -INFINITY;
  for (int i = blockIdx.x * blockDim.x + threadIdx.x; i < n;
       i += gridDim.x * blockDim.x) {
    float v = adj[i];
    lmin = fminf(lmin, v);
    lmax = fmaxf(lmax, v);
  }
#pragma unroll
  for (int off = 32; off; off >>= 1) {
    lmin = fminf(lmin, __shfl_xor(lmin, off, 64));
    lmax = fmaxf(lmax, __shfl_xor(lmax, off, 64));
  }
  __shared__ float smn[4], smx[4];
  int w = threadIdx.x >> 6;
  if ((threadIdx.x & 63) == 0) { smn[w] = lmin; smx[w] = lmax; }
  __syncthreads();
  if (threadIdx.x == 0) {
    lmin = fminf(fminf(smn[0], smn[1]), fminf(smn[2], smn[3]));
    lmax = fmaxf(fmaxf(smx[0], smx[1]), fmaxf(smx[2], smx[3]));
    atomicMin(&sc->mn_bits, __float_as_int(lmin));
    atomicMax(&sc->mx_bits, __float_as_int(lmax));
  }
}

__global__ void k_scale(Scal* sc) {
  float mn = fminf(0.0f, __int_as_float(sc->mn_bits));
  float mx = fmaxf(0.0f, __int_as_float(sc->mx_bits));
  sc->Amin = mn;
  sc->invr = 1.0f / (mx - mn);
  sc->c0 = (0.0f - mn) * sc->invr;
}

__global__ void k_dis(const float* __restrict__ adj, const Scal* __restrict__ sc,
                      float* __restrict__ dis) {
  int j = blockIdx.x * 256 + threadIdx.x;
  int t = j >> 8, jj = j & 255;
  const float* a = adj + (size_t)t * 65536;
  float Amin = sc->Amin, invr = sc->invr, c0 = sc->c0;
  float sum = 0.f;
  for (int i = 0; i < 256; ++i) sum += (a[i * 256 + jj] - Amin) * invr;
  float djj = (a[jj * 256 + jj] - Amin) * invr;
  float deg = sum + 1792.0f * c0 + (djj == 0.0f ? 1.0f : 0.0f);
  dis[j] = deg > 0.0f ? 1.0f / sqrtf(deg) : 0.0f;
}

__global__ void k_agg(const float* __restrict__ adj, const Scal* __restrict__ sc,
                      const float* __restrict__ dis, float* __restrict__ agg) {
  int idx = blockIdx.x * 256 + threadIdx.x;
  int t = idx >> 16, i = (idx >> 8) & 255, j = idx & 255;
  float v = (adj[(size_t)t * 65536 + j * 256 + i] - sc->Amin) * sc->invr;
  if (i == j && v == 0.0f) v += 1.0f;
  agg[idx] = dis[t * 256 + j] * v * dis[t * 256 + i];
}

__global__ void k_enc1(const float* __restrict__ traj, const float* __restrict__ w,
                       const float* __restrict__ b, float* __restrict__ out) {
  int idx = blockIdx.x * 256 + threadIdx.x;
  int r = idx >> 7, f = idx & 127;
  float v = traj[r * 2] * w[f * 2] + traj[r * 2 + 1] * w[f * 2 + 1] + b[f];
  out[idx] = fmaxf(v, 0.0f);
}

// fp32 -> bf16 hi/lo, 4 elems/thread
__global__ void k_cvt(const float* __restrict__ src, unsigned short* __restrict__ h,
                      unsigned short* __restrict__ l, int n4) {
  int i = blockIdx.x * 256 + threadIdx.x;
  if (i >= n4) return;
  float4 v = reinterpret_cast<const float4*>(src)[i];
  us4 hh, ll;
  split4(v, hh, ll);
  reinterpret_cast<us4*>(h)[i] = hh;
  reinterpret_cast<us4*>(l)[i] = ll;
}

// ---------------- small fp32 GEMM (front-end, M=2048) ----------------
#define BM 64
#define BN 64
#define KC 32
#define LP 68

template <bool TB>
__global__ __launch_bounds__(256) void gemm_kernel(
    const float* __restrict__ A, const float* __restrict__ B,
    const float* __restrict__ bias, float* __restrict__ C, int K, int ldb,
    int ldc, int flags, size_t aStride, size_t bStride, size_t cStride) {
  if (blockIdx.z) {
    A += (size_t)blockIdx.z * aStride;
    B += (size_t)blockIdx.z * bStride;
    C += (size_t)blockIdx.z * cStride;
  }
  __shared__ float As[KC][LP];
  __shared__ float Bs[KC][LP];
  const int tid = threadIdx.x;
  const int tx = tid & 15, ty = tid >> 4;
  const int m0 = blockIdx.y * BM, n0 = blockIdx.x * BN;
  float acc[4][4] = {};
  for (int k0 = 0; k0 < K; k0 += KC) {
#pragma unroll
    for (int i = 0; i < 2; ++i) {
      int q = tid + i * 256;
      int row = q >> 3, kq = q & 7;
      float4 v = *reinterpret_cast<const float4*>(
          &A[(size_t)(m0 + row) * K + k0 + kq * 4]);
      As[kq * 4 + 0][row] = v.x;
      As[kq * 4 + 1][row] = v.y;
      As[kq * 4 + 2][row] = v.z;
      As[kq * 4 + 3][row] = v.w;
    }
    if (TB) {
#pragma unroll
      for (int i = 0; i < 2; ++i) {
        int q = tid + i * 256;
        int row = q >> 3, kq = q & 7;
        float4 v = *reinterpret_cast<const float4*>(
            &B[(size_t)(n0 + row) * ldb + k0 + kq * 4]);
        Bs[kq * 4 + 0][row] = v.x;
        Bs[kq * 4 + 1][row] = v.y;
        Bs[kq * 4 + 2][row] = v.z;
        Bs[kq * 4 + 3][row] = v.w;
      }
    } else {
#pragma unroll
      for (int i = 0; i < 2; ++i) {
        int q = tid + i * 256;
        int kr = q >> 4, nq = q & 15;
        float4 v = *reinterpret_cast<const float4*>(
            &B[(size_t)(k0 + kr) * ldb + n0 + nq * 4]);
        *reinterpret_cast<float4*>(&Bs[kr][nq * 4]) = v;
      }
    }
    __syncthreads();
#pragma unroll
    for (int kk = 0; kk < KC; ++kk) {
      float4 a4 = *reinterpret_cast<const float4*>(&As[kk][ty * 4]);
      float4 b4 = *reinterpret_cast<const float4*>(&Bs[kk][tx * 4]);
      float av[4] = {a4.x, a4.y, a4.z, a4.w};
      float bv[4] = {b4.x, b4.y, b4.z, b4.w};
#pragma unroll
      for (int i = 0; i < 4; ++i)
#pragma unroll
        for (int j = 0; j < 4; ++j) acc[i][j] += av[i] * bv[j];
    }
    __syncthreads();
  }
  float bv[4] = {0.f, 0.f, 0.f, 0.f};
  if (bias) {
    float4 b4 = *reinterpret_cast<const float4*>(&bias[n0 + tx * 4]);
    bv[0] = b4.x; bv[1] = b4.y; bv[2] = b4.z; bv[3] = b4.w;
  }
#pragma unroll
  for (int i = 0; i < 4; ++i) {
    float* cp = &C[(size_t)(m0 + ty * 4 + i) * ldc + n0 + tx * 4];
    float4 o;
    float ov[4];
#pragma unroll
    for (int j = 0; j < 4; ++j) ov[j] = acc[i][j] + bv[j];
    if (flags & 2) {
      float4 old = *reinterpret_cast<const float4*>(cp);
      ov[0] += old.x; ov[1] += old.y; ov[2] += old.z; ov[3] += old.w;
    }
    if (flags & 1) {
#pragma unroll
      for (int j = 0; j < 4; ++j) ov[j] = fmaxf(ov[j], 0.0f);
    }
    o.x = ov[0]; o.y = ov[1]; o.z = ov[2]; o.w = ov[3];
    *reinterpret_cast<float4*>(cp) = o;
  }
}

// ---------------- MFMA split-bf16 GEMM (qkv / out-proj) ----------------
// C(M,N) = (Ah+Al)(M,K) @ (Bh+Bl)(N,K)^T + bias.  Tile BMb x BNb, BK=32,
// 4 waves (2x2).  global_load_lds staging, swizzled (swz4, both sides).
// flags: 1=relu  2=acc into fp32 C.
template <int BMb, int BNb>
__global__ __launch_bounds__(256) void gemm_bf(
    const unsigned short* __restrict__ Ah, const unsigned short* __restrict__ Al,
    const unsigned short* __restrict__ Bh, const unsigned short* __restrict__ Bl,
    const float* __restrict__ bias, float* __restrict__ C,
    int K, int lda, int ldb, int ldc, int flags) {
  constexpr int MI = BMb / 32, NI = BNb / 32;
  constexpr int WTM = BMb / 2, WTN = BNb / 2;
  __shared__ unsigned short sAh[BMb * 32], sAl[BMb * 32];
  __shared__ unsigned short sBh[BNb * 32], sBl[BNb * 32];
  const int tid = threadIdx.x, lane = tid & 63, w = tid >> 6;
  const int wr = w >> 1, wc = w & 1;
  const int m0 = blockIdx.y * BMb, n0 = blockIdx.x * BNb;
  f32x4 acc[MI][NI];
#pragma unroll
  for (int i = 0; i < MI; ++i)
#pragma unroll
    for (int j = 0; j < NI; ++j) acc[i][j] = (f32x4){0.f, 0.f, 0.f, 0.f};

  for (int k0 = 0; k0 < K; k0 += 32) {
#pragma unroll
    for (int i = 0; i < BMb / 64; ++i) {
      int c = tid + i * 256;
      int g = swz4(c);
      int row = g >> 2, c4 = g & 3;
      size_t ga = (size_t)(m0 + row) * lda + k0 + c4 * 8;
      GLL(&Ah[ga], &sAh[c * 8]);
      GLL(&Al[ga], &sAl[c * 8]);
    }
#pragma unroll
    for (int i = 0; i < BNb / 64; ++i) {
      int c = tid + i * 256;
      int g = swz4(c);
      int row = g >> 2, c4 = g & 3;
      size_t ga = (size_t)(n0 + row) * ldb + k0 + c4 * 8;
      GLL(&Bh[ga], &sBh[c * 8]);
      GLL(&Bl[ga], &sBl[c * 8]);
    }
    __syncthreads();
    bf16x8 bh[NI], bl[NI];
#pragma unroll
    for (int ni = 0; ni < NI; ++ni) {
      int p = swz4((wc * WTN + ni * 16 + (lane & 15)) * 4 + (lane >> 4));
      bh[ni] = *reinterpret_cast<const bf16x8*>(&sBh[p * 8]);
      bl[ni] = *reinterpret_cast<const bf16x8*>(&sBl[p * 8]);
    }
#pragma unroll
    for (int mi = 0; mi < MI; ++mi) {
      int p = swz4((wr * WTM + mi * 16 + (lane & 15)) * 4 + (lane >> 4));
      bf16x8 ah = *reinterpret_cast<const bf16x8*>(&sAh[p * 8]);
      bf16x8 al = *reinterpret_cast<const bf16x8*>(&sAl[p * 8]);
#pragma unroll
      for (int ni = 0; ni < NI; ++ni) {
        acc[mi][ni] = __builtin_amdgcn_mfma_f32_16x16x32_bf16(
            ah, bh[ni], acc[mi][ni], 0, 0, 0);
        acc[mi][ni] = __builtin_amdgcn_mfma_f32_16x16x32_bf16(
            ah, bl[ni], acc[mi][ni], 0, 0, 0);
        acc[mi][ni] = __builtin_amdgcn_mfma_f32_16x16x32_bf16(
            al, bh[ni], acc[mi][ni], 0, 0, 0);
      }
    }
    __syncthreads();
  }
  const int crow0 = m0 + wr * WTM + (lane >> 4) * 4;
  const int ccol0 = n0 + wc * WTN + (lane & 15);
#pragma unroll
  for (int ni = 0; ni < NI; ++ni) {
    int col = ccol0 + ni * 16;
    float bv = bias ? bias[col] : 0.f;
#pragma unroll
    for (int mi = 0; mi < MI; ++mi) {
#pragma unroll
      for (int r = 0; r < 4; ++r) {
        int row = crow0 + mi * 16 + r;
        float v = acc[mi][ni][r] + bv;
        if (flags & 2) v += C[(size_t)row * ldc + col];
        if (flags & 1) v = fmaxf(v, 0.0f);
        C[(size_t)row * ldc + col] = v;
      }
    }
  }
}

// ---------------- fused FFN: tmp = relu(X@W1^T + b1) @ W2^T + b2 ----------
// One block per 64 rows, all 128 out cols.  X-block staged once, X A-frags
// hoisted to registers.  64 f-chunks of 32: stage W1/W2 chunk -> GEMM1 ->
// P hi/lo to LDS -> GEMM2 accumulate.  Fs never hits global.
__global__ __launch_bounds__(256) void k_ffn(
    const unsigned short* __restrict__ Xh, const unsigned short* __restrict__ Xl,
    const unsigned short* __restrict__ W1h, const unsigned short* __restrict__ W1l,
    const float* __restrict__ b1,
    const unsigned short* __restrict__ W2h, const unsigned short* __restrict__ W2l,
    const float* __restrict__ b2, float* __restrict__ out) {
  __shared__ unsigned short sXh[64 * 128], sXl[64 * 128];   // 16 KB each
  __shared__ unsigned short sW1h[32 * 128], sW1l[32 * 128]; // 8 KB each
  __shared__ unsigned short sPh[64 * 32], sPl[64 * 32];     // 4 KB each
  __shared__ unsigned short sW2h[128 * 32], sW2l[128 * 32]; // 8 KB each
  const int tid = threadIdx.x, lane = tid & 63, w = tid >> 6;
  const int wr = w >> 1, wc = w & 1;
  const int m0 = blockIdx.x * 64;
  // stage X block (64x128 hi/lo), swz16
#pragma unroll
  for (int i = 0; i < 4; ++i) {
    int c = tid + i * 256;
    int g = swz16(c);
    size_t ga = (size_t)(m0 + (g >> 4)) * 128 + (g & 15) * 8;
    GLL(&Xh[ga], &sXh[c * 8]);
    GLL(&Xl[ga], &sXl[c * 8]);
  }
  __syncthreads();
  // hoist X A-fragments [kstep][mi]
  bf16x8 xah[4][2], xal[4][2];
#pragma unroll
  for (int ks = 0; ks < 4; ++ks)
#pragma unroll
    for (int mi = 0; mi < 2; ++mi) {
      int row = wr * 32 + mi * 16 + (lane & 15);
      int p = swz16(row * 16 + ks * 4 + (lane >> 4));
      xah[ks][mi] = *reinterpret_cast<const bf16x8*>(&sXh[p * 8]);
      xal[ks][mi] = *reinterpret_cast<const bf16x8*>(&sXl[p * 8]);
    }
  f32x4 acc2[2][4];
#pragma unroll
  for (int i = 0; i < 2; ++i)
#pragma unroll
    for (int j = 0; j < 4; ++j) acc2[i][j] = (f32x4){0.f, 0.f, 0.f, 0.f};

  const int pcol = wc * 16 + (lane & 15);
  for (int fc = 0; fc < 64; ++fc) {
    const int f0 = fc * 32;
    // stage W1 chunk (32x128, swz16) and W2 chunk (128x32, swz4)
#pragma unroll
    for (int i = 0; i < 2; ++i) {
      int c = tid + i * 256;
      {
        int g = swz16(c);
        size_t ga = (size_t)(f0 + (g >> 4)) * 128 + (g & 15) * 8;
        GLL(&W1h[ga], &sW1h[c * 8]);
        GLL(&W1l[ga], &sW1l[c * 8]);
      }
      {
        int g = swz4(c);
        size_t ga = (size_t)(g >> 2) * 2048 + f0 + (g & 3) * 8;
        GLL(&W2h[ga], &sW2h[c * 8]);
        GLL(&W2l[ga], &sW2l[c * 8]);
      }
    }
    __syncthreads();  // A: stage complete
    // GEMM1: P(64x32) = X(64x128) @ W1c(32x128)^T
    f32x4 acc1[2];
    acc1[0] = (f32x4){0.f, 0.f, 0.f, 0.f};
    acc1[1] = (f32x4){0.f, 0.f, 0.f, 0.f};
#pragma unroll
    for (int ks = 0; ks < 4; ++ks) {
      int p = swz16((wc * 16 + (lane & 15)) * 16 + ks * 4 + (lane >> 4));
      bf16x8 bh = *reinterpret_cast<const bf16x8*>(&sW1h[p * 8]);
      bf16x8 bl = *reinterpret_cast<const bf16x8*>(&sW1l[p * 8]);
#pragma unroll
      for (int mi = 0; mi < 2; ++mi) {
        acc1[mi] = __builtin_amdgcn_mfma_f32_16x16x32_bf16(xah[ks][mi], bh,
                                                           acc1[mi], 0, 0, 0);
        acc1[mi] = __builtin_amdgcn_mfma_f32_16x16x32_bf16(xah[ks][mi], bl,
                                                           acc1[mi], 0, 0, 0);
        acc1[mi] = __builtin_amdgcn_mfma_f32_16x16x32_bf16(xal[ks][mi], bh,
                                                           acc1[mi], 0, 0, 0);
      }
    }
    // P epilogue: bias, relu, hi/lo split, swizzled LDS write
    float b1v = b1[f0 + pcol];
#pragma unroll
    for (int mi = 0; mi < 2; ++mi)
#pragma unroll
      for (int r = 0; r < 4; ++r) {
        int prow = wr * 32 + mi * 16 + (lane >> 4) * 4 + r;
        float v = fmaxf(acc1[mi][r] + b1v, 0.0f);
        unsigned short h = f2bf(v);
        int p = swz4(prow * 4 + (pcol >> 3));
        sPh[p * 8 + (pcol & 7)] = h;
        sPl[p * 8 + (pcol & 7)] = f2bf(v - bf2f(h));
      }
    __syncthreads();  // B: P visible
    // GEMM2: acc2 += P(64x32) @ W2c(128x32)^T
    bf16x8 pah[2], pal[2];
#pragma unroll
    for (int mi = 0; mi < 2; ++mi) {
      int p = swz4((wr * 32 + mi * 16 + (lane & 15)) * 4 + (lane >> 4));
      pah[mi] = *reinterpret_cast<const bf16x8*>(&sPh[p * 8]);
      pal[mi] = *reinterpret_cast<const bf16x8*>(&sPl[p * 8]);
    }
#pragma unroll
    for (int ni = 0; ni < 4; ++ni) {
      int p = swz4((wc * 64 + ni * 16 + (lane & 15)) * 4 + (lane >> 4));
      bf16x8 bh = *reinterpret_cast<const bf16x8*>(&sW2h[p * 8]);
      bf16x8 bl = *reinterpret_cast<const bf16x8*>(&sW2l[p * 8]);
#pragma unroll
      for (int mi = 0; mi < 2; ++mi) {
        acc2[mi][ni] = __builtin_amdgcn_mfma_f32_16x16x32_bf16(
            pah[mi], bh, acc2[mi][ni], 0, 0, 0);
        acc2[mi][ni] = __builtin_amdgcn_mfma_f32_16x16x32_bf16(
            pah[mi], bl, acc2[mi][ni], 0, 0, 0);
        acc2[mi][ni] = __builtin_amdgcn_mfma_f32_16x16x32_bf16(
            pal[mi], bh, acc2[mi][ni], 0, 0, 0);
      }
    }
    __syncthreads();  // C: reads done before next stage overwrites
  }
  // epilogue: out = acc2 + b2
#pragma unroll
  for (int ni = 0; ni < 4; ++ni) {
    int col = wc * 64 + ni * 16 + (lane & 15);
    float bv = b2[col];
#pragma unroll
    for (int mi = 0; mi < 2; ++mi)
#pragma unroll
      for (int r = 0; r < 4; ++r) {
        int row = m0 + wr * 32 + mi * 16 + (lane >> 4) * 4 + r;
        out[(size_t)row * 128 + col] = acc2[mi][ni][r] + bv;
      }
  }
}

__global__ void k_zkld(const float* __restrict__ mu, const float* __restrict__ lsr,
                       const float* __restrict__ eps, const int* __restrict__ iftrain,
                       float* __restrict__ Z, Scal* sc) {
  int i = blockIdx.x * 256 + threadIdx.x;
  float m = mu[i];
  float ls = fminf(lsr[i], 10.0f);
  float z = (*iftrain > 0) ? m + eps[i] * __expf(ls) : m;
  Z[i] = z;
  float kt = 1.0f + 2.0f * ls - m * m - __expf(2.0f * ls);
  kt = waveReduceSum(kt);
  __shared__ float sh[4];
  int w = threadIdx.x >> 6;
  if ((threadIdx.x & 63) == 0) sh[w] = kt;
  __syncthreads();
  if (threadIdx.x == 0)
    atomicAdd(&sc->kld_sum, (double)(sh[0] + sh[1] + sh[2] + sh[3]));
}

__global__ __launch_bounds__(256) void k_struct(const float* __restrict__ Z,
                                                const float* __restrict__ adj,
                                                Scal* sc) {
  __shared__ float As[KC][LP];
  __shared__ float Bs[KC][LP];
  const int tid = threadIdx.x;
  const int tx = tid & 15, ty = tid >> 4;
  const int m0 = blockIdx.y * BM, n0 = blockIdx.x * BN;
  float acc[4][4] = {};
  for (int k0 = 0; k0 < kH; k0 += KC) {
#pragma unroll
    for (int i = 0; i < 2; ++i) {
      int q = tid + i * 256;
      int row = q >> 3, kq = q & 7;
      float4 va = *reinterpret_cast<const float4*>(
          &Z[(size_t)(m0 + row) * kH + k0 + kq * 4]);
      As[kq * 4 + 0][row] = va.x;
      As[kq * 4 + 1][row] = va.y;
      As[kq * 4 + 2][row] = va.z;
      As[kq * 4 + 3][row] = va.w;
      float4 vb = *reinterpret_cast<const float4*>(
          &Z[(size_t)(n0 + row) * kH + k0 + kq * 4]);
      Bs[kq * 4 + 0][row] = vb.x;
      Bs[kq * 4 + 1][row] = vb.y;
      Bs[kq * 4 + 2][row] = vb.z;
      Bs[kq * 4 + 3][row] = vb.w;
    }
    __syncthreads();
#pragma unroll
    for (int kk = 0; kk < KC; ++kk) {
      float4 a4 = *reinterpret_cast<const float4*>(&As[kk][ty * 4]);
      float4 b4 = *reinterpret_cast<const float4*>(&Bs[kk][tx * 4]);
      float av[4] = {a4.x, a4.y, a4.z, a4.w};
      float bv[4] = {b4.x, b4.y, b4.z, b4.w};
#pragma unroll
      for (int i = 0; i < 4; ++i)
#pragma unroll
        for (int j = 0; j < 4; ++j) acc[i][j] += av[i] * bv[j];
    }
    __syncthreads();
  }
  float Amin = sc->Amin, invr = sc->invr, c0v = sc->c0;
  float lsum = 0.f;
#pragma unroll
  for (int i = 0; i < 4; ++i) {
#pragma unroll
    for (int j = 0; j < 4; ++j) {
      int gi = m0 + ty * 4 + i, gj = n0 + tx * 4 + j;
      float l = acc[i][j];
      float adjv = c0v;
      if ((gi >> 8) == (gj >> 8))
        adjv = (adj[((size_t)(gi >> 8) << 16) + (gi & 255) * 256 + (gj & 255)] -
                Amin) * invr;
      lsum += fmaxf(l, 0.0f) - l * adjv + __logf(1.0f + __expf(-fabsf(l)));
    }
  }
  lsum = waveReduceSum(lsum);
  __shared__ float sh[4];
  int w = threadIdx.x >> 6;
  if ((threadIdx.x & 63) == 0) sh[w] = lsum;
  __syncthreads();
  if (threadIdx.x == 0)
    atomicAdd(&sc->struct_sum, (double)(sh[0] + sh[1] + sh[2] + sh[3]));
}

__global__ void k_x0(const float* __restrict__ gdl, const float* __restrict__ w3,
                     const float* __restrict__ b3, float* __restrict__ X,
                     unsigned short* __restrict__ Xh,
                     unsigned short* __restrict__ Xl) {
  int f = threadIdx.x;
  size_t r = (size_t)blockIdx.x * 2 + threadIdx.y;
  int n = (int)(r >> 7), h = (int)(r & 127);
  float a = b3[f];
#pragma unroll
  for (int o = 0; o < 8; ++o)
    a += gdl[((size_t)o * 256 + n) * 128 + h] * w3[f * 8 + o];
  X[r * 128 + f] = a;
  unsigned short hh = f2bf(a);
  Xh[r * 128 + f] = hh;
  Xl[r * 128 + f] = f2bf(a - bf2f(hh));
}

// attention: one block per (head,b); 256 threads, 1 q-row each.  Single-pass
// online softmax w/ deferred rescale (THR=8).  Writes O as bf16 hi/lo.
__global__ __launch_bounds__(256) void k_attn(const float* __restrict__ QKV,
                                              unsigned short* __restrict__ Oh,
                                              unsigned short* __restrict__ Ol) {
  const int head = blockIdx.x, b = blockIdx.y;
  const int s = threadIdx.x;  // 0..255
  __shared__ float ks[256][16];
  __shared__ float vs[256][16];
  const size_t base = ((size_t)s * 128 + b) * 384 + head * 16;
#pragma unroll
  for (int i = 0; i < 4; ++i) {
    *reinterpret_cast<float4*>(&ks[s][i * 4]) =
        *reinterpret_cast<const float4*>(&QKV[base + 128 + i * 4]);
    *reinterpret_cast<float4*>(&vs[s][i * 4]) =
        *reinterpret_cast<const float4*>(&QKV[base + 256 + i * 4]);
  }
  float q[16];
#pragma unroll
  for (int i = 0; i < 4; ++i) {
    float4 v = *reinterpret_cast<const float4*>(&QKV[base + i * 4]);
    q[i * 4 + 0] = v.x * 0.25f; q[i * 4 + 1] = v.y * 0.25f;
    q[i * 4 + 2] = v.z * 0.25f; q[i * 4 + 3] = v.w * 0.25f;
  }
  __syncthreads();
  float m = -1e30f, lsum = 0.f;
  float o[16] = {};
#pragma unroll 2
  for (int t = 0; t < 256; ++t) {
    float kv[16], vv[16];
#pragma unroll
    for (int i = 0; i < 4; ++i) {
      float4 k4 = *reinterpret_cast<const float4*>(&ks[t][i * 4]);
      float4 v4 = *reinterpret_cast<const float4*>(&vs[t][i * 4]);
      kv[i * 4 + 0] = k4.x; kv[i * 4 + 1] = k4.y;
      kv[i * 4 + 2] = k4.z; kv[i * 4 + 3] = k4.w;
      vv[i * 4 + 0] = v4.x; vv[i * 4 + 1] = v4.y;
      vv[i * 4 + 2] = v4.z; vv[i * 4 + 3] = v4.w;
    }
    float d = 0.f;
#pragma unroll
    for (int i = 0; i < 16; ++i) d += q[i] * kv[i];
    if (d > m + 8.f) {            // deferred rescale (T13)
      float c = __expf(m - d);
      lsum *= c;
#pragma unroll
      for (int i = 0; i < 16; ++i) o[i] *= c;
      m = d;
    }
    float p = __expf(d - m);
    lsum += p;
#pragma unroll
    for (int i = 0; i < 16; ++i) o[i] += p * vv[i];
  }
  float inv = 1.0f / lsum;
  size_t ob = ((size_t)s * 128 + b) * 128 + head * 16;
#pragma unroll
  for (int i = 0; i < 4; ++i) {
    float4 v;
    v.x = o[i * 4 + 0] * inv; v.y = o[i * 4 + 1] * inv;
    v.z = o[i * 4 + 2] * inv; v.w = o[i * 4 + 3] * inv;
    us4 hh, ll;
    split4(v, hh, ll);
    *reinterpret_cast<us4*>(&Oh[ob + i * 4]) = hh;
    *reinterpret_cast<us4*>(&Ol[ob + i * 4]) = ll;
  }
}

// X = LN(X + T); also emits Xh/Xl bf16 hi/lo
__global__ __launch_bounds__(256) void k_resid_ln(
    float* __restrict__ X, const float* __restrict__ T,
    const float* __restrict__ g, const float* __restrict__ b,
    unsigned short* __restrict__ Xh, unsigned short* __restrict__ Xl) {
  int lane = threadIdx.x & 63, rl = threadIdx.x >> 6;
  size_t row = (size_t)blockIdx.x * 4 + rl;
  float* xp = X + row * 128;
  const float* tp = T + row * 128;
  float e0 = xp[lane] + tp[lane];
  float e1 = xp[lane + 64] + tp[lane + 64];
  float mean = waveReduceSum(e0 + e1) * 0.0078125f;
  float d0 = e0 - mean, d1 = e1 - mean;
  float var = waveReduceSum(d0 * d0 + d1 * d1) * 0.0078125f;
  float inv = 1.0f / sqrtf(var + 1e-5f);
  float v0 = d0 * inv * g[lane] + b[lane];
  float v1 = d1 * inv * g[lane + 64] + b[lane + 64];
  xp[lane] = v0;
  xp[lane + 64] = v1;
  unsigned short h0 = f2bf(v0), h1 = f2bf(v1);
  Xh[row * 128 + lane] = h0;
  Xl[row * 128 + lane] = f2bf(v0 - bf2f(h0));
  Xh[row * 128 + lane + 64] = h1;
  Xl[row * 128 + lane + 64] = f2bf(v1 - bf2f(h1));
}

__global__ void k_heady(const float* __restrict__ X, const float* __restrict__ w4,
                        const float* __restrict__ b4, float* __restrict__ y) {
  int tid = threadIdx.x;
  int o = tid & 7, rl = tid >> 3;
  size_t r = (size_t)blockIdx.x * 32 + rl;
  const float* xp = X + r * 128;
  const float* wp = w4 + o * 128;
  float a = b4[o];
  for (int f = 0; f < 128; f += 4)
    a += xp[f] * wp[f] + xp[f + 1] * wp[f + 1] + xp[f + 2] * wp[f + 2] +
         xp[f + 3] * wp[f + 3];
  y[r * 8 + o] = a;
}

__global__ void k_traj(const float* __restrict__ y, const float* __restrict__ w5,
                       const float* __restrict__ b5,
                       const float* __restrict__ traj_in, float* __restrict__ dout,
                       Scal* sc) {
  int n = blockIdx.x, lane = threadIdx.x;
  float w0a = w5[lane], w0b = w5[lane + 64];
  float w1a = w5[128 + lane], w1b = w5[128 + lane + 64];
  float dsum = 0.f;
  for (int oi = 0; oi < 4; ++oi) {
    int o = 4 + oi;
    float ya = y[((size_t)n * 128 + lane) * 8 + o];
    float yb = y[((size_t)n * 128 + lane + 64) * 8 + o];
    float s0 = waveReduceSum(w0a * ya + w0b * yb);
    float s1 = waveReduceSum(w1a * ya + w1b * yb);
    if (lane == 0) {
      float t0 = s0 + b5[0], t1 = s1 + b5[1];
      dout[oi * 512 + n * 2 + 0] = t0;
      dout[oi * 512 + n * 2 + 1] = t1;
      float dx = t0 - traj_in[((8 + oi) * 256 + n) * 2 + 0];
      float dy = t1 - traj_in[((8 + oi) * 256 + n) * 2 + 1];
      dsum += sqrtf(dx * dx + dy * dy);
    }
  }
  if (lane == 0) atomicAdd(&sc->traj_sum, (double)dsum);
}

__global__ void k_loss(const Scal* sc, float* dout) {
  if (threadIdx.x == 0) {
    double traj_loss = sc->traj_sum / 256.0;
    double kld = -0.5 * sc->kld_sum / 2048.0;
    double st = sc->struct_sum / (2048.0 * 2048.0);
    dout[2048] = (float)(traj_loss + kld + st);
  }
}

}  // namespace

extern "C" void kernel_launch(void* const* d_in, const int* in_sizes, int n_in,
                              void* d_out, int out_size, void* d_ws,
                              size_t ws_size, hipStream_t stream) {
  (void)in_sizes; (void)n_in; (void)out_size; (void)ws_size;
  const float* traj_in = (const float*)d_in[0];
  const float* adj     = (const float*)d_in[1];
  const float* eps     = (const float*)d_in[2];
  const float* pro1_w  = (const float*)d_in[3];
  const float* pro1_b  = (const float*)d_in[4];
  const float* pro2_w  = (const float*)d_in[5];
  const float* pro2_b  = (const float*)d_in[6];
  const float* mu_w    = (const float*)d_in[7];
  const float* mu_b    = (const float*)d_in[8];
  const float* ls_w    = (const float*)d_in[9];
  const float* ls_b    = (const float*)d_in[10];
  const float* gdl_w   = (const float*)d_in[11];
  const float* gdl_b   = (const float*)d_in[12];
  const float* pro3_w  = (const float*)d_in[13];
  const float* pro3_b  = (const float*)d_in[14];
  const float* pro4_w  = (const float*)d_in[15];
  const float* pro4_b  = (const float*)d_in[16];
  const float* pro5_w  = (const float*)d_in[17];
  const float* pro5_b  = (const float*)d_in[18];
  const float* qkv_w   = (const float*)d_in[19];
  const float* qkv_b   = (const float*)d_in[20];
  const float* outp_w  = (const float*)d_in[21];
  const float* outp_b  = (const float*)d_in[22];
  const float* ff1_w   = (const float*)d_in[23];
  const float* ff1_b   = (const float*)d_in[24];
  const float* ff2_w   = (const float*)d_in[25];
  const float* ff2_b   = (const float*)d_in[26];
  const float* ln1_g   = (const float*)d_in[27];
  const float* ln1_b   = (const float*)d_in[28];
  const float* ln2_g   = (const float*)d_in[29];
  const float* ln2_b   = (const float*)d_in[30];
  const int*   iftrain = (const int*)d_in[31];
  float* dout = (float*)d_out;

  char* wsb = (char*)d_ws;
  size_t off = 0;
  auto alloc = [&](size_t bytes) {
    char* p = wsb + off;
    off += (bytes + 255) & ~(size_t)255;
    return p;
  };
  Scal* sc    = (Scal*)alloc(256);
  float* dis  = (float*)alloc(kGN * 4);
  float* agg  = (float*)alloc((size_t)kOBS * 65536 * 4);
  float* enc1 = (float*)alloc((size_t)kGN * kH * 4);
  float* enc  = (float*)alloc((size_t)kGN * kH * 4);
  float* Mmu  = (float*)alloc((size_t)kGN * kH * 4);
  float* Mls  = (float*)alloc((size_t)kGN * kH * 4);
  float* mu   = (float*)alloc((size_t)kGN * kH * 4);
  float* lsb  = (float*)alloc((size_t)kGN * kH * 4);
  float* Z    = (float*)alloc((size_t)kGN * kH * 4);
  float* gdl  = (float*)alloc((size_t)kGN * kH * 4);
  float* X    = (float*)alloc((size_t)kROWS * kH * 4);
  unsigned short* Xh = (unsigned short*)alloc((size_t)kROWS * kH * 2);
  unsigned short* Xl = (unsigned short*)alloc((size_t)kROWS * kH * 2);
  float* QKV = (float*)alloc((size_t)kROWS * 384 * 4);
  unsigned short* Oh = (unsigned short*)alloc((size_t)kROWS * kH * 2);
  unsigned short* Ol = (unsigned short*)alloc((size_t)kROWS * kH * 2);
  float* tmp  = (float*)alloc((size_t)kROWS * kH * 4);
  float* y    = (float*)alloc((size_t)kROWS * 8 * 4);
  unsigned short* qkvWh = (unsigned short*)alloc(6 * 384 * 128 * 2);
  unsigned short* qkvWl = (unsigned short*)alloc(6 * 384 * 128 * 2);
  unsigned short* outWh = (unsigned short*)alloc(6 * 128 * 128 * 2);
  unsigned short* outWl = (unsigned short*)alloc(6 * 128 * 128 * 2);
  unsigned short* ff1Wh = (unsigned short*)alloc(6 * 2048 * 128 * 2);
  unsigned short* ff1Wl = (unsigned short*)alloc(6 * 2048 * 128 * 2);
  unsigned short* ff2Wh = (unsigned short*)alloc(6 * 128 * 2048 * 2);
  unsigned short* ff2Wl = (unsigned short*)alloc(6 * 128 * 2048 * 2);

  auto gemm_nt_small = [&](const float* A, const float* B, const float* bias,
                           float* C, int M, int N, int K, int ldb, int ldc,
                           int flags) {
    dim3 g(N / 64, M / 64, 1);
    gemm_kernel<true><<<g, 256, 0, stream>>>(A, B, bias, C, K, ldb, ldc, flags,
                                             (size_t)0, (size_t)0, (size_t)0);
  };

  // one-time weight conversions
  k_cvt<<<(6 * 384 * 128 / 4 + 255) / 256, 256, 0, stream>>>(
      qkv_w, qkvWh, qkvWl, 6 * 384 * 128 / 4);
  k_cvt<<<(6 * 128 * 128 / 4 + 255) / 256, 256, 0, stream>>>(
      outp_w, outWh, outWl, 6 * 128 * 128 / 4);
  k_cvt<<<(6 * 2048 * 128 / 4 + 255) / 256, 256, 0, stream>>>(
      ff1_w, ff1Wh, ff1Wl, 6 * 2048 * 128 / 4);
  k_cvt<<<(6 * 128 * 2048 / 4 + 255) / 256, 256, 0, stream>>>(
      ff2_w, ff2Wh, ff2Wl, 6 * 128 * 2048 / 4);

  k_init<<<1, 64, 0, stream>>>(sc);
  k_minmax<<<512, 256, 0, stream>>>(adj, kOBS * kNAG * kNAG, sc);
  k_scale<<<1, 1, 0, stream>>>(sc);
  k_dis<<<8, 256, 0, stream>>>(adj, sc, dis);
  k_agg<<<2048, 256, 0, stream>>>(adj, sc, dis, agg);

  k_enc1<<<(kGN * kH) / 256, 256, 0, stream>>>(traj_in, pro1_w, pro1_b, enc1);
  gemm_nt_small(enc1, pro2_w, pro2_b, enc, kGN, kH, kH, kH, kH, 0);
  gemm_nt_small(enc, mu_w, mu_b, Mmu, kGN, kH, kH, kH, kH, 0);
  gemm_nt_small(enc, ls_w, ls_b, Mls, kGN, kH, kH, kH, kH, 0);
  {
    dim3 g(kH / 64, kNAG / 64, kOBS);
    gemm_kernel<false><<<g, 256, 0, stream>>>(agg, Mmu, nullptr, mu, kNAG, kH,
                                              kH, 0, (size_t)65536,
                                              (size_t)kNAG * kH, (size_t)kNAG * kH);
    gemm_kernel<false><<<g, 256, 0, stream>>>(agg, Mls, nullptr, lsb, kNAG, kH,
                                              kH, 0, (size_t)65536,
                                              (size_t)kNAG * kH, (size_t)kNAG * kH);
  }
  k_zkld<<<(kGN * kH) / 256, 256, 0, stream>>>(mu, lsb, eps, iftrain, Z, sc);
  gemm_nt_small(Z, gdl_w, gdl_b, gdl, kGN, kH, kH, kH, kH, 0);
  k_struct<<<dim3(kGN / 64, kGN / 64), 256, 0, stream>>>(Z, adj, sc);
  k_x0<<<kROWS / 2, dim3(128, 2), 0, stream>>>(gdl, pro3_w, pro3_b, X, Xh, Xl);

  for (int l = 0; l < 6; ++l) {
    // qkv: (32768,384) = X @ Wqkv^T  -> fp32 QKV
    gemm_bf<128, 128><<<dim3(3, kROWS / 128), 256, 0, stream>>>(
        Xh, Xl, qkvWh + (size_t)l * 384 * 128, qkvWl + (size_t)l * 384 * 128,
        qkv_b + l * 384, QKV, 128, 128, 128, 384, 0);
    k_attn<<<dim3(8, 128), 256, 0, stream>>>(QKV, Oh, Ol);
    // out-proj: (32768,128) -> fp32 tmp
    gemm_bf<64, 128><<<dim3(1, kROWS / 64), 256, 0, stream>>>(
        Oh, Ol, outWh + (size_t)l * 128 * 128, outWl + (size_t)l * 128 * 128,
        outp_b + l * 128, tmp, 128, 128, 128, 128, 0);
    k_resid_ln<<<kROWS / 4, 256, 0, stream>>>(X, tmp, ln1_g + l * kH,
                                              ln1_b + l * kH, Xh, Xl);
    // fused FFN -> fp32 tmp
    k_ffn<<<kROWS / 64, 256, 0, stream>>>(
        Xh, Xl, ff1Wh + (size_t)l * 2048 * 128, ff1Wl + (size_t)l * 2048 * 128,
        ff1_b + l * 2048, ff2Wh + (size_t)l * 128 * 2048,
        ff2Wl + (size_t)l * 128 * 2048, ff2_b + l * 128, tmp);
    k_resid_ln<<<kROWS / 4, 256, 0, stream>>>(X, tmp, ln2_g + l * kH,
                                              ln2_b + l * kH, Xh, Xl);
  }

  k_heady<<<kROWS / 32, 256, 0, stream>>>(X, pro4_w, pro4_b, y);
  k_traj<<<kNAG, 64, 0, stream>>>(y, pro5_w, pro5_b, traj_in, dout, sc);
  k_loss<<<1, 1, 0, stream>>>(sc, dout);
}

// Round 7
// 1912.793 us; speedup vs baseline: 2.5090x; 1.0321x over previous
//
#include <hip/hip_runtime.h>
#include <math.h>

// GVAE-Transformer forward. fp32 interfaces; transformer matmuls on MFMA via
// split-bf16 (3-term: ah*bh + ah*bl + al*bh, fp32 accum), pre-converted
// inputs, global_load_lds staging with involution-swizzled LDS.
// Shapes: OBS=8 PRED=4 NAG=256 FIN=2 FOUT=2 H=128 NH=8 FF=2048 NL=6.
//
// R7 changes vs R6 (1974 us; k_ffn 146us x6 stall-bound: MfmaUtil 31%,
// VALU 31%, hbm 3% -> barrier-drain stalls):
//  - k_ffn: T3/T4 double-buffered W staging. STAGE(fc+1) issued before
//    compute(fc); counted `s_waitcnt vmcnt(8)` + raw s_barrier (no vmcnt(0)
//    drain). X-staging LDS aliased with W-buffer1 (dead after reg-hoist);
//    b1 moved to LDS (a global read in-loop would force a vmcnt drain).
//    80KB LDS -> still 2 blocks/CU.

namespace {

constexpr int kOBS = 8, kNAG = 256, kH = 128;
constexpr int kGN = kOBS * kNAG;   // 2048 graph nodes
constexpr int kROWS = kNAG * kH;   // 32768 transformer rows (S=256, B=128)

typedef __attribute__((ext_vector_type(8))) short bf16x8;
typedef __attribute__((ext_vector_type(4))) float f32x4;
typedef __attribute__((ext_vector_type(4))) unsigned short us4;

struct Scal {
  int    mn_bits;
  int    mx_bits;
  float  Amin;
  float  invr;
  float  c0;
  int    pad;
  double kld_sum;
  double struct_sum;
  double traj_sum;
};

__device__ inline float waveReduceSum(float v) {
#pragma unroll
  for (int off = 32; off; off >>= 1) v += __shfl_xor(v, off, 64);
  return v;
}

__device__ inline unsigned short f2bf(float f) {  // RNE fp32 -> bf16
  unsigned u = __float_as_uint(f);
  return (unsigned short)((u + 0x7fffu + ((u >> 16) & 1u)) >> 16);
}
__device__ inline float bf2f(unsigned short h) {
  return __uint_as_float((unsigned)h << 16);
}
__device__ inline void split4(float4 v, us4& h, us4& l) {
  h.x = f2bf(v.x); l.x = f2bf(v.x - bf2f(h.x));
  h.y = f2bf(v.y); l.y = f2bf(v.y - bf2f(h.y));
  h.z = f2bf(v.z); l.z = f2bf(v.z - bf2f(h.z));
  h.w = f2bf(v.w); l.w = f2bf(v.w - bf2f(h.w));
}

// involution chunk swizzles (16B chunk index c).  swz4: rows of 4 chunks
// (32 shorts); swz16: rows of 16 chunks (128 shorts).  Applied to BOTH the
// global source chunk (staging) and the read chunk -> bank spread 8 groups.
__device__ inline int swz4(int c)  { return c ^ ((c >> 3) & 7); }
__device__ inline int swz16(int c) { return c ^ ((c >> 4) & 7); }

// async global->LDS, 16B per lane (dest = uniform base + lane*16)
#define GLL(g, s)                                             \
  __builtin_amdgcn_global_load_lds(                           \
      (const __attribute__((address_space(1))) void*)(g),     \
      (__attribute__((address_space(3))) void*)(s), 16, 0, 0)

__global__ void k_init(Scal* sc) {
  if (threadIdx.x == 0) {
    sc->mn_bits = 0x7f800000;
    sc->mx_bits = 0xff800000;
    sc->kld_sum = 0.0;
    sc->struct_sum = 0.0;
    sc->traj_sum = 0.0;
  }
}

__global__ void k_minmax(const float* __restrict__ adj, int n, Scal* sc) {
  float lmin = INFINITY, lmax = -INFINITY;
  for (int i = blockIdx.x * blockDim.x + threadIdx.x; i < n;
       i += gridDim.x * blockDim.x) {
    float v = adj[i];
    lmin = fminf(lmin, v);
    lmax = fmaxf(lmax, v);
  }
#pragma unroll
  for (int off = 32; off; off >>= 1) {
    lmin = fminf(lmin, __shfl_xor(lmin, off, 64));
    lmax = fmaxf(lmax, __shfl_xor(lmax, off, 64));
  }
  __shared__ float smn[4], smx[4];
  int w = threadIdx.x >> 6;
  if ((threadIdx.x & 63) == 0) { smn[w] = lmin; smx[w] = lmax; }
  __syncthreads();
  if (threadIdx.x == 0) {
    lmin = fminf(fminf(smn[0], smn[1]), fminf(smn[2], smn[3]));
    lmax = fmaxf(fmaxf(smx[0], smx[1]), fmaxf(smx[2], smx[3]));
    atomicMin(&sc->mn_bits, __float_as_int(lmin));
    atomicMax(&sc->mx_bits, __float_as_int(lmax));
  }
}

__global__ void k_scale(Scal* sc) {
  float mn = fminf(0.0f, __int_as_float(sc->mn_bits));
  float mx = fmaxf(0.0f, __int_as_float(sc->mx_bits));
  sc->Amin = mn;
  sc->invr = 1.0f / (mx - mn);
  sc->c0 = (0.0f - mn) * sc->invr;
}

__global__ void k_dis(const float* __restrict__ adj, const Scal* __restrict__ sc,
                      float* __restrict__ dis) {
  int j = blockIdx.x * 256 + threadIdx.x;
  int t = j >> 8, jj = j & 255;
  const float* a = adj + (size_t)t * 65536;
  float Amin = sc->Amin, invr = sc->invr, c0 = sc->c0;
  float sum = 0.f;
  for (int i = 0; i < 256; ++i) sum += (a[i * 256 + jj] - Amin) * invr;
  float djj = (a[jj * 256 + jj] - Amin) * invr;
  float deg = sum + 1792.0f * c0 + (djj == 0.0f ? 1.0f : 0.0f);
  dis[j] = deg > 0.0f ? 1.0f / sqrtf(deg) : 0.0f;
}

__global__ void k_agg(const float* __restrict__ adj, const Scal* __restrict__ sc,
                      const float* __restrict__ dis, float* __restrict__ agg) {
  int idx = blockIdx.x * 256 + threadIdx.x;
  int t = idx >> 16, i = (idx >> 8) & 255, j = idx & 255;
  float v = (adj[(size_t)t * 65536 + j * 256 + i] - sc->Amin) * sc->invr;
  if (i == j && v == 0.0f) v += 1.0f;
  agg[idx] = dis[t * 256 + j] * v * dis[t * 256 + i];
}

__global__ void k_enc1(const float* __restrict__ traj, const float* __restrict__ w,
                       const float* __restrict__ b, float* __restrict__ out) {
  int idx = blockIdx.x * 256 + threadIdx.x;
  int r = idx >> 7, f = idx & 127;
  float v = traj[r * 2] * w[f * 2] + traj[r * 2 + 1] * w[f * 2 + 1] + b[f];
  out[idx] = fmaxf(v, 0.0f);
}

// fp32 -> bf16 hi/lo, 4 elems/thread
__global__ void k_cvt(const float* __restrict__ src, unsigned short* __restrict__ h,
                      unsigned short* __restrict__ l, int n4) {
  int i = blockIdx.x * 256 + threadIdx.x;
  if (i >= n4) return;
  float4 v = reinterpret_cast<const float4*>(src)[i];
  us4 hh, ll;
  split4(v, hh, ll);
  reinterpret_cast<us4*>(h)[i] = hh;
  reinterpret_cast<us4*>(l)[i] = ll;
}

// ---------------- small fp32 GEMM (front-end, M=2048) ----------------
#define BM 64
#define BN 64
#define KC 32
#define LP 68

template <bool TB>
__global__ __launch_bounds__(256) void gemm_kernel(
    const float* __restrict__ A, const float* __restrict__ B,
    const float* __restrict__ bias, float* __restrict__ C, int K, int ldb,
    int ldc, int flags, size_t aStride, size_t bStride, size_t cStride) {
  if (blockIdx.z) {
    A += (size_t)blockIdx.z * aStride;
    B += (size_t)blockIdx.z * bStride;
    C += (size_t)blockIdx.z * cStride;
  }
  __shared__ float As[KC][LP];
  __shared__ float Bs[KC][LP];
  const int tid = threadIdx.x;
  const int tx = tid & 15, ty = tid >> 4;
  const int m0 = blockIdx.y * BM, n0 = blockIdx.x * BN;
  float acc[4][4] = {};
  for (int k0 = 0; k0 < K; k0 += KC) {
#pragma unroll
    for (int i = 0; i < 2; ++i) {
      int q = tid + i * 256;
      int row = q >> 3, kq = q & 7;
      float4 v = *reinterpret_cast<const float4*>(
          &A[(size_t)(m0 + row) * K + k0 + kq * 4]);
      As[kq * 4 + 0][row] = v.x;
      As[kq * 4 + 1][row] = v.y;
      As[kq * 4 + 2][row] = v.z;
      As[kq * 4 + 3][row] = v.w;
    }
    if (TB) {
#pragma unroll
      for (int i = 0; i < 2; ++i) {
        int q = tid + i * 256;
        int row = q >> 3, kq = q & 7;
        float4 v = *reinterpret_cast<const float4*>(
            &B[(size_t)(n0 + row) * ldb + k0 + kq * 4]);
        Bs[kq * 4 + 0][row] = v.x;
        Bs[kq * 4 + 1][row] = v.y;
        Bs[kq * 4 + 2][row] = v.z;
        Bs[kq * 4 + 3][row] = v.w;
      }
    } else {
#pragma unroll
      for (int i = 0; i < 2; ++i) {
        int q = tid + i * 256;
        int kr = q >> 4, nq = q & 15;
        float4 v = *reinterpret_cast<const float4*>(
            &B[(size_t)(k0 + kr) * ldb + n0 + nq * 4]);
        *reinterpret_cast<float4*>(&Bs[kr][nq * 4]) = v;
      }
    }
    __syncthreads();
#pragma unroll
    for (int kk = 0; kk < KC; ++kk) {
      float4 a4 = *reinterpret_cast<const float4*>(&As[kk][ty * 4]);
      float4 b4 = *reinterpret_cast<const float4*>(&Bs[kk][tx * 4]);
      float av[4] = {a4.x, a4.y, a4.z, a4.w};
      float bv[4] = {b4.x, b4.y, b4.z, b4.w};
#pragma unroll
      for (int i = 0; i < 4; ++i)
#pragma unroll
        for (int j = 0; j < 4; ++j) acc[i][j] += av[i] * bv[j];
    }
    __syncthreads();
  }
  float bv[4] = {0.f, 0.f, 0.f, 0.f};
  if (bias) {
    float4 b4 = *reinterpret_cast<const float4*>(&bias[n0 + tx * 4]);
    bv[0] = b4.x; bv[1] = b4.y; bv[2] = b4.z; bv[3] = b4.w;
  }
#pragma unroll
  for (int i = 0; i < 4; ++i) {
    float* cp = &C[(size_t)(m0 + ty * 4 + i) * ldc + n0 + tx * 4];
    float4 o;
    float ov[4];
#pragma unroll
    for (int j = 0; j < 4; ++j) ov[j] = acc[i][j] + bv[j];
    if (flags & 2) {
      float4 old = *reinterpret_cast<const float4*>(cp);
      ov[0] += old.x; ov[1] += old.y; ov[2] += old.z; ov[3] += old.w;
    }
    if (flags & 1) {
#pragma unroll
      for (int j = 0; j < 4; ++j) ov[j] = fmaxf(ov[j], 0.0f);
    }
    o.x = ov[0]; o.y = ov[1]; o.z = ov[2]; o.w = ov[3];
    *reinterpret_cast<float4*>(cp) = o;
  }
}

// ---------------- MFMA split-bf16 GEMM (qkv / out-proj) ----------------
template <int BMb, int BNb>
__global__ __launch_bounds__(256) void gemm_bf(
    const unsigned short* __restrict__ Ah, const unsigned short* __restrict__ Al,
    const unsigned short* __restrict__ Bh, const unsigned short* __restrict__ Bl,
    const float* __restrict__ bias, float* __restrict__ C,
    int K, int lda, int ldb, int ldc, int flags) {
  constexpr int MI = BMb / 32, NI = BNb / 32;
  constexpr int WTM = BMb / 2, WTN = BNb / 2;
  __shared__ unsigned short sAh[BMb * 32], sAl[BMb * 32];
  __shared__ unsigned short sBh[BNb * 32], sBl[BNb * 32];
  const int tid = threadIdx.x, lane = tid & 63, w = tid >> 6;
  const int wr = w >> 1, wc = w & 1;
  const int m0 = blockIdx.y * BMb, n0 = blockIdx.x * BNb;
  f32x4 acc[MI][NI];
#pragma unroll
  for (int i = 0; i < MI; ++i)
#pragma unroll
    for (int j = 0; j < NI; ++j) acc[i][j] = (f32x4){0.f, 0.f, 0.f, 0.f};

  for (int k0 = 0; k0 < K; k0 += 32) {
#pragma unroll
    for (int i = 0; i < BMb / 64; ++i) {
      int c = tid + i * 256;
      int g = swz4(c);
      int row = g >> 2, c4 = g & 3;
      size_t ga = (size_t)(m0 + row) * lda + k0 + c4 * 8;
      GLL(&Ah[ga], &sAh[c * 8]);
      GLL(&Al[ga], &sAl[c * 8]);
    }
#pragma unroll
    for (int i = 0; i < BNb / 64; ++i) {
      int c = tid + i * 256;
      int g = swz4(c);
      int row = g >> 2, c4 = g & 3;
      size_t ga = (size_t)(n0 + row) * ldb + k0 + c4 * 8;
      GLL(&Bh[ga], &sBh[c * 8]);
      GLL(&Bl[ga], &sBl[c * 8]);
    }
    __syncthreads();
    bf16x8 bh[NI], bl[NI];
#pragma unroll
    for (int ni = 0; ni < NI; ++ni) {
      int p = swz4((wc * WTN + ni * 16 + (lane & 15)) * 4 + (lane >> 4));
      bh[ni] = *reinterpret_cast<const bf16x8*>(&sBh[p * 8]);
      bl[ni] = *reinterpret_cast<const bf16x8*>(&sBl[p * 8]);
    }
#pragma unroll
    for (int mi = 0; mi < MI; ++mi) {
      int p = swz4((wr * WTM + mi * 16 + (lane & 15)) * 4 + (lane >> 4));
      bf16x8 ah = *reinterpret_cast<const bf16x8*>(&sAh[p * 8]);
      bf16x8 al = *reinterpret_cast<const bf16x8*>(&sAl[p * 8]);
#pragma unroll
      for (int ni = 0; ni < NI; ++ni) {
        acc[mi][ni] = __builtin_amdgcn_mfma_f32_16x16x32_bf16(
            ah, bh[ni], acc[mi][ni], 0, 0, 0);
        acc[mi][ni] = __builtin_amdgcn_mfma_f32_16x16x32_bf16(
            ah, bl[ni], acc[mi][ni], 0, 0, 0);
        acc[mi][ni] = __builtin_amdgcn_mfma_f32_16x16x32_bf16(
            al, bh[ni], acc[mi][ni], 0, 0, 0);
      }
    }
    __syncthreads();
  }
  const int crow0 = m0 + wr * WTM + (lane >> 4) * 4;
  const int ccol0 = n0 + wc * WTN + (lane & 15);
#pragma unroll
  for (int ni = 0; ni < NI; ++ni) {
    int col = ccol0 + ni * 16;
    float bv = bias ? bias[col] : 0.f;
#pragma unroll
    for (int mi = 0; mi < MI; ++mi) {
#pragma unroll
      for (int r = 0; r < 4; ++r) {
        int row = crow0 + mi * 16 + r;
        float v = acc[mi][ni][r] + bv;
        if (flags & 2) v += C[(size_t)row * ldc + col];
        if (flags & 1) v = fmaxf(v, 0.0f);
        C[(size_t)row * ldc + col] = v;
      }
    }
  }
}

// ---------------- fused FFN, pipelined: tmp = relu(X@W1^T+b1)@W2^T+b2 -----
// One block per 64 rows.  Double-buffered W staging with counted vmcnt(8)
// and raw s_barrier (no vmcnt(0) drain in the loop).  b1 in LDS (avoids
// in-loop global loads that would force a vmcnt drain).  X staged once into
// the buffer-1 alias, hoisted to registers.  LDS map (shorts):
//   [0)      buf0: W1h(4096) W1l(4096) W2h(4096) W2l(4096)
//   [16384)  buf1: same       (aliased at prologue by sXh/sXl, 16K shorts)
//   [32768)  Ph(2048) Pl(2048)
//   [36864)  b1 as float[2048] (4096 shorts)   total 40960 shorts = 80 KB
__global__ __launch_bounds__(256) void k_ffn(
    const unsigned short* __restrict__ Xh, const unsigned short* __restrict__ Xl,
    const unsigned short* __restrict__ W1h, const unsigned short* __restrict__ W1l,
    const float* __restrict__ b1,
    const unsigned short* __restrict__ W2h, const unsigned short* __restrict__ W2l,
    const float* __restrict__ b2, float* __restrict__ out) {
  __shared__ unsigned short sLds[40960];
  unsigned short* sPh = sLds + 32768;
  unsigned short* sPl = sLds + 34816;
  float* sB1 = reinterpret_cast<float*>(sLds + 36864);
  const int tid = threadIdx.x, lane = tid & 63, w = tid >> 6;
  const int wr = w >> 1, wc = w & 1;
  const int m0 = blockIdx.x * 64;

  // stage W1/W2 f-chunk f0 into buffer `buf` (8 GLLs per thread)
  auto stageW = [&](int buf, int f0) {
    unsigned short* d = sLds + buf * 16384;
#pragma unroll
    for (int i = 0; i < 2; ++i) {
      int c = tid + i * 256;
      {
        int g = swz16(c);
        size_t ga = (size_t)(f0 + (g >> 4)) * 128 + (g & 15) * 8;
        GLL(&W1h[ga], &d[c * 8]);           // -> buf W1h
        GLL(&W1l[ga], &d[4096 + c * 8]);    // -> buf W1l
      }
      {
        int g = swz4(c);
        size_t ga = (size_t)(g >> 2) * 2048 + f0 + (g & 3) * 8;
        GLL(&W2h[ga], &d[8192 + c * 8]);    // -> buf W2h
        GLL(&W2l[ga], &d[12288 + c * 8]);   // -> buf W2l
      }
    }
  };

  // ---- prologue: stage X (into buf1 alias) + b1; hoist X frags ----
  {
    unsigned short* sXh = sLds + 16384;   // 8192 shorts
    unsigned short* sXl = sLds + 24576;   // 8192 shorts
#pragma unroll
    for (int i = 0; i < 4; ++i) {
      int c = tid + i * 256;
      int g = swz16(c);
      size_t ga = (size_t)(m0 + (g >> 4)) * 128 + (g & 15) * 8;
      GLL(&Xh[ga], &sXh[c * 8]);
      GLL(&Xl[ga], &sXl[c * 8]);
    }
#pragma unroll
    for (int i = 0; i < 2; ++i) {
      int c = tid + i * 256;
      GLL(&b1[c * 4], &sB1[c * 4]);
    }
  }
  __builtin_amdgcn_sched_barrier(0);
  asm volatile("s_waitcnt vmcnt(0)");
  __builtin_amdgcn_sched_barrier(0);
  __builtin_amdgcn_s_barrier();
  // prefetch f-chunk 0 into buf0 (latency hides under the X-frag hoist)
  stageW(0, 0);
  // hoist X A-fragments [kstep][mi] from the buf1 alias
  bf16x8 xah[4][2], xal[4][2];
  {
    unsigned short* sXh = sLds + 16384;
    unsigned short* sXl = sLds + 24576;
#pragma unroll
    for (int ks = 0; ks < 4; ++ks)
#pragma unroll
      for (int mi = 0; mi < 2; ++mi) {
        int row = wr * 32 + mi * 16 + (lane & 15);
        int p = swz16(row * 16 + ks * 4 + (lane >> 4));
        xah[ks][mi] = *reinterpret_cast<const bf16x8*>(&sXh[p * 8]);
        xal[ks][mi] = *reinterpret_cast<const bf16x8*>(&sXl[p * 8]);
      }
  }
  __builtin_amdgcn_sched_barrier(0);
  asm volatile("s_waitcnt lgkmcnt(0)");
  __builtin_amdgcn_sched_barrier(0);
  __builtin_amdgcn_s_barrier();   // all hoists done before buf1 is re-staged

  f32x4 acc2[2][4];
#pragma unroll
  for (int i = 0; i < 2; ++i)
#pragma unroll
    for (int j = 0; j < 4; ++j) acc2[i][j] = (f32x4){0.f, 0.f, 0.f, 0.f};

  const int pcol = wc * 16 + (lane & 15);

  // one pipelined f-chunk: buf[cur] is staged & in flight on entry
  auto body = [&](int cur, int f0, bool hasNext) {
    unsigned short* bW1h = sLds + cur * 16384;
    unsigned short* bW1l = bW1h + 4096;
    unsigned short* bW2h = bW1h + 8192;
    unsigned short* bW2l = bW1h + 12288;
    if (hasNext) {
      stageW(cur ^ 1, f0 + 32);           // prefetch next chunk (8 GLLs)
      __builtin_amdgcn_sched_barrier(0);
      asm volatile("s_waitcnt vmcnt(8)"); // wait ONLY for buf[cur]'s loads
    } else {
      __builtin_amdgcn_sched_barrier(0);
      asm volatile("s_waitcnt vmcnt(0)");
    }
    __builtin_amdgcn_sched_barrier(0);
    __builtin_amdgcn_s_barrier();          // buf[cur] visible to all threads
    // GEMM1: P(64x32) = X(64x128) @ W1c(32x128)^T
    f32x4 acc1[2];
    acc1[0] = (f32x4){0.f, 0.f, 0.f, 0.f};
    acc1[1] = (f32x4){0.f, 0.f, 0.f, 0.f};
#pragma unroll
    for (int ks = 0; ks < 4; ++ks) {
      int p = swz16((wc * 16 + (lane & 15)) * 16 + ks * 4 + (lane >> 4));
      bf16x8 bh = *reinterpret_cast<const bf16x8*>(&bW1h[p * 8]);
      bf16x8 bl = *reinterpret_cast<const bf16x8*>(&bW1l[p * 8]);
#pragma unroll
      for (int mi = 0; mi < 2; ++mi) {
        acc1[mi] = __builtin_amdgcn_mfma_f32_16x16x32_bf16(xah[ks][mi], bh,
                                                           acc1[mi], 0, 0, 0);
        acc1[mi] = __builtin_amdgcn_mfma_f32_16x16x32_bf16(xah[ks][mi], bl,
                                                           acc1[mi], 0, 0, 0);
        acc1[mi] = __builtin_amdgcn_mfma_f32_16x16x32_bf16(xal[ks][mi], bh,
                                                           acc1[mi], 0, 0, 0);
      }
    }
    // P epilogue: bias(LDS), relu, hi/lo split, swizzled LDS write
    float b1v = sB1[f0 + pcol];
#pragma unroll
    for (int mi = 0; mi < 2; ++mi)
#pragma unroll
      for (int r = 0; r < 4; ++r) {
        int prow = wr * 32 + mi * 16 + (lane >> 4) * 4 + r;
        float v = fmaxf(acc1[mi][r] + b1v, 0.0f);
        unsigned short h = f2bf(v);
        int p = swz4(prow * 4 + (pcol >> 3));
        sPh[p * 8 + (pcol & 7)] = h;
        sPl[p * 8 + (pcol & 7)] = f2bf(v - bf2f(h));
      }
    __builtin_amdgcn_sched_barrier(0);
    asm volatile("s_waitcnt lgkmcnt(0)");  // P writes drained
    __builtin_amdgcn_sched_barrier(0);
    __builtin_amdgcn_s_barrier();           // P visible
    // GEMM2: acc2 += P(64x32) @ W2c(128x32)^T
    bf16x8 pah[2], pal[2];
#pragma unroll
    for (int mi = 0; mi < 2; ++mi) {
      int p = swz4((wr * 32 + mi * 16 + (lane & 15)) * 4 + (lane >> 4));
      pah[mi] = *reinterpret_cast<const bf16x8*>(&sPh[p * 8]);
      pal[mi] = *reinterpret_cast<const bf16x8*>(&sPl[p * 8]);
    }
#pragma unroll
    for (int ni = 0; ni < 4; ++ni) {
      int p = swz4((wc * 64 + ni * 16 + (lane & 15)) * 4 + (lane >> 4));
      bf16x8 bh = *reinterpret_cast<const bf16x8*>(&bW2h[p * 8]);
      bf16x8 bl = *reinterpret_cast<const bf16x8*>(&bW2l[p * 8]);
#pragma unroll
      for (int mi = 0; mi < 2; ++mi) {
        acc2[mi][ni] = __builtin_amdgcn_mfma_f32_16x16x32_bf16(
            pah[mi], bh, acc2[mi][ni], 0, 0, 0);
        acc2[mi][ni] = __builtin_amdgcn_mfma_f32_16x16x32_bf16(
            pah[mi], bl, acc2[mi][ni], 0, 0, 0);
        acc2[mi][ni] = __builtin_amdgcn_mfma_f32_16x16x32_bf16(
            pal[mi], bh, acc2[mi][ni], 0, 0, 0);
      }
    }
    __builtin_amdgcn_sched_barrier(0);
    __builtin_amdgcn_s_barrier();  // all GEMM1/2 reads of buf[cur] + P done
                                   // before the next iteration stages over them
  };

  for (int fc2 = 0; fc2 < 32; ++fc2) {
    body(0, fc2 * 64, true);
    body(1, fc2 * 64 + 32, fc2 != 31);
  }

  // epilogue: out = acc2 + b2
#pragma unroll
  for (int ni = 0; ni < 4; ++ni) {
    int col = wc * 64 + ni * 16 + (lane & 15);
    float bv = b2[col];
#pragma unroll
    for (int mi = 0; mi < 2; ++mi)
#pragma unroll
      for (int r = 0; r < 4; ++r) {
        int row = m0 + wr * 32 + mi * 16 + (lane >> 4) * 4 + r;
        out[(size_t)row * 128 + col] = acc2[mi][ni][r] + bv;
      }
  }
}

__global__ void k_zkld(const float* __restrict__ mu, const float* __restrict__ lsr,
                       const float* __restrict__ eps, const int* __restrict__ iftrain,
                       float* __restrict__ Z, Scal* sc) {
  int i = blockIdx.x * 256 + threadIdx.x;
  float m = mu[i];
  float ls = fminf(lsr[i], 10.0f);
  float z = (*iftrain > 0) ? m + eps[i] * __expf(ls) : m;
  Z[i] = z;
  float kt = 1.0f + 2.0f * ls - m * m - __expf(2.0f * ls);
  kt = waveReduceSum(kt);
  __shared__ float sh[4];
  int w = threadIdx.x >> 6;
  if ((threadIdx.x & 63) == 0) sh[w] = kt;
  __syncthreads();
  if (threadIdx.x == 0)
    atomicAdd(&sc->kld_sum, (double)(sh[0] + sh[1] + sh[2] + sh[3]));
}

__global__ __launch_bounds__(256) void k_struct(const float* __restrict__ Z,
                                                const float* __restrict__ adj,
                                                Scal* sc) {
  __shared__ float As[KC][LP];
  __shared__ float Bs[KC][LP];
  const int tid = threadIdx.x;
  const int tx = tid & 15, ty = tid >> 4;
  const int m0 = blockIdx.y * BM, n0 = blockIdx.x * BN;
  float acc[4][4] = {};
  for (int k0 = 0; k0 < kH; k0 += KC) {
#pragma unroll
    for (int i = 0; i < 2; ++i) {
      int q = tid + i * 256;
      int row = q >> 3, kq = q & 7;
      float4 va = *reinterpret_cast<const float4*>(
          &Z[(size_t)(m0 + row) * kH + k0 + kq * 4]);
      As[kq * 4 + 0][row] = va.x;
      As[kq * 4 + 1][row] = va.y;
      As[kq * 4 + 2][row] = va.z;
      As[kq * 4 + 3][row] = va.w;
      float4 vb = *reinterpret_cast<const float4*>(
          &Z[(size_t)(n0 + row) * kH + k0 + kq * 4]);
      Bs[kq * 4 + 0][row] = vb.x;
      Bs[kq * 4 + 1][row] = vb.y;
      Bs[kq * 4 + 2][row] = vb.z;
      Bs[kq * 4 + 3][row] = vb.w;
    }
    __syncthreads();
#pragma unroll
    for (int kk = 0; kk < KC; ++kk) {
      float4 a4 = *reinterpret_cast<const float4*>(&As[kk][ty * 4]);
      float4 b4 = *reinterpret_cast<const float4*>(&Bs[kk][tx * 4]);
      float av[4] = {a4.x, a4.y, a4.z, a4.w};
      float bv[4] = {b4.x, b4.y, b4.z, b4.w};
#pragma unroll
      for (int i = 0; i < 4; ++i)
#pragma unroll
        for (int j = 0; j < 4; ++j) acc[i][j] += av[i] * bv[j];
    }
    __syncthreads();
  }
  float Amin = sc->Amin, invr = sc->invr, c0v = sc->c0;
  float lsum = 0.f;
#pragma unroll
  for (int i = 0; i < 4; ++i) {
#pragma unroll
    for (int j = 0; j < 4; ++j) {
      int gi = m0 + ty * 4 + i, gj = n0 + tx * 4 + j;
      float l = acc[i][j];
      float adjv = c0v;
      if ((gi >> 8) == (gj >> 8))
        adjv = (adj[((size_t)(gi >> 8) << 16) + (gi & 255) * 256 + (gj & 255)] -
                Amin) * invr;
      lsum += fmaxf(l, 0.0f) - l * adjv + __logf(1.0f + __expf(-fabsf(l)));
    }
  }
  lsum = waveReduceSum(lsum);
  __shared__ float sh[4];
  int w = threadIdx.x >> 6;
  if ((threadIdx.x & 63) == 0) sh[w] = lsum;
  __syncthreads();
  if (threadIdx.x == 0)
    atomicAdd(&sc->struct_sum, (double)(sh[0] + sh[1] + sh[2] + sh[3]));
}

__global__ void k_x0(const float* __restrict__ gdl, const float* __restrict__ w3,
                     const float* __restrict__ b3, float* __restrict__ X,
                     unsigned short* __restrict__ Xh,
                     unsigned short* __restrict__ Xl) {
  int f = threadIdx.x;
  size_t r = (size_t)blockIdx.x * 2 + threadIdx.y;
  int n = (int)(r >> 7), h = (int)(r & 127);
  float a = b3[f];
#pragma unroll
  for (int o = 0; o < 8; ++o)
    a += gdl[((size_t)o * 256 + n) * 128 + h] * w3[f * 8 + o];
  X[r * 128 + f] = a;
  unsigned short hh = f2bf(a);
  Xh[r * 128 + f] = hh;
  Xl[r * 128 + f] = f2bf(a - bf2f(hh));
}

// attention: one block per (head,b); 256 threads, 1 q-row each.  Single-pass
// online softmax w/ deferred rescale (THR=8).  Writes O as bf16 hi/lo.
__global__ __launch_bounds__(256) void k_attn(const float* __restrict__ QKV,
                                              unsigned short* __restrict__ Oh,
                                              unsigned short* __restrict__ Ol) {
  const int head = blockIdx.x, b = blockIdx.y;
  const int s = threadIdx.x;  // 0..255
  __shared__ float ks[256][16];
  __shared__ float vs[256][16];
  const size_t base = ((size_t)s * 128 + b) * 384 + head * 16;
#pragma unroll
  for (int i = 0; i < 4; ++i) {
    *reinterpret_cast<float4*>(&ks[s][i * 4]) =
        *reinterpret_cast<const float4*>(&QKV[base + 128 + i * 4]);
    *reinterpret_cast<float4*>(&vs[s][i * 4]) =
        *reinterpret_cast<const float4*>(&QKV[base + 256 + i * 4]);
  }
  float q[16];
#pragma unroll
  for (int i = 0; i < 4; ++i) {
    float4 v = *reinterpret_cast<const float4*>(&QKV[base + i * 4]);
    q[i * 4 + 0] = v.x * 0.25f; q[i * 4 + 1] = v.y * 0.25f;
    q[i * 4 + 2] = v.z * 0.25f; q[i * 4 + 3] = v.w * 0.25f;
  }
  __syncthreads();
  float m = -1e30f, lsum = 0.f;
  float o[16] = {};
#pragma unroll 2
  for (int t = 0; t < 256; ++t) {
    float kv[16], vv[16];
#pragma unroll
    for (int i = 0; i < 4; ++i) {
      float4 k4 = *reinterpret_cast<const float4*>(&ks[t][i * 4]);
      float4 v4 = *reinterpret_cast<const float4*>(&vs[t][i * 4]);
      kv[i * 4 + 0] = k4.x; kv[i * 4 + 1] = k4.y;
      kv[i * 4 + 2] = k4.z; kv[i * 4 + 3] = k4.w;
      vv[i * 4 + 0] = v4.x; vv[i * 4 + 1] = v4.y;
      vv[i * 4 + 2] = v4.z; vv[i * 4 + 3] = v4.w;
    }
    float d = 0.f;
#pragma unroll
    for (int i = 0; i < 16; ++i) d += q[i] * kv[i];
    if (d > m + 8.f) {            // deferred rescale (T13)
      float c = __expf(m - d);
      lsum *= c;
#pragma unroll
      for (int i = 0; i < 16; ++i) o[i] *= c;
      m = d;
    }
    float p = __expf(d - m);
    lsum += p;
#pragma unroll
    for (int i = 0; i < 16; ++i) o[i] += p * vv[i];
  }
  float inv = 1.0f / lsum;
  size_t ob = ((size_t)s * 128 + b) * 128 + head * 16;
#pragma unroll
  for (int i = 0; i < 4; ++i) {
    float4 v;
    v.x = o[i * 4 + 0] * inv; v.y = o[i * 4 + 1] * inv;
    v.z = o[i * 4 + 2] * inv; v.w = o[i * 4 + 3] * inv;
    us4 hh, ll;
    split4(v, hh, ll);
    *reinterpret_cast<us4*>(&Oh[ob + i * 4]) = hh;
    *reinterpret_cast<us4*>(&Ol[ob + i * 4]) = ll;
  }
}

// X = LN(X + T); also emits Xh/Xl bf16 hi/lo
__global__ __launch_bounds__(256) void k_resid_ln(
    float* __restrict__ X, const float* __restrict__ T,
    const float* __restrict__ g, const float* __restrict__ b,
    unsigned short* __restrict__ Xh, unsigned short* __restrict__ Xl) {
  int lane = threadIdx.x & 63, rl = threadIdx.x >> 6;
  size_t row = (size_t)blockIdx.x * 4 + rl;
  float* xp = X + row * 128;
  const float* tp = T + row * 128;
  float e0 = xp[lane] + tp[lane];
  float e1 = xp[lane + 64] + tp[lane + 64];
  float mean = waveReduceSum(e0 + e1) * 0.0078125f;
  float d0 = e0 - mean, d1 = e1 - mean;
  float var = waveReduceSum(d0 * d0 + d1 * d1) * 0.0078125f;
  float inv = 1.0f / sqrtf(var + 1e-5f);
  float v0 = d0 * inv * g[lane] + b[lane];
  float v1 = d1 * inv * g[lane + 64] + b[lane + 64];
  xp[lane] = v0;
  xp[lane + 64] = v1;
  unsigned short h0 = f2bf(v0), h1 = f2bf(v1);
  Xh[row * 128 + lane] = h0;
  Xl[row * 128 + lane] = f2bf(v0 - bf2f(h0));
  Xh[row * 128 + lane + 64] = h1;
  Xl[row * 128 + lane + 64] = f2bf(v1 - bf2f(h1));
}

__global__ void k_heady(const float* __restrict__ X, const float* __restrict__ w4,
                        const float* __restrict__ b4, float* __restrict__ y) {
  int tid = threadIdx.x;
  int o = tid & 7, rl = tid >> 3;
  size_t r = (size_t)blockIdx.x * 32 + rl;
  const float* xp = X + r * 128;
  const float* wp = w4 + o * 128;
  float a = b4[o];
  for (int f = 0; f < 128; f += 4)
    a += xp[f] * wp[f] + xp[f + 1] * wp[f + 1] + xp[f + 2] * wp[f + 2] +
         xp[f + 3] * wp[f + 3];
  y[r * 8 + o] = a;
}

__global__ void k_traj(const float* __restrict__ y, const float* __restrict__ w5,
                       const float* __restrict__ b5,
                       const float* __restrict__ traj_in, float* __restrict__ dout,
                       Scal* sc) {
  int n = blockIdx.x, lane = threadIdx.x;
  float w0a = w5[lane], w0b = w5[lane + 64];
  float w1a = w5[128 + lane], w1b = w5[128 + lane + 64];
  float dsum = 0.f;
  for (int oi = 0; oi < 4; ++oi) {
    int o = 4 + oi;
    float ya = y[((size_t)n * 128 + lane) * 8 + o];
    float yb = y[((size_t)n * 128 + lane + 64) * 8 + o];
    float s0 = waveReduceSum(w0a * ya + w0b * yb);
    float s1 = waveReduceSum(w1a * ya + w1b * yb);
    if (lane == 0) {
      float t0 = s0 + b5[0], t1 = s1 + b5[1];
      dout[oi * 512 + n * 2 + 0] = t0;
      dout[oi * 512 + n * 2 + 1] = t1;
      float dx = t0 - traj_in[((8 + oi) * 256 + n) * 2 + 0];
      float dy = t1 - traj_in[((8 + oi) * 256 + n) * 2 + 1];
      dsum += sqrtf(dx * dx + dy * dy);
    }
  }
  if (lane == 0) atomicAdd(&sc->traj_sum, (double)dsum);
}

__global__ void k_loss(const Scal* sc, float* dout) {
  if (threadIdx.x == 0) {
    double traj_loss = sc->traj_sum / 256.0;
    double kld = -0.5 * sc->kld_sum / 2048.0;
    double st = sc->struct_sum / (2048.0 * 2048.0);
    dout[2048] = (float)(traj_loss + kld + st);
  }
}

}  // namespace

extern "C" void kernel_launch(void* const* d_in, const int* in_sizes, int n_in,
                              void* d_out, int out_size, void* d_ws,
                              size_t ws_size, hipStream_t stream) {
  (void)in_sizes; (void)n_in; (void)out_size; (void)ws_size;
  const float* traj_in = (const float*)d_in[0];
  const float* adj     = (const float*)d_in[1];
  const float* eps     = (const float*)d_in[2];
  const float* pro1_w  = (const float*)d_in[3];
  const float* pro1_b  = (const float*)d_in[4];
  const float* pro2_w  = (const float*)d_in[5];
  const float* pro2_b  = (const float*)d_in[6];
  const float* mu_w    = (const float*)d_in[7];
  const float* mu_b    = (const float*)d_in[8];
  const float* ls_w    = (const float*)d_in[9];
  const float* ls_b    = (const float*)d_in[10];
  const float* gdl_w   = (const float*)d_in[11];
  const float* gdl_b   = (const float*)d_in[12];
  const float* pro3_w  = (const float*)d_in[13];
  const float* pro3_b  = (const float*)d_in[14];
  const float* pro4_w  = (const float*)d_in[15];
  const float* pro4_b  = (const float*)d_in[16];
  const float* pro5_w  = (const float*)d_in[17];
  const float* pro5_b  = (const float*)d_in[18];
  const float* qkv_w   = (const float*)d_in[19];
  const float* qkv_b   = (const float*)d_in[20];
  const float* outp_w  = (const float*)d_in[21];
  const float* outp_b  = (const float*)d_in[22];
  const float* ff1_w   = (const float*)d_in[23];
  const float* ff1_b   = (const float*)d_in[24];
  const float* ff2_w   = (const float*)d_in[25];
  const float* ff2_b   = (const float*)d_in[26];
  const float* ln1_g   = (const float*)d_in[27];
  const float* ln1_b   = (const float*)d_in[28];
  const float* ln2_g   = (const float*)d_in[29];
  const float* ln2_b   = (const float*)d_in[30];
  const int*   iftrain = (const int*)d_in[31];
  float* dout = (float*)d_out;

  char* wsb = (char*)d_ws;
  size_t off = 0;
  auto alloc = [&](size_t bytes) {
    char* p = wsb + off;
    off += (bytes + 255) & ~(size_t)255;
    return p;
  };
  Scal* sc    = (Scal*)alloc(256);
  float* dis  = (float*)alloc(kGN * 4);
  float* agg  = (float*)alloc((size_t)kOBS * 65536 * 4);
  float* enc1 = (float*)alloc((size_t)kGN * kH * 4);
  float* enc  = (float*)alloc((size_t)kGN * kH * 4);
  float* Mmu  = (float*)alloc((size_t)kGN * kH * 4);
  float* Mls  = (float*)alloc((size_t)kGN * kH * 4);
  float* mu   = (float*)alloc((size_t)kGN * kH * 4);
  float* lsb  = (float*)alloc((size_t)kGN * kH * 4);
  float* Z    = (float*)alloc((size_t)kGN * kH * 4);
  float* gdl  = (float*)alloc((size_t)kGN * kH * 4);
  float* X    = (float*)alloc((size_t)kROWS * kH * 4);
  unsigned short* Xh = (unsigned short*)alloc((size_t)kROWS * kH * 2);
  unsigned short* Xl = (unsigned short*)alloc((size_t)kROWS * kH * 2);
  float* QKV = (float*)alloc((size_t)kROWS * 384 * 4);
  unsigned short* Oh = (unsigned short*)alloc((size_t)kROWS * kH * 2);
  unsigned short* Ol = (unsigned short*)alloc((size_t)kROWS * kH * 2);
  float* tmp  = (float*)alloc((size_t)kROWS * kH * 4);
  float* y    = (float*)alloc((size_t)kROWS * 8 * 4);
  unsigned short* qkvWh = (unsigned short*)alloc(6 * 384 * 128 * 2);
  unsigned short* qkvWl = (unsigned short*)alloc(6 * 384 * 128 * 2);
  unsigned short* outWh = (unsigned short*)alloc(6 * 128 * 128 * 2);
  unsigned short* outWl = (unsigned short*)alloc(6 * 128 * 128 * 2);
  unsigned short* ff1Wh = (unsigned short*)alloc(6 * 2048 * 128 * 2);
  unsigned short* ff1Wl = (unsigned short*)alloc(6 * 2048 * 128 * 2);
  unsigned short* ff2Wh = (unsigned short*)alloc(6 * 128 * 2048 * 2);
  unsigned short* ff2Wl = (unsigned short*)alloc(6 * 128 * 2048 * 2);

  auto gemm_nt_small = [&](const float* A, const float* B, const float* bias,
                           float* C, int M, int N, int K, int ldb, int ldc,
                           int flags) {
    dim3 g(N / 64, M / 64, 1);
    gemm_kernel<true><<<g, 256, 0, stream>>>(A, B, bias, C, K, ldb, ldc, flags,
                                             (size_t)0, (size_t)0, (size_t)0);
  };

  // one-time weight conversions
  k_cvt<<<(6 * 384 * 128 / 4 + 255) / 256, 256, 0, stream>>>(
      qkv_w, qkvWh, qkvWl, 6 * 384 * 128 / 4);
  k_cvt<<<(6 * 128 * 128 / 4 + 255) / 256, 256, 0, stream>>>(
      outp_w, outWh, outWl, 6 * 128 * 128 / 4);
  k_cvt<<<(6 * 2048 * 128 / 4 + 255) / 256, 256, 0, stream>>>(
      ff1_w, ff1Wh, ff1Wl, 6 * 2048 * 128 / 4);
  k_cvt<<<(6 * 128 * 2048 / 4 + 255) / 256, 256, 0, stream>>>(
      ff2_w, ff2Wh, ff2Wl, 6 * 128 * 2048 / 4);

  k_init<<<1, 64, 0, stream>>>(sc);
  k_minmax<<<512, 256, 0, stream>>>(adj, kOBS * kNAG * kNAG, sc);
  k_scale<<<1, 1, 0, stream>>>(sc);
  k_dis<<<8, 256, 0, stream>>>(adj, sc, dis);
  k_agg<<<2048, 256, 0, stream>>>(adj, sc, dis, agg);

  k_enc1<<<(kGN * kH) / 256, 256, 0, stream>>>(traj_in, pro1_w, pro1_b, enc1);
  gemm_nt_small(enc1, pro2_w, pro2_b, enc, kGN, kH, kH, kH, kH, 0);
  gemm_nt_small(enc, mu_w, mu_b, Mmu, kGN, kH, kH, kH, kH, 0);
  gemm_nt_small(enc, ls_w, ls_b, Mls, kGN, kH, kH, kH, kH, 0);
  {
    dim3 g(kH / 64, kNAG / 64, kOBS);
    gemm_kernel<false><<<g, 256, 0, stream>>>(agg, Mmu, nullptr, mu, kNAG, kH,
                                              kH, 0, (size_t)65536,
                                              (size_t)kNAG * kH, (size_t)kNAG * kH);
    gemm_kernel<false><<<g, 256, 0, stream>>>(agg, Mls, nullptr, lsb, kNAG, kH,
                                              kH, 0, (size_t)65536,
                                              (size_t)kNAG * kH, (size_t)kNAG * kH);
  }
  k_zkld<<<(kGN * kH) / 256, 256, 0, stream>>>(mu, lsb, eps, iftrain, Z, sc);
  gemm_nt_small(Z, gdl_w, gdl_b, gdl, kGN, kH, kH, kH, kH, 0);
  k_struct<<<dim3(kGN / 64, kGN / 64), 256, 0, stream>>>(Z, adj, sc);
  k_x0<<<kROWS / 2, dim3(128, 2), 0, stream>>>(gdl, pro3_w, pro3_b, X, Xh, Xl);

  for (int l = 0; l < 6; ++l) {
    // qkv: (32768,384) = X @ Wqkv^T  -> fp32 QKV
    gemm_bf<128, 128><<<dim3(3, kROWS / 128), 256, 0, stream>>>(
        Xh, Xl, qkvWh + (size_t)l * 384 * 128, qkvWl + (size_t)l * 384 * 128,
        qkv_b + l * 384, QKV, 128, 128, 128, 384, 0);
    k_attn<<<dim3(8, 128), 256, 0, stream>>>(QKV, Oh, Ol);
    // out-proj: (32768,128) -> fp32 tmp
    gemm_bf<64, 128><<<dim3(1, kROWS / 64), 256, 0, stream>>>(
        Oh, Ol, outWh + (size_t)l * 128 * 128, outWl + (size_t)l * 128 * 128,
        outp_b + l * 128, tmp, 128, 128, 128, 128, 0);
    k_resid_ln<<<kROWS / 4, 256, 0, stream>>>(X, tmp, ln1_g + l * kH,
                                              ln1_b + l * kH, Xh, Xl);
    // fused FFN (pipelined) -> fp32 tmp
    k_ffn<<<kROWS / 64, 256, 0, stream>>>(
        Xh, Xl, ff1Wh + (size_t)l * 2048 * 128, ff1Wl + (size_t)l * 2048 * 128,
        ff1_b + l * 2048, ff2Wh + (size_t)l * 128 * 2048,
        ff2Wl + (size_t)l * 128 * 2048, ff2_b + l * 128, tmp);
    k_resid_ln<<<kROWS / 4, 256, 0, stream>>>(X, tmp, ln2_g + l * kH,
                                              ln2_b + l * kH, Xh, Xl);
  }

  k_heady<<<kROWS / 32, 256, 0, stream>>>(X, pro4_w, pro4_b, y);
  k_traj<<<kNAG, 64, 0, stream>>>(y, pro5_w, pro5_b, traj_in, dout, sc);
  k_loss<<<1, 1, 0, stream>>>(sc, dout);
}

// Round 8
// 1650.659 us; speedup vs baseline: 2.9075x; 1.1588x over previous
//
#include <hip/hip_runtime.h>
#include <math.h>

// GVAE-Transformer forward. fp32 interfaces; transformer matmuls on MFMA via
// split-bf16 (3-term: ah*bh + ah*bl + al*bh, fp32 accum), pre-converted
// inputs, global_load_lds staging with involution-swizzled LDS.
// Shapes: OBS=8 PRED=4 NAG=256 FIN=2 FOUT=2 H=128 NH=8 FF=2048 NL=6.
//
// R8 changes vs R7 (1913 us; k_attn 103.5us x6 VALU/LDS-bound, MfmaUtil 0):
//  - k_attn: MFMA flash attention. S^T = K@Q^T via 16x16x32 bf16 MFMA
//    (d padded 16->32, pad lanes zeroed on BOTH operands), K-row permutation
//    t=8*(x>>2)+(x&3) so each lane's S^T frags own t=8g..8g+7 per 32-block
//    -> p packs in-lane into the K=32 PV B-operand (no cross-lane shuffles).
//    PV: O^T = V^T @ P^T with V staged transposed [d][t] (plain b64 reads).
//    Split-bf16 3-term for S, 2-term P + V hi/lo for PV (fp32-class error).
//    Online softmax, always-rescale, lane-local l partial + end butterfly.

namespace {

constexpr int kOBS = 8, kNAG = 256, kH = 128;
constexpr int kGN = kOBS * kNAG;   // 2048 graph nodes
constexpr int kROWS = kNAG * kH;   // 32768 transformer rows (S=256, B=128)

typedef __attribute__((ext_vector_type(8))) short bf16x8;
typedef __attribute__((ext_vector_type(4))) short s16x4;
typedef __attribute__((ext_vector_type(4))) float f32x4;
typedef __attribute__((ext_vector_type(4))) unsigned short us4;

struct Scal {
  int    mn_bits;
  int    mx_bits;
  float  Amin;
  float  invr;
  float  c0;
  int    pad;
  double kld_sum;
  double struct_sum;
  double traj_sum;
};

__device__ inline float waveReduceSum(float v) {
#pragma unroll
  for (int off = 32; off; off >>= 1) v += __shfl_xor(v, off, 64);
  return v;
}

__device__ inline unsigned short f2bf(float f) {  // RNE fp32 -> bf16
  unsigned u = __float_as_uint(f);
  return (unsigned short)((u + 0x7fffu + ((u >> 16) & 1u)) >> 16);
}
__device__ inline float bf2f(unsigned short h) {
  return __uint_as_float((unsigned)h << 16);
}
__device__ inline void split4(float4 v, us4& h, us4& l) {
  h.x = f2bf(v.x); l.x = f2bf(v.x - bf2f(h.x));
  h.y = f2bf(v.y); l.y = f2bf(v.y - bf2f(h.y));
  h.z = f2bf(v.z); l.z = f2bf(v.z - bf2f(h.z));
  h.w = f2bf(v.w); l.w = f2bf(v.w - bf2f(h.w));
}

// load bf16x8 from 8B-aligned LDS (two b64 reads)
__device__ inline bf16x8 ld_bf8(const unsigned short* p) {
  union { bf16x8 v; s16x4 h[2]; } u;
  u.h[0] = *reinterpret_cast<const s16x4*>(p);
  u.h[1] = *reinterpret_cast<const s16x4*>(p + 4);
  return u.v;
}

// involution chunk swizzles (16B chunk index c).
__device__ inline int swz4(int c)  { return c ^ ((c >> 3) & 7); }
__device__ inline int swz16(int c) { return c ^ ((c >> 4) & 7); }

// async global->LDS, 16B per lane (dest = uniform base + lane*16)
#define GLL(g, s)                                             \
  __builtin_amdgcn_global_load_lds(                           \
      (const __attribute__((address_space(1))) void*)(g),     \
      (__attribute__((address_space(3))) void*)(s), 16, 0, 0)

__global__ void k_init(Scal* sc) {
  if (threadIdx.x == 0) {
    sc->mn_bits = 0x7f800000;
    sc->mx_bits = 0xff800000;
    sc->kld_sum = 0.0;
    sc->struct_sum = 0.0;
    sc->traj_sum = 0.0;
  }
}

__global__ void k_minmax(const float* __restrict__ adj, int n, Scal* sc) {
  float lmin = INFINITY, lmax = -INFINITY;
  for (int i = blockIdx.x * blockDim.x + threadIdx.x; i < n;
       i += gridDim.x * blockDim.x) {
    float v = adj[i];
    lmin = fminf(lmin, v);
    lmax = fmaxf(lmax, v);
  }
#pragma unroll
  for (int off = 32; off; off >>= 1) {
    lmin = fminf(lmin, __shfl_xor(lmin, off, 64));
    lmax = fmaxf(lmax, __shfl_xor(lmax, off, 64));
  }
  __shared__ float smn[4], smx[4];
  int w = threadIdx.x >> 6;
  if ((threadIdx.x & 63) == 0) { smn[w] = lmin; smx[w] = lmax; }
  __syncthreads();
  if (threadIdx.x == 0) {
    lmin = fminf(fminf(smn[0], smn[1]), fminf(smn[2], smn[3]));
    lmax = fmaxf(fmaxf(smx[0], smx[1]), fmaxf(smx[2], smx[3]));
    atomicMin(&sc->mn_bits, __float_as_int(lmin));
    atomicMax(&sc->mx_bits, __float_as_int(lmax));
  }
}

__global__ void k_scale(Scal* sc) {
  float mn = fminf(0.0f, __int_as_float(sc->mn_bits));
  float mx = fmaxf(0.0f, __int_as_float(sc->mx_bits));
  sc->Amin = mn;
  sc->invr = 1.0f / (mx - mn);
  sc->c0 = (0.0f - mn) * sc->invr;
}

__global__ void k_dis(const float* __restrict__ adj, const Scal* __restrict__ sc,
                      float* __restrict__ dis) {
  int j = blockIdx.x * 256 + threadIdx.x;
  int t = j >> 8, jj = j & 255;
  const float* a = adj + (size_t)t * 65536;
  float Amin = sc->Amin, invr = sc->invr, c0 = sc->c0;
  float sum = 0.f;
  for (int i = 0; i < 256; ++i) sum += (a[i * 256 + jj] - Amin) * invr;
  float djj = (a[jj * 256 + jj] - Amin) * invr;
  float deg = sum + 1792.0f * c0 + (djj == 0.0f ? 1.0f : 0.0f);
  dis[j] = deg > 0.0f ? 1.0f / sqrtf(deg) : 0.0f;
}

__global__ void k_agg(const float* __restrict__ adj, const Scal* __restrict__ sc,
                      const float* __restrict__ dis, float* __restrict__ agg) {
  int idx = blockIdx.x * 256 + threadIdx.x;
  int t = idx >> 16, i = (idx >> 8) & 255, j = idx & 255;
  float v = (adj[(size_t)t * 65536 + j * 256 + i] - sc->Amin) * sc->invr;
  if (i == j && v == 0.0f) v += 1.0f;
  agg[idx] = dis[t * 256 + j] * v * dis[t * 256 + i];
}

__global__ void k_enc1(const float* __restrict__ traj, const float* __restrict__ w,
                       const float* __restrict__ b, float* __restrict__ out) {
  int idx = blockIdx.x * 256 + threadIdx.x;
  int r = idx >> 7, f = idx & 127;
  float v = traj[r * 2] * w[f * 2] + traj[r * 2 + 1] * w[f * 2 + 1] + b[f];
  out[idx] = fmaxf(v, 0.0f);
}

// fp32 -> bf16 hi/lo, 4 elems/thread
__global__ void k_cvt(const float* __restrict__ src, unsigned short* __restrict__ h,
                      unsigned short* __restrict__ l, int n4) {
  int i = blockIdx.x * 256 + threadIdx.x;
  if (i >= n4) return;
  float4 v = reinterpret_cast<const float4*>(src)[i];
  us4 hh, ll;
  split4(v, hh, ll);
  reinterpret_cast<us4*>(h)[i] = hh;
  reinterpret_cast<us4*>(l)[i] = ll;
}

// ---------------- small fp32 GEMM (front-end, M=2048) ----------------
#define BM 64
#define BN 64
#define KC 32
#define LP 68

template <bool TB>
__global__ __launch_bounds__(256) void gemm_kernel(
    const float* __restrict__ A, const float* __restrict__ B,
    const float* __restrict__ bias, float* __restrict__ C, int K, int ldb,
    int ldc, int flags, size_t aStride, size_t bStride, size_t cStride) {
  if (blockIdx.z) {
    A += (size_t)blockIdx.z * aStride;
    B += (size_t)blockIdx.z * bStride;
    C += (size_t)blockIdx.z * cStride;
  }
  __shared__ float As[KC][LP];
  __shared__ float Bs[KC][LP];
  const int tid = threadIdx.x;
  const int tx = tid & 15, ty = tid >> 4;
  const int m0 = blockIdx.y * BM, n0 = blockIdx.x * BN;
  float acc[4][4] = {};
  for (int k0 = 0; k0 < K; k0 += KC) {
#pragma unroll
    for (int i = 0; i < 2; ++i) {
      int q = tid + i * 256;
      int row = q >> 3, kq = q & 7;
      float4 v = *reinterpret_cast<const float4*>(
          &A[(size_t)(m0 + row) * K + k0 + kq * 4]);
      As[kq * 4 + 0][row] = v.x;
      As[kq * 4 + 1][row] = v.y;
      As[kq * 4 + 2][row] = v.z;
      As[kq * 4 + 3][row] = v.w;
    }
    if (TB) {
#pragma unroll
      for (int i = 0; i < 2; ++i) {
        int q = tid + i * 256;
        int row = q >> 3, kq = q & 7;
        float4 v = *reinterpret_cast<const float4*>(
            &B[(size_t)(n0 + row) * ldb + k0 + kq * 4]);
        Bs[kq * 4 + 0][row] = v.x;
        Bs[kq * 4 + 1][row] = v.y;
        Bs[kq * 4 + 2][row] = v.z;
        Bs[kq * 4 + 3][row] = v.w;
      }
    } else {
#pragma unroll
      for (int i = 0; i < 2; ++i) {
        int q = tid + i * 256;
        int kr = q >> 4, nq = q & 15;
        float4 v = *reinterpret_cast<const float4*>(
            &B[(size_t)(k0 + kr) * ldb + n0 + nq * 4]);
        *reinterpret_cast<float4*>(&Bs[kr][nq * 4]) = v;
      }
    }
    __syncthreads();
#pragma unroll
    for (int kk = 0; kk < KC; ++kk) {
      float4 a4 = *reinterpret_cast<const float4*>(&As[kk][ty * 4]);
      float4 b4 = *reinterpret_cast<const float4*>(&Bs[kk][tx * 4]);
      float av[4] = {a4.x, a4.y, a4.z, a4.w};
      float bv[4] = {b4.x, b4.y, b4.z, b4.w};
#pragma unroll
      for (int i = 0; i < 4; ++i)
#pragma unroll
        for (int j = 0; j < 4; ++j) acc[i][j] += av[i] * bv[j];
    }
    __syncthreads();
  }
  float bv[4] = {0.f, 0.f, 0.f, 0.f};
  if (bias) {
    float4 b4 = *reinterpret_cast<const float4*>(&bias[n0 + tx * 4]);
    bv[0] = b4.x; bv[1] = b4.y; bv[2] = b4.z; bv[3] = b4.w;
  }
#pragma unroll
  for (int i = 0; i < 4; ++i) {
    float* cp = &C[(size_t)(m0 + ty * 4 + i) * ldc + n0 + tx * 4];
    float4 o;
    float ov[4];
#pragma unroll
    for (int j = 0; j < 4; ++j) ov[j] = acc[i][j] + bv[j];
    if (flags & 2) {
      float4 old = *reinterpret_cast<const float4*>(cp);
      ov[0] += old.x; ov[1] += old.y; ov[2] += old.z; ov[3] += old.w;
    }
    if (flags & 1) {
#pragma unroll
      for (int j = 0; j < 4; ++j) ov[j] = fmaxf(ov[j], 0.0f);
    }
    o.x = ov[0]; o.y = ov[1]; o.z = ov[2]; o.w = ov[3];
    *reinterpret_cast<float4*>(cp) = o;
  }
}

// ---------------- MFMA split-bf16 GEMM (qkv / out-proj) ----------------
template <int BMb, int BNb>
__global__ __launch_bounds__(256) void gemm_bf(
    const unsigned short* __restrict__ Ah, const unsigned short* __restrict__ Al,
    const unsigned short* __restrict__ Bh, const unsigned short* __restrict__ Bl,
    const float* __restrict__ bias, float* __restrict__ C,
    int K, int lda, int ldb, int ldc, int flags) {
  constexpr int MI = BMb / 32, NI = BNb / 32;
  constexpr int WTM = BMb / 2, WTN = BNb / 2;
  __shared__ unsigned short sAh[BMb * 32], sAl[BMb * 32];
  __shared__ unsigned short sBh[BNb * 32], sBl[BNb * 32];
  const int tid = threadIdx.x, lane = tid & 63, w = tid >> 6;
  const int wr = w >> 1, wc = w & 1;
  const int m0 = blockIdx.y * BMb, n0 = blockIdx.x * BNb;
  f32x4 acc[MI][NI];
#pragma unroll
  for (int i = 0; i < MI; ++i)
#pragma unroll
    for (int j = 0; j < NI; ++j) acc[i][j] = (f32x4){0.f, 0.f, 0.f, 0.f};

  for (int k0 = 0; k0 < K; k0 += 32) {
#pragma unroll
    for (int i = 0; i < BMb / 64; ++i) {
      int c = tid + i * 256;
      int g = swz4(c);
      int row = g >> 2, c4 = g & 3;
      size_t ga = (size_t)(m0 + row) * lda + k0 + c4 * 8;
      GLL(&Ah[ga], &sAh[c * 8]);
      GLL(&Al[ga], &sAl[c * 8]);
    }
#pragma unroll
    for (int i = 0; i < BNb / 64; ++i) {
      int c = tid + i * 256;
      int g = swz4(c);
      int row = g >> 2, c4 = g & 3;
      size_t ga = (size_t)(n0 + row) * ldb + k0 + c4 * 8;
      GLL(&Bh[ga], &sBh[c * 8]);
      GLL(&Bl[ga], &sBl[c * 8]);
    }
    __syncthreads();
    bf16x8 bh[NI], bl[NI];
#pragma unroll
    for (int ni = 0; ni < NI; ++ni) {
      int p = swz4((wc * WTN + ni * 16 + (lane & 15)) * 4 + (lane >> 4));
      bh[ni] = *reinterpret_cast<const bf16x8*>(&sBh[p * 8]);
      bl[ni] = *reinterpret_cast<const bf16x8*>(&sBl[p * 8]);
    }
#pragma unroll
    for (int mi = 0; mi < MI; ++mi) {
      int p = swz4((wr * WTM + mi * 16 + (lane & 15)) * 4 + (lane >> 4));
      bf16x8 ah = *reinterpret_cast<const bf16x8*>(&sAh[p * 8]);
      bf16x8 al = *reinterpret_cast<const bf16x8*>(&sAl[p * 8]);
#pragma unroll
      for (int ni = 0; ni < NI; ++ni) {
        acc[mi][ni] = __builtin_amdgcn_mfma_f32_16x16x32_bf16(
            ah, bh[ni], acc[mi][ni], 0, 0, 0);
        acc[mi][ni] = __builtin_amdgcn_mfma_f32_16x16x32_bf16(
            ah, bl[ni], acc[mi][ni], 0, 0, 0);
        acc[mi][ni] = __builtin_amdgcn_mfma_f32_16x16x32_bf16(
            al, bh[ni], acc[mi][ni], 0, 0, 0);
      }
    }
    __syncthreads();
  }
  const int crow0 = m0 + wr * WTM + (lane >> 4) * 4;
  const int ccol0 = n0 + wc * WTN + (lane & 15);
#pragma unroll
  for (int ni = 0; ni < NI; ++ni) {
    int col = ccol0 + ni * 16;
    float bv = bias ? bias[col] : 0.f;
#pragma unroll
    for (int mi = 0; mi < MI; ++mi) {
#pragma unroll
      for (int r = 0; r < 4; ++r) {
        int row = crow0 + mi * 16 + r;
        float v = acc[mi][ni][r] + bv;
        if (flags & 2) v += C[(size_t)row * ldc + col];
        if (flags & 1) v = fmaxf(v, 0.0f);
        C[(size_t)row * ldc + col] = v;
      }
    }
  }
}

// ---------------- fused FFN, pipelined (R7 state) ----------------
__global__ __launch_bounds__(256) void k_ffn(
    const unsigned short* __restrict__ Xh, const unsigned short* __restrict__ Xl,
    const unsigned short* __restrict__ W1h, const unsigned short* __restrict__ W1l,
    const float* __restrict__ b1,
    const unsigned short* __restrict__ W2h, const unsigned short* __restrict__ W2l,
    const float* __restrict__ b2, float* __restrict__ out) {
  __shared__ unsigned short sLds[40960];
  unsigned short* sPh = sLds + 32768;
  unsigned short* sPl = sLds + 34816;
  float* sB1 = reinterpret_cast<float*>(sLds + 36864);
  const int tid = threadIdx.x, lane = tid & 63, w = tid >> 6;
  const int wr = w >> 1, wc = w & 1;
  const int m0 = blockIdx.x * 64;

  auto stageW = [&](int buf, int f0) {
    unsigned short* d = sLds + buf * 16384;
#pragma unroll
    for (int i = 0; i < 2; ++i) {
      int c = tid + i * 256;
      {
        int g = swz16(c);
        size_t ga = (size_t)(f0 + (g >> 4)) * 128 + (g & 15) * 8;
        GLL(&W1h[ga], &d[c * 8]);
        GLL(&W1l[ga], &d[4096 + c * 8]);
      }
      {
        int g = swz4(c);
        size_t ga = (size_t)(g >> 2) * 2048 + f0 + (g & 3) * 8;
        GLL(&W2h[ga], &d[8192 + c * 8]);
        GLL(&W2l[ga], &d[12288 + c * 8]);
      }
    }
  };

  {
    unsigned short* sXh = sLds + 16384;
    unsigned short* sXl = sLds + 24576;
#pragma unroll
    for (int i = 0; i < 4; ++i) {
      int c = tid + i * 256;
      int g = swz16(c);
      size_t ga = (size_t)(m0 + (g >> 4)) * 128 + (g & 15) * 8;
      GLL(&Xh[ga], &sXh[c * 8]);
      GLL(&Xl[ga], &sXl[c * 8]);
    }
#pragma unroll
    for (int i = 0; i < 2; ++i) {
      int c = tid + i * 256;
      GLL(&b1[c * 4], &sB1[c * 4]);
    }
  }
  __builtin_amdgcn_sched_barrier(0);
  asm volatile("s_waitcnt vmcnt(0)");
  __builtin_amdgcn_sched_barrier(0);
  __builtin_amdgcn_s_barrier();
  stageW(0, 0);
  bf16x8 xah[4][2], xal[4][2];
  {
    unsigned short* sXh = sLds + 16384;
    unsigned short* sXl = sLds + 24576;
#pragma unroll
    for (int ks = 0; ks < 4; ++ks)
#pragma unroll
      for (int mi = 0; mi < 2; ++mi) {
        int row = wr * 32 + mi * 16 + (lane & 15);
        int p = swz16(row * 16 + ks * 4 + (lane >> 4));
        xah[ks][mi] = *reinterpret_cast<const bf16x8*>(&sXh[p * 8]);
        xal[ks][mi] = *reinterpret_cast<const bf16x8*>(&sXl[p * 8]);
      }
  }
  __builtin_amdgcn_sched_barrier(0);
  asm volatile("s_waitcnt lgkmcnt(0)");
  __builtin_amdgcn_sched_barrier(0);
  __builtin_amdgcn_s_barrier();

  f32x4 acc2[2][4];
#pragma unroll
  for (int i = 0; i < 2; ++i)
#pragma unroll
    for (int j = 0; j < 4; ++j) acc2[i][j] = (f32x4){0.f, 0.f, 0.f, 0.f};

  const int pcol = wc * 16 + (lane & 15);

  auto body = [&](int cur, int f0, bool hasNext) {
    unsigned short* bW1h = sLds + cur * 16384;
    unsigned short* bW1l = bW1h + 4096;
    unsigned short* bW2h = bW1h + 8192;
    unsigned short* bW2l = bW1h + 12288;
    if (hasNext) {
      stageW(cur ^ 1, f0 + 32);
      __builtin_amdgcn_sched_barrier(0);
      asm volatile("s_waitcnt vmcnt(8)");
    } else {
      __builtin_amdgcn_sched_barrier(0);
      asm volatile("s_waitcnt vmcnt(0)");
    }
    __builtin_amdgcn_sched_barrier(0);
    __builtin_amdgcn_s_barrier();
    f32x4 acc1[2];
    acc1[0] = (f32x4){0.f, 0.f, 0.f, 0.f};
    acc1[1] = (f32x4){0.f, 0.f, 0.f, 0.f};
#pragma unroll
    for (int ks = 0; ks < 4; ++ks) {
      int p = swz16((wc * 16 + (lane & 15)) * 16 + ks * 4 + (lane >> 4));
      bf16x8 bh = *reinterpret_cast<const bf16x8*>(&bW1h[p * 8]);
      bf16x8 bl = *reinterpret_cast<const bf16x8*>(&bW1l[p * 8]);
#pragma unroll
      for (int mi = 0; mi < 2; ++mi) {
        acc1[mi] = __builtin_amdgcn_mfma_f32_16x16x32_bf16(xah[ks][mi], bh,
                                                           acc1[mi], 0, 0, 0);
        acc1[mi] = __builtin_amdgcn_mfma_f32_16x16x32_bf16(xah[ks][mi], bl,
                                                           acc1[mi], 0, 0, 0);
        acc1[mi] = __builtin_amdgcn_mfma_f32_16x16x32_bf16(xal[ks][mi], bh,
                                                           acc1[mi], 0, 0, 0);
      }
    }
    float b1v = sB1[f0 + pcol];
#pragma unroll
    for (int mi = 0; mi < 2; ++mi)
#pragma unroll
      for (int r = 0; r < 4; ++r) {
        int prow = wr * 32 + mi * 16 + (lane >> 4) * 4 + r;
        float v = fmaxf(acc1[mi][r] + b1v, 0.0f);
        unsigned short h = f2bf(v);
        int p = swz4(prow * 4 + (pcol >> 3));
        sPh[p * 8 + (pcol & 7)] = h;
        sPl[p * 8 + (pcol & 7)] = f2bf(v - bf2f(h));
      }
    __builtin_amdgcn_sched_barrier(0);
    asm volatile("s_waitcnt lgkmcnt(0)");
    __builtin_amdgcn_sched_barrier(0);
    __builtin_amdgcn_s_barrier();
    bf16x8 pah[2], pal[2];
#pragma unroll
    for (int mi = 0; mi < 2; ++mi) {
      int p = swz4((wr * 32 + mi * 16 + (lane & 15)) * 4 + (lane >> 4));
      pah[mi] = *reinterpret_cast<const bf16x8*>(&sPh[p * 8]);
      pal[mi] = *reinterpret_cast<const bf16x8*>(&sPl[p * 8]);
    }
#pragma unroll
    for (int ni = 0; ni < 4; ++ni) {
      int p = swz4((wc * 64 + ni * 16 + (lane & 15)) * 4 + (lane >> 4));
      bf16x8 bh = *reinterpret_cast<const bf16x8*>(&bW2h[p * 8]);
      bf16x8 bl = *reinterpret_cast<const bf16x8*>(&bW2l[p * 8]);
#pragma unroll
      for (int mi = 0; mi < 2; ++mi) {
        acc2[mi][ni] = __builtin_amdgcn_mfma_f32_16x16x32_bf16(
            pah[mi], bh, acc2[mi][ni], 0, 0, 0);
        acc2[mi][ni] = __builtin_amdgcn_mfma_f32_16x16x32_bf16(
            pah[mi], bl, acc2[mi][ni], 0, 0, 0);
        acc2[mi][ni] = __builtin_amdgcn_mfma_f32_16x16x32_bf16(
            pal[mi], bh, acc2[mi][ni], 0, 0, 0);
      }
    }
    __builtin_amdgcn_sched_barrier(0);
    __builtin_amdgcn_s_barrier();
  };

  for (int fc2 = 0; fc2 < 32; ++fc2) {
    body(0, fc2 * 64, true);
    body(1, fc2 * 64 + 32, fc2 != 31);
  }

#pragma unroll
  for (int ni = 0; ni < 4; ++ni) {
    int col = wc * 64 + ni * 16 + (lane & 15);
    float bv = b2[col];
#pragma unroll
    for (int mi = 0; mi < 2; ++mi)
#pragma unroll
      for (int r = 0; r < 4; ++r) {
        int row = m0 + wr * 32 + mi * 16 + (lane >> 4) * 4 + r;
        out[(size_t)row * 128 + col] = acc2[mi][ni][r] + bv;
      }
  }
}

__global__ void k_zkld(const float* __restrict__ mu, const float* __restrict__ lsr,
                       const float* __restrict__ eps, const int* __restrict__ iftrain,
                       float* __restrict__ Z, Scal* sc) {
  int i = blockIdx.x * 256 + threadIdx.x;
  float m = mu[i];
  float ls = fminf(lsr[i], 10.0f);
  float z = (*iftrain > 0) ? m + eps[i] * __expf(ls) : m;
  Z[i] = z;
  float kt = 1.0f + 2.0f * ls - m * m - __expf(2.0f * ls);
  kt = waveReduceSum(kt);
  __shared__ float sh[4];
  int w = threadIdx.x >> 6;
  if ((threadIdx.x & 63) == 0) sh[w] = kt;
  __syncthreads();
  if (threadIdx.x == 0)
    atomicAdd(&sc->kld_sum, (double)(sh[0] + sh[1] + sh[2] + sh[3]));
}

__global__ __launch_bounds__(256) void k_struct(const float* __restrict__ Z,
                                                const float* __restrict__ adj,
                                                Scal* sc) {
  __shared__ float As[KC][LP];
  __shared__ float Bs[KC][LP];
  const int tid = threadIdx.x;
  const int tx = tid & 15, ty = tid >> 4;
  const int m0 = blockIdx.y * BM, n0 = blockIdx.x * BN;
  float acc[4][4] = {};
  for (int k0 = 0; k0 < kH; k0 += KC) {
#pragma unroll
    for (int i = 0; i < 2; ++i) {
      int q = tid + i * 256;
      int row = q >> 3, kq = q & 7;
      float4 va = *reinterpret_cast<const float4*>(
          &Z[(size_t)(m0 + row) * kH + k0 + kq * 4]);
      As[kq * 4 + 0][row] = va.x;
      As[kq * 4 + 1][row] = va.y;
      As[kq * 4 + 2][row] = va.z;
      As[kq * 4 + 3][row] = va.w;
      float4 vb = *reinterpret_cast<const float4*>(
          &Z[(size_t)(n0 + row) * kH + k0 + kq * 4]);
      Bs[kq * 4 + 0][row] = vb.x;
      Bs[kq * 4 + 1][row] = vb.y;
      Bs[kq * 4 + 2][row] = vb.z;
      Bs[kq * 4 + 3][row] = vb.w;
    }
    __syncthreads();
#pragma unroll
    for (int kk = 0; kk < KC; ++kk) {
      float4 a4 = *reinterpret_cast<const float4*>(&As[kk][ty * 4]);
      float4 b4 = *reinterpret_cast<const float4*>(&Bs[kk][tx * 4]);
      float av[4] = {a4.x, a4.y, a4.z, a4.w};
      float bv[4] = {b4.x, b4.y, b4.z, b4.w};
#pragma unroll
      for (int i = 0; i < 4; ++i)
#pragma unroll
        for (int j = 0; j < 4; ++j) acc[i][j] += av[i] * bv[j];
    }
    __syncthreads();
  }
  float Amin = sc->Amin, invr = sc->invr, c0v = sc->c0;
  float lsum = 0.f;
#pragma unroll
  for (int i = 0; i < 4; ++i) {
#pragma unroll
    for (int j = 0; j < 4; ++j) {
      int gi = m0 + ty * 4 + i, gj = n0 + tx * 4 + j;
      float l = acc[i][j];
      float adjv = c0v;
      if ((gi >> 8) == (gj >> 8))
        adjv = (adj[((size_t)(gi >> 8) << 16) + (gi & 255) * 256 + (gj & 255)] -
                Amin) * invr;
      lsum += fmaxf(l, 0.0f) - l * adjv + __logf(1.0f + __expf(-fabsf(l)));
    }
  }
  lsum = waveReduceSum(lsum);
  __shared__ float sh[4];
  int w = threadIdx.x >> 6;
  if ((threadIdx.x & 63) == 0) sh[w] = lsum;
  __syncthreads();
  if (threadIdx.x == 0)
    atomicAdd(&sc->struct_sum, (double)(sh[0] + sh[1] + sh[2] + sh[3]));
}

__global__ void k_x0(const float* __restrict__ gdl, const float* __restrict__ w3,
                     const float* __restrict__ b3, float* __restrict__ X,
                     unsigned short* __restrict__ Xh,
                     unsigned short* __restrict__ Xl) {
  int f = threadIdx.x;
  size_t r = (size_t)blockIdx.x * 2 + threadIdx.y;
  int n = (int)(r >> 7), h = (int)(r & 127);
  float a = b3[f];
#pragma unroll
  for (int o = 0; o < 8; ++o)
    a += gdl[((size_t)o * 256 + n) * 128 + h] * w3[f * 8 + o];
  X[r * 128 + f] = a;
  unsigned short hh = f2bf(a);
  Xh[r * 128 + f] = hh;
  Xl[r * 128 + f] = f2bf(a - bf2f(hh));
}

// ---------------- MFMA flash attention ----------------
// One block per (head, b); 4 waves x 64 q-rows.  S^T = K @ Q^T via
// mfma_f32_16x16x32_bf16 with d padded 16->32 (pad lanes g>=2 supply ZERO
// on both operands).  K-row permutation t=8*(x>>2)+(x&3) per 32-t block so
// lane (g,x) ends up owning p for t=8g+i (i=0..7) at q=x -> packs directly
// into the K=32 B-operand of PV: O^T = V^T @ P^T (V staged transposed).
__global__ __launch_bounds__(256) void k_attn(const float* __restrict__ QKV,
                                              unsigned short* __restrict__ Oh,
                                              unsigned short* __restrict__ Ol) {
  __shared__ unsigned short sQh[256 * 20], sQl[256 * 20];
  __shared__ unsigned short sKh[256 * 20], sKl[256 * 20];
  __shared__ unsigned short sVh[16 * 264], sVl[16 * 264];
  const int head = blockIdx.x, b = blockIdx.y;
  const int tid = threadIdx.x;
  const int lane = tid & 63, w = tid >> 6;
  const int g = lane >> 4, x = lane & 15;

  // ---- stage: Q (scaled 0.25) / K as [s][d] rows padded to 20 shorts;
  //      V transposed as [d][s] rows padded to 264 shorts.  hi/lo split.
  {
    const size_t base = ((size_t)tid * 128 + b) * 384 + (size_t)head * 16;
#pragma unroll
    for (int j = 0; j < 4; ++j) {
      float4 qv = *reinterpret_cast<const float4*>(&QKV[base + j * 4]);
      qv.x *= 0.25f; qv.y *= 0.25f; qv.z *= 0.25f; qv.w *= 0.25f;
      us4 h, l;
      split4(qv, h, l);
      *reinterpret_cast<us4*>(&sQh[tid * 20 + j * 4]) = h;
      *reinterpret_cast<us4*>(&sQl[tid * 20 + j * 4]) = l;
      float4 kv = *reinterpret_cast<const float4*>(&QKV[base + 128 + j * 4]);
      split4(kv, h, l);
      *reinterpret_cast<us4*>(&sKh[tid * 20 + j * 4]) = h;
      *reinterpret_cast<us4*>(&sKl[tid * 20 + j * 4]) = l;
      float4 vv = *reinterpret_cast<const float4*>(&QKV[base + 256 + j * 4]);
      split4(vv, h, l);
      sVh[(j * 4 + 0) * 264 + tid] = h.x; sVl[(j * 4 + 0) * 264 + tid] = l.x;
      sVh[(j * 4 + 1) * 264 + tid] = h.y; sVl[(j * 4 + 1) * 264 + tid] = l.y;
      sVh[(j * 4 + 2) * 264 + tid] = h.z; sVl[(j * 4 + 2) * 264 + tid] = l.z;
      sVh[(j * 4 + 3) * 264 + tid] = h.w; sVl[(j * 4 + 3) * 264 + tid] = l.w;
    }
  }
  __syncthreads();

  const bf16x8 zero8 = {0, 0, 0, 0, 0, 0, 0, 0};
  // hoisted Q B-frags: lane supplies Q[q = qtile + x][d = 8g+i]; zero for
  // the d-pad lanes (g>=2).
  bf16x8 qbh[4], qbl[4];
#pragma unroll
  for (int qi = 0; qi < 4; ++qi) {
    if (g < 2) {
      int row = w * 64 + qi * 16 + x;
      qbh[qi] = ld_bf8(&sQh[row * 20 + 8 * g]);
      qbl[qi] = ld_bf8(&sQl[row * 20 + 8 * g]);
    } else {
      qbh[qi] = zero8;
      qbl[qi] = zero8;
    }
  }

  f32x4 oacc[4];
  float mrun[4], lrun[4];
#pragma unroll
  for (int qi = 0; qi < 4; ++qi) {
    oacc[qi] = (f32x4){0.f, 0.f, 0.f, 0.f};
    mrun[qi] = -1e30f;
    lrun[qi] = 0.f;
  }

  for (int b32 = 0; b32 < 8; ++b32) {
    // K A-frags, rows permuted (tileA: t=8*(x>>2)+(x&3); tileB: +4)
    const int xa = 32 * b32 + 8 * (x >> 2) + (x & 3);
    const int xb = xa + 4;
    bf16x8 kah = zero8, kal = zero8, kbh = zero8, kbl = zero8;
    if (g < 2) {
      kah = ld_bf8(&sKh[xa * 20 + 8 * g]);
      kal = ld_bf8(&sKl[xa * 20 + 8 * g]);
      kbh = ld_bf8(&sKh[xb * 20 + 8 * g]);
      kbl = ld_bf8(&sKl[xb * 20 + 8 * g]);
    }
    // V^T A-frags for this 32-t block: V^T[d=x][t=32*b32+8g+i]
    const bf16x8 vth = ld_bf8(&sVh[x * 264 + 32 * b32 + 8 * g]);
    const bf16x8 vtl = ld_bf8(&sVl[x * 264 + 32 * b32 + 8 * g]);
#pragma unroll
    for (int qi = 0; qi < 4; ++qi) {
      f32x4 sA = (f32x4){0.f, 0.f, 0.f, 0.f};
      f32x4 sB = (f32x4){0.f, 0.f, 0.f, 0.f};
      sA = __builtin_amdgcn_mfma_f32_16x16x32_bf16(kah, qbh[qi], sA, 0, 0, 0);
      sA = __builtin_amdgcn_mfma_f32_16x16x32_bf16(kah, qbl[qi], sA, 0, 0, 0);
      sA = __builtin_amdgcn_mfma_f32_16x16x32_bf16(kal, qbh[qi], sA, 0, 0, 0);
      sB = __builtin_amdgcn_mfma_f32_16x16x32_bf16(kbh, qbh[qi], sB, 0, 0, 0);
      sB = __builtin_amdgcn_mfma_f32_16x16x32_bf16(kbh, qbl[qi], sB, 0, 0, 0);
      sB = __builtin_amdgcn_mfma_f32_16x16x32_bf16(kbl, qbh[qi], sB, 0, 0, 0);
      // online softmax for q = x over the 32 t of this block
      float mt = fmaxf(fmaxf(fmaxf(sA[0], sA[1]), fmaxf(sA[2], sA[3])),
                       fmaxf(fmaxf(sB[0], sB[1]), fmaxf(sB[2], sB[3])));
      mt = fmaxf(mt, __shfl_xor(mt, 16));
      mt = fmaxf(mt, __shfl_xor(mt, 32));
      const float mnew = fmaxf(mrun[qi], mt);
      const float c = __expf(mrun[qi] - mnew);
      mrun[qi] = mnew;
      float p[8];
      p[0] = __expf(sA[0] - mnew); p[1] = __expf(sA[1] - mnew);
      p[2] = __expf(sA[2] - mnew); p[3] = __expf(sA[3] - mnew);
      p[4] = __expf(sB[0] - mnew); p[5] = __expf(sB[1] - mnew);
      p[6] = __expf(sB[2] - mnew); p[7] = __expf(sB[3] - mnew);
      lrun[qi] = lrun[qi] * c +
                 ((p[0] + p[1]) + (p[2] + p[3])) +
                 ((p[4] + p[5]) + (p[6] + p[7]));
      union { bf16x8 v; unsigned short s[8]; } ph, pl;
#pragma unroll
      for (int i = 0; i < 8; ++i) {
        unsigned short h = f2bf(p[i]);
        ph.s[i] = h;
        pl.s[i] = f2bf(p[i] - bf2f(h));
      }
      f32x4 o = oacc[qi] * c;
      o = __builtin_amdgcn_mfma_f32_16x16x32_bf16(vth, ph.v, o, 0, 0, 0);
      o = __builtin_amdgcn_mfma_f32_16x16x32_bf16(vth, pl.v, o, 0, 0, 0);
      o = __builtin_amdgcn_mfma_f32_16x16x32_bf16(vtl, ph.v, o, 0, 0, 0);
      oacc[qi] = o;
    }
  }

  // epilogue: O[q][d] = O^T frag / l; write bf16 hi/lo
#pragma unroll
  for (int qi = 0; qi < 4; ++qi) {
    float lt = lrun[qi];
    lt += __shfl_xor(lt, 16);
    lt += __shfl_xor(lt, 32);
    const float inv = 1.0f / lt;
    const int qrow = w * 64 + qi * 16 + x;
    const size_t ob = ((size_t)qrow * 128 + b) * 128 + head * 16 + 4 * g;
    float4 ov;
    ov.x = oacc[qi][0] * inv; ov.y = oacc[qi][1] * inv;
    ov.z = oacc[qi][2] * inv; ov.w = oacc[qi][3] * inv;
    us4 h, l;
    split4(ov, h, l);
    *reinterpret_cast<us4*>(&Oh[ob]) = h;
    *reinterpret_cast<us4*>(&Ol[ob]) = l;
  }
}

// X = LN(X + T); also emits Xh/Xl bf16 hi/lo
__global__ __launch_bounds__(256) void k_resid_ln(
    float* __restrict__ X, const float* __restrict__ T,
    const float* __restrict__ g, const float* __restrict__ b,
    unsigned short* __restrict__ Xh, unsigned short* __restrict__ Xl) {
  int lane = threadIdx.x & 63, rl = threadIdx.x >> 6;
  size_t row = (size_t)blockIdx.x * 4 + rl;
  float* xp = X + row * 128;
  const float* tp = T + row * 128;
  float e0 = xp[lane] + tp[lane];
  float e1 = xp[lane + 64] + tp[lane + 64];
  float mean = waveReduceSum(e0 + e1) * 0.0078125f;
  float d0 = e0 - mean, d1 = e1 - mean;
  float var = waveReduceSum(d0 * d0 + d1 * d1) * 0.0078125f;
  float inv = 1.0f / sqrtf(var + 1e-5f);
  float v0 = d0 * inv * g[lane] + b[lane];
  float v1 = d1 * inv * g[lane + 64] + b[lane + 64];
  xp[lane] = v0;
  xp[lane + 64] = v1;
  unsigned short h0 = f2bf(v0), h1 = f2bf(v1);
  Xh[row * 128 + lane] = h0;
  Xl[row * 128 + lane] = f2bf(v0 - bf2f(h0));
  Xh[row * 128 + lane + 64] = h1;
  Xl[row * 128 + lane + 64] = f2bf(v1 - bf2f(h1));
}

__global__ void k_heady(const float* __restrict__ X, const float* __restrict__ w4,
                        const float* __restrict__ b4, float* __restrict__ y) {
  int tid = threadIdx.x;
  int o = tid & 7, rl = tid >> 3;
  size_t r = (size_t)blockIdx.x * 32 + rl;
  const float* xp = X + r * 128;
  const float* wp = w4 + o * 128;
  float a = b4[o];
  for (int f = 0; f < 128; f += 4)
    a += xp[f] * wp[f] + xp[f + 1] * wp[f + 1] + xp[f + 2] * wp[f + 2] +
         xp[f + 3] * wp[f + 3];
  y[r * 8 + o] = a;
}

__global__ void k_traj(const float* __restrict__ y, const float* __restrict__ w5,
                       const float* __restrict__ b5,
                       const float* __restrict__ traj_in, float* __restrict__ dout,
                       Scal* sc) {
  int n = blockIdx.x, lane = threadIdx.x;
  float w0a = w5[lane], w0b = w5[lane + 64];
  float w1a = w5[128 + lane], w1b = w5[128 + lane + 64];
  float dsum = 0.f;
  for (int oi = 0; oi < 4; ++oi) {
    int o = 4 + oi;
    float ya = y[((size_t)n * 128 + lane) * 8 + o];
    float yb = y[((size_t)n * 128 + lane + 64) * 8 + o];
    float s0 = waveReduceSum(w0a * ya + w0b * yb);
    float s1 = waveReduceSum(w1a * ya + w1b * yb);
    if (lane == 0) {
      float t0 = s0 + b5[0], t1 = s1 + b5[1];
      dout[oi * 512 + n * 2 + 0] = t0;
      dout[oi * 512 + n * 2 + 1] = t1;
      float dx = t0 - traj_in[((8 + oi) * 256 + n) * 2 + 0];
      float dy = t1 - traj_in[((8 + oi) * 256 + n) * 2 + 1];
      dsum += sqrtf(dx * dx + dy * dy);
    }
  }
  if (lane == 0) atomicAdd(&sc->traj_sum, (double)dsum);
}

__global__ void k_loss(const Scal* sc, float* dout) {
  if (threadIdx.x == 0) {
    double traj_loss = sc->traj_sum / 256.0;
    double kld = -0.5 * sc->kld_sum / 2048.0;
    double st = sc->struct_sum / (2048.0 * 2048.0);
    dout[2048] = (float)(traj_loss + kld + st);
  }
}

}  // namespace

extern "C" void kernel_launch(void* const* d_in, const int* in_sizes, int n_in,
                              void* d_out, int out_size, void* d_ws,
                              size_t ws_size, hipStream_t stream) {
  (void)in_sizes; (void)n_in; (void)out_size; (void)ws_size;
  const float* traj_in = (const float*)d_in[0];
  const float* adj     = (const float*)d_in[1];
  const float* eps     = (const float*)d_in[2];
  const float* pro1_w  = (const float*)d_in[3];
  const float* pro1_b  = (const float*)d_in[4];
  const float* pro2_w  = (const float*)d_in[5];
  const float* pro2_b  = (const float*)d_in[6];
  const float* mu_w    = (const float*)d_in[7];
  const float* mu_b    = (const float*)d_in[8];
  const float* ls_w    = (const float*)d_in[9];
  const float* ls_b    = (const float*)d_in[10];
  const float* gdl_w   = (const float*)d_in[11];
  const float* gdl_b   = (const float*)d_in[12];
  const float* pro3_w  = (const float*)d_in[13];
  const float* pro3_b  = (const float*)d_in[14];
  const float* pro4_w  = (const float*)d_in[15];
  const float* pro4_b  = (const float*)d_in[16];
  const float* pro5_w  = (const float*)d_in[17];
  const float* pro5_b  = (const float*)d_in[18];
  const float* qkv_w   = (const float*)d_in[19];
  const float* qkv_b   = (const float*)d_in[20];
  const float* outp_w  = (const float*)d_in[21];
  const float* outp_b  = (const float*)d_in[22];
  const float* ff1_w   = (const float*)d_in[23];
  const float* ff1_b   = (const float*)d_in[24];
  const float* ff2_w   = (const float*)d_in[25];
  const float* ff2_b   = (const float*)d_in[26];
  const float* ln1_g   = (const float*)d_in[27];
  const float* ln1_b   = (const float*)d_in[28];
  const float* ln2_g   = (const float*)d_in[29];
  const float* ln2_b   = (const float*)d_in[30];
  const int*   iftrain = (const int*)d_in[31];
  float* dout = (float*)d_out;

  char* wsb = (char*)d_ws;
  size_t off = 0;
  auto alloc = [&](size_t bytes) {
    char* p = wsb + off;
    off += (bytes + 255) & ~(size_t)255;
    return p;
  };
  Scal* sc    = (Scal*)alloc(256);
  float* dis  = (float*)alloc(kGN * 4);
  float* agg  = (float*)alloc((size_t)kOBS * 65536 * 4);
  float* enc1 = (float*)alloc((size_t)kGN * kH * 4);
  float* enc  = (float*)alloc((size_t)kGN * kH * 4);
  float* Mmu  = (float*)alloc((size_t)kGN * kH * 4);
  float* Mls  = (float*)alloc((size_t)kGN * kH * 4);
  float* mu   = (float*)alloc((size_t)kGN * kH * 4);
  float* lsb  = (float*)alloc((size_t)kGN * kH * 4);
  float* Z    = (float*)alloc((size_t)kGN * kH * 4);
  float* gdl  = (float*)alloc((size_t)kGN * kH * 4);
  float* X    = (float*)alloc((size_t)kROWS * kH * 4);
  unsigned short* Xh = (unsigned short*)alloc((size_t)kROWS * kH * 2);
  unsigned short* Xl = (unsigned short*)alloc((size_t)kROWS * kH * 2);
  float* QKV = (float*)alloc((size_t)kROWS * 384 * 4);
  unsigned short* Oh = (unsigned short*)alloc((size_t)kROWS * kH * 2);
  unsigned short* Ol = (unsigned short*)alloc((size_t)kROWS * kH * 2);
  float* tmp  = (float*)alloc((size_t)kROWS * kH * 4);
  float* y    = (float*)alloc((size_t)kROWS * 8 * 4);
  unsigned short* qkvWh = (unsigned short*)alloc(6 * 384 * 128 * 2);
  unsigned short* qkvWl = (unsigned short*)alloc(6 * 384 * 128 * 2);
  unsigned short* outWh = (unsigned short*)alloc(6 * 128 * 128 * 2);
  unsigned short* outWl = (unsigned short*)alloc(6 * 128 * 128 * 2);
  unsigned short* ff1Wh = (unsigned short*)alloc(6 * 2048 * 128 * 2);
  unsigned short* ff1Wl = (unsigned short*)alloc(6 * 2048 * 128 * 2);
  unsigned short* ff2Wh = (unsigned short*)alloc(6 * 128 * 2048 * 2);
  unsigned short* ff2Wl = (unsigned short*)alloc(6 * 128 * 2048 * 2);

  auto gemm_nt_small = [&](const float* A, const float* B, const float* bias,
                           float* C, int M, int N, int K, int ldb, int ldc,
                           int flags) {
    dim3 g(N / 64, M / 64, 1);
    gemm_kernel<true><<<g, 256, 0, stream>>>(A, B, bias, C, K, ldb, ldc, flags,
                                             (size_t)0, (size_t)0, (size_t)0);
  };

  // one-time weight conversions
  k_cvt<<<(6 * 384 * 128 / 4 + 255) / 256, 256, 0, stream>>>(
      qkv_w, qkvWh, qkvWl, 6 * 384 * 128 / 4);
  k_cvt<<<(6 * 128 * 128 / 4 + 255) / 256, 256, 0, stream>>>(
      outp_w, outWh, outWl, 6 * 128 * 128 / 4);
  k_cvt<<<(6 * 2048 * 128 / 4 + 255) / 256, 256, 0, stream>>>(
      ff1_w, ff1Wh, ff1Wl, 6 * 2048 * 128 / 4);
  k_cvt<<<(6 * 128 * 2048 / 4 + 255) / 256, 256, 0, stream>>>(
      ff2_w, ff2Wh, ff2Wl, 6 * 128 * 2048 / 4);

  k_init<<<1, 64, 0, stream>>>(sc);
  k_minmax<<<512, 256, 0, stream>>>(adj, kOBS * kNAG * kNAG, sc);
  k_scale<<<1, 1, 0, stream>>>(sc);
  k_dis<<<8, 256, 0, stream>>>(adj, sc, dis);
  k_agg<<<2048, 256, 0, stream>>>(adj, sc, dis, agg);

  k_enc1<<<(kGN * kH) / 256, 256, 0, stream>>>(traj_in, pro1_w, pro1_b, enc1);
  gemm_nt_small(enc1, pro2_w, pro2_b, enc, kGN, kH, kH, kH, kH, 0);
  gemm_nt_small(enc, mu_w, mu_b, Mmu, kGN, kH, kH, kH, kH, 0);
  gemm_nt_small(enc, ls_w, ls_b, Mls, kGN, kH, kH, kH, kH, 0);
  {
    dim3 g(kH / 64, kNAG / 64, kOBS);
    gemm_kernel<false><<<g, 256, 0, stream>>>(agg, Mmu, nullptr, mu, kNAG, kH,
                                              kH, 0, (size_t)65536,
                                              (size_t)kNAG * kH, (size_t)kNAG * kH);
    gemm_kernel<false><<<g, 256, 0, stream>>>(agg, Mls, nullptr, lsb, kNAG, kH,
                                              kH, 0, (size_t)65536,
                                              (size_t)kNAG * kH, (size_t)kNAG * kH);
  }
  k_zkld<<<(kGN * kH) / 256, 256, 0, stream>>>(mu, lsb, eps, iftrain, Z, sc);
  gemm_nt_small(Z, gdl_w, gdl_b, gdl, kGN, kH, kH, kH, kH, 0);
  k_struct<<<dim3(kGN / 64, kGN / 64), 256, 0, stream>>>(Z, adj, sc);
  k_x0<<<kROWS / 2, dim3(128, 2), 0, stream>>>(gdl, pro3_w, pro3_b, X, Xh, Xl);

  for (int l = 0; l < 6; ++l) {
    // qkv: (32768,384) = X @ Wqkv^T  -> fp32 QKV
    gemm_bf<128, 128><<<dim3(3, kROWS / 128), 256, 0, stream>>>(
        Xh, Xl, qkvWh + (size_t)l * 384 * 128, qkvWl + (size_t)l * 384 * 128,
        qkv_b + l * 384, QKV, 128, 128, 128, 384, 0);
    k_attn<<<dim3(8, 128), 256, 0, stream>>>(QKV, Oh, Ol);
    // out-proj: (32768,128) -> fp32 tmp
    gemm_bf<64, 128><<<dim3(1, kROWS / 64), 256, 0, stream>>>(
        Oh, Ol, outWh + (size_t)l * 128 * 128, outWl + (size_t)l * 128 * 128,
        outp_b + l * 128, tmp, 128, 128, 128, 128, 0);
    k_resid_ln<<<kROWS / 4, 256, 0, stream>>>(X, tmp, ln1_g + l * kH,
                                              ln1_b + l * kH, Xh, Xl);
    // fused FFN (pipelined) -> fp32 tmp
    k_ffn<<<kROWS / 64, 256, 0, stream>>>(
        Xh, Xl, ff1Wh + (size_t)l * 2048 * 128, ff1Wl + (size_t)l * 2048 * 128,
        ff1_b + l * 2048, ff2Wh + (size_t)l * 128 * 2048,
        ff2Wl + (size_t)l * 128 * 2048, ff2_b + l * 128, tmp);
    k_resid_ln<<<kROWS / 4, 256, 0, stream>>>(X, tmp, ln2_g + l * kH,
                                              ln2_b + l * kH, Xh, Xl);
  }

  k_heady<<<kROWS / 32, 256, 0, stream>>>(X, pro4_w, pro4_b, y);
  k_traj<<<kNAG, 64, 0, stream>>>(y, pro5_w, pro5_b, traj_in, dout, sc);
  k_loss<<<1, 1, 0, stream>>>(sc, dout);
}